// Round 1
// 7497.378 us; speedup vs baseline: 1.0151x; 1.0151x over previous
//
#include <hip/hip_runtime.h>
#include <math.h>

// ---------------- constants ----------------
#define Bc   32
#define Nc   379
#define Hc   512
#define NHc  8
#define Pc   3
#define HDc  64          // H/NH
#define NNc  (Nc*Nc)     // 143641
#define CB   8           // batch chunk
#define NCHUNK 4
static const size_t NH_f  = (size_t)Nc*Hc;           // 194,048
static const size_t BNH   = (size_t)Bc*Nc*Hc;        // 6,207,488
#define ROWS_BN   12128   // B*N
#define ROWS_CHUNK 3032   // CB*N
#define ROWS_WG    9096   // CB*P*N
static const size_t CHUNK_NH = (size_t)CB*Nc*Hc;     // 1,552,384
static const size_t PEC_SZ   = (size_t)ROWS_WG*Hc;   // 4,657,152
static const size_t HIDC_SZ  = (size_t)ROWS_CHUNK*4*Hc; // 6,209,536

#define WGS_SPLIT 16     // blocks per (b,r) row in wg_stats
#define TSPLIT 16        // n-splits in tokens reduction

typedef __attribute__((ext_vector_type(8))) short bf16x8;
typedef __attribute__((ext_vector_type(4))) float f32x4;

__device__ inline float gelu_f(float x) {
    return 0.5f * x * (1.0f + erff(x * 0.7071067811865476f));
}

// fp32 -> bf16 bits, round-to-nearest-even
__device__ inline short f2bf(float f) {
    unsigned u = __float_as_uint(f);
    unsigned r = u + 0x7fffu + ((u >> 16) & 1u);
    return (short)(r >> 16);
}

// block reductions (blockDim == 256)
__device__ inline float blk_sum(float v, float* sh) {
#pragma unroll
    for (int off = 32; off; off >>= 1) v += __shfl_xor(v, off, 64);
    int w = threadIdx.x >> 6;
    __syncthreads();
    if ((threadIdx.x & 63) == 0) sh[w] = v;
    __syncthreads();
    return sh[0] + sh[1] + sh[2] + sh[3];
}
__device__ inline float blk_max(float v, float* sh) {
#pragma unroll
    for (int off = 32; off; off >>= 1) v = fmaxf(v, __shfl_xor(v, off, 64));
    int w = threadIdx.x >> 6;
    __syncthreads();
    if ((threadIdx.x & 63) == 0) sh[w] = v;
    __syncthreads();
    return fmaxf(fmaxf(sh[0], sh[1]), fmaxf(sh[2], sh[3]));
}

// ---------------- bf16 MFMA GEMM ----------------
// C(M,N) = A(M,K)@B(K,N), A,B fp32 in global, converted to bf16 in LDS, fp32 acc.
// Requires N % 128 == 0. M,K arbitrary (guarded / zero-padded).
// Epilogues: 0 none; 1 +bias; 2 gelu(+bias); 3 gelu(+bias + addsrc P-broadcast); 4 *rowscale[row/rs_div]+bias
#define BM 128
#define BN 128
#define BK 32
#define LDK 40   // padded k-stride (bf16 elems)

template<int EPI>
__global__ __launch_bounds__(256) void bgemm_k(
    const float* __restrict__ A, const float* __restrict__ B, float* __restrict__ C,
    int M, int N, int K,
    const float* __restrict__ bias,
    const float* __restrict__ rowscale, int rs_div,
    const float* __restrict__ addsrc, int addP, int addN)
{
    __shared__ __attribute__((aligned(16))) short As[BM * LDK];
    __shared__ __attribute__((aligned(16))) short Bs[BN * LDK];
    int tid = threadIdx.x;
    int wave = tid >> 6, lane = tid & 63;
    int wr = wave >> 1, wc = wave & 1;         // 2x2 waves, each 64x64
    int m0 = blockIdx.y * BM, n0 = blockIdx.x * BN;
    int quad = lane >> 4, l16 = lane & 15;
    bool k_vec = ((K & 3) == 0);

    f32x4 acc[4][4] = {};

    for (int k0 = 0; k0 < K; k0 += BK) {
        // ---- stage A tile: 128 x 32, fp32 -> bf16 ----
        {
            int row = tid >> 3;            // 0..31
            int kk  = (tid & 7) * 4;       // 0..28
#pragma unroll
            for (int rr = 0; rr < 4; rr++) {
                int m = row + rr * 32;
                int gm = m0 + m;
                float4 v = make_float4(0.f, 0.f, 0.f, 0.f);
                if (gm < M) {
                    int gk = k0 + kk;
                    const float* src = A + (size_t)gm * K + gk;
                    if (k_vec && gk + 3 < K) v = *(const float4*)src;
                    else {
                        if (gk     < K) v.x = src[0];
                        if (gk + 1 < K) v.y = src[1];
                        if (gk + 2 < K) v.z = src[2];
                        if (gk + 3 < K) v.w = src[3];
                    }
                }
                short* dst = &As[m * LDK + kk];
                dst[0] = f2bf(v.x); dst[1] = f2bf(v.y);
                dst[2] = f2bf(v.z); dst[3] = f2bf(v.w);
            }
        }
        // ---- stage B tile transposed: Bs[n][k], 128 n x 32 k ----
        {
            int kk = tid >> 5;             // 0..7
            int nn = (tid & 31) * 4;       // 0..124
#pragma unroll
            for (int rr = 0; rr < 4; rr++) {
                int k = kk + rr * 8;
                int gk = k0 + k;
                float4 v = make_float4(0.f, 0.f, 0.f, 0.f);
                if (gk < K) v = *(const float4*)(B + (size_t)gk * N + n0 + nn);
                Bs[(nn + 0) * LDK + k] = f2bf(v.x);
                Bs[(nn + 1) * LDK + k] = f2bf(v.y);
                Bs[(nn + 2) * LDK + k] = f2bf(v.z);
                Bs[(nn + 3) * LDK + k] = f2bf(v.w);
            }
        }
        __syncthreads();
        bf16x8 afr[4], bfr[4];
#pragma unroll
        for (int mt = 0; mt < 4; mt++)
            afr[mt] = *(const bf16x8*)&As[(wr * 64 + mt * 16 + l16) * LDK + quad * 8];
#pragma unroll
        for (int nt = 0; nt < 4; nt++)
            bfr[nt] = *(const bf16x8*)&Bs[(wc * 64 + nt * 16 + l16) * LDK + quad * 8];
#pragma unroll
        for (int mt = 0; mt < 4; mt++)
#pragma unroll
            for (int nt = 0; nt < 4; nt++)
                acc[mt][nt] = __builtin_amdgcn_mfma_f32_16x16x32_bf16(
                    afr[mt], bfr[nt], acc[mt][nt], 0, 0, 0);
        __syncthreads();
    }
    // ---- epilogue: C/D layout col=lane&15, row=quad*4+reg ----
#pragma unroll
    for (int mt = 0; mt < 4; mt++) {
#pragma unroll
        for (int nt = 0; nt < 4; nt++) {
#pragma unroll
            for (int r = 0; r < 4; r++) {
                int gm = m0 + wr * 64 + mt * 16 + quad * 4 + r;
                int gn = n0 + wc * 64 + nt * 16 + l16;
                if (gm < M) {
                    float v = acc[mt][nt][r];
                    if (EPI == 1 || EPI == 2 || EPI == 3) v += bias[gn];
                    if (EPI == 4) v = v * rowscale[gm / rs_div] + bias[gn];
                    if (EPI == 3) {
                        int addrow = (gm / (addP * addN)) * addN + (gm % addN);
                        v += addsrc[(size_t)addrow * N + gn];
                    }
                    if (EPI == 2 || EPI == 3) v = gelu_f(v);
                    C[(size_t)gm * N + gn] = v;
                }
            }
        }
    }
}

template<int EPI>
static void launch_bgemm(const float* A, const float* B, float* C, int M, int N, int K,
                         const float* bias, const float* rowscale, int rs_div,
                         const float* addsrc, int addP, int addN, hipStream_t st) {
    dim3 grid(N / 128, (M + 127) / 128);
    bgemm_k<EPI><<<grid, 256, 0, st>>>(A, B, C, M, N, K, bias, rowscale, rs_div, addsrc, addP, addN);
}

// ---------------- LayerNorm (rows of 512) ----------------
__global__ __launch_bounds__(256) void ln_k(const float* __restrict__ x,
                                            const float* __restrict__ g,
                                            const float* __restrict__ b,
                                            float* __restrict__ z) {
    __shared__ float sh[4];
    int r = blockIdx.x, t = threadIdx.x;
    const float* xr = x + (size_t)r * Hc;
    float v0 = xr[t], v1 = xr[t + 256];
    float sum = blk_sum(v0 + v1, sh);
    float sq  = blk_sum(v0 * v0 + v1 * v1, sh);
    float mean = sum * (1.f / Hc);
    float var  = sq * (1.f / Hc) - mean * mean;
    float inv  = rsqrtf(var + 1e-5f);
    float* zr = z + (size_t)r * Hc;
    zr[t]       = (v0 - mean) * inv * g[t]       + b[t];
    zr[t + 256] = (v1 - mean) * inv * g[t + 256] + b[t + 256];
}

// ---------------- weight-gen stats ----------------
// Split each (b,r) reduction over WGS_SPLIT blocks; partials accumulate via atomicAdd
// into zeroed MASS/DOT/NRMP/NRMC (raw sums; sqrt applied downstream in wg_sw_k).
// grid: (Bc*(Pc+1), WGS_SPLIT). Was 128 blocks (0.5/CU, 254 GB/s); now 2048 blocks.
__global__ __launch_bounds__(256) void wg_stats_k(const float* __restrict__ pri,
                                                  const float* __restrict__ conn,
                                                  float* __restrict__ mass, float* __restrict__ dot,
                                                  float* __restrict__ nrmp, float* __restrict__ nrmc) {
    __shared__ float sh[4];
    int bp = blockIdx.x;
    int sp = blockIdx.y;
    int b = bp >> 2, r = bp & 3;   // P+1 == 4
    const int per = (NNc + WGS_SPLIT - 1) / WGS_SPLIT;   // 8978
    int i0 = sp * per;
    int i1 = i0 + per; if (i1 > NNc) i1 = NNc;
    const float* c = conn + (size_t)b * NNc;
    if (r < Pc) {
        const float* p = pri + (size_t)(b * Pc + r) * NNc;
        float sa = 0, sq = 0, sd = 0;
        for (int i = i0 + threadIdx.x; i < i1; i += 256) {
            float pv = p[i], cv = c[i];
            sa += fabsf(pv); sq += pv * pv; sd += pv * cv;
        }
        sa = blk_sum(sa, sh);
        sq = blk_sum(sq, sh);
        sd = blk_sum(sd, sh);
        if (threadIdx.x == 0) {
            atomicAdd(&mass[b * Pc + r], sa);
            atomicAdd(&nrmp[b * Pc + r], sq);   // raw sum-of-squares
            atomicAdd(&dot[b * Pc + r], sd);
        }
    } else {
        float sq = 0;
        for (int i = i0 + threadIdx.x; i < i1; i += 256) { float cv = c[i]; sq += cv * cv; }
        sq = blk_sum(sq, sh);
        if (threadIdx.x == 0) atomicAdd(&nrmc[b], sq);  // raw sum-of-squares
    }
}

__global__ void wg_sw_k(const float* mass, const float* dot, const float* nrmp, const float* nrmc,
                        float* sw, float* invm) {
    int b = threadIdx.x;
    if (b >= Bc) return;
    float nc = fmaxf(sqrtf(nrmc[b]), 1e-12f);
    float s[Pc];
    for (int p = 0; p < Pc; p++) s[p] = dot[b * Pc + p] / (nc * fmaxf(sqrtf(nrmp[b * Pc + p]), 1e-12f));
    float m = fmaxf(s[0], fmaxf(s[1], s[2]));
    float e[Pc], sum = 0;
    for (int p = 0; p < Pc; p++) { e[p] = expf(s[p] - m); sum += e[p]; }
    for (int p = 0; p < Pc; p++) {
        sw[b * Pc + p] = e[p] / sum;
        invm[b * Pc + p] = 1.f / mass[b * Pc + p];
    }
}

__global__ void fused_nh_k(const float* __restrict__ PEc, const float* __restrict__ swp,
                           float* __restrict__ FNp, size_t count) {
    size_t idx = (size_t)blockIdx.x * blockDim.x + threadIdx.x;
    if (idx >= count) return;
    int bl = (int)(idx / NH_f);
    size_t within = idx % NH_f;
    const float* sw = swp + bl * Pc;
    size_t base = (size_t)bl * Pc * NH_f + within;
    FNp[idx] = sw[0] * PEc[base] + sw[1] * PEc[base + NH_f] + sw[2] * PEc[base + 2 * NH_f];
}

// ---------------- tokens: mean over N, split for parallelism ----------------
// Stage 1: grid (CB*Pc, TSPLIT), each block sums ~24 rows -> TOKP[bp][sp][h].
// Stage 2: grid (CB*Pc), sums TSPLIT partials -> TOK. Deterministic (no atomics).
__global__ __launch_bounds__(512) void tokens_part_k(const float* __restrict__ F2,
                                                     float* __restrict__ TOKP) {
    int bp = blockIdx.x, sp = blockIdx.y, h = threadIdx.x;
    const int rows = (Nc + TSPLIT - 1) / TSPLIT;   // 24
    int n0 = sp * rows;
    int n1 = n0 + rows; if (n1 > Nc) n1 = Nc;
    const float* base = F2 + (size_t)bp * NH_f + h;
    float s = 0;
    for (int n = n0; n < n1; n++) s += base[(size_t)n * Hc];
    TOKP[((size_t)bp * TSPLIT + sp) * Hc + h] = s;
}

__global__ __launch_bounds__(512) void tokens_red_k(const float* __restrict__ TOKP,
                                                    float* __restrict__ TOK) {
    int bp = blockIdx.x, h = threadIdx.x;
    float s = 0;
#pragma unroll
    for (int sp = 0; sp < TSPLIT; sp++) s += TOKP[((size_t)bp * TSPLIT + sp) * Hc + h];
    TOK[(size_t)bp * Hc + h] = s * (1.0f / (float)Nc);
}

__global__ __launch_bounds__(64) void wg_attn_k(const float* __restrict__ QW,
                                                float* __restrict__ aw_out, float* __restrict__ msum) {
    int b = blockIdx.x, lane = threadIdx.x;
    float s[4][Pc][Pc];
    for (int h = 0; h < 4; h++)
        for (int i = 0; i < Pc; i++)
            for (int j = 0; j < Pc; j++) {
                const float* q = QW + (size_t)(b * Pc + i) * 1536 + h * 128;
                const float* k = QW + (size_t)(b * Pc + j) * 1536 + 512 + h * 128;
                float p = q[lane] * k[lane] + q[lane + 64] * k[lane + 64];
#pragma unroll
                for (int off = 32; off; off >>= 1) p += __shfl_xor(p, off, 64);
                s[h][i][j] = p * 0.08838834764831845f;  // 1/sqrt(128)
            }
    float aw[Pc] = {0, 0, 0};
    for (int h = 0; h < 4; h++)
        for (int i = 0; i < Pc; i++) {
            float m = fmaxf(s[h][i][0], fmaxf(s[h][i][1], s[h][i][2]));
            float e0 = expf(s[h][i][0] - m), e1 = expf(s[h][i][1] - m), e2 = expf(s[h][i][2] - m);
            float inv = 1.f / (e0 + e1 + e2);
            aw[0] += e0 * inv; aw[1] += e1 * inv; aw[2] += e2 * inv;
        }
    for (int j = 0; j < Pc; j++) aw[j] *= (1.f / 12.f);
    float m2 = fmaxf(aw[0], fmaxf(aw[1], aw[2]));
    float e0 = expf((aw[0] - m2) * 100.f), e1 = expf((aw[1] - m2) * 100.f), e2 = expf((aw[2] - m2) * 100.f);
    float inv = 1.f / (e0 + e1 + e2);
    if (lane == 0) {
        aw_out[b * Pc + 0] = e0 * inv;
        aw_out[b * Pc + 1] = e1 * inv;
        aw_out[b * Pc + 2] = e2 * inv;
        msum[b] = (e0 + e1 + e2) * inv;
    }
}

// ---------------- flash attention: block = (32 queries, head, batch-local) ----------------
// thread t: q = t>>3 (0..31), sub = t&7. Per-thread state: acc[8] (d-slice sub*8..+7), m, l.
// K/V staged per 64-j tile; exp weights round-trip through Es. ld=66 keeps all LDS reads <=2-way.
#define AQT 32
__global__ __launch_bounds__(256) void fattn_k(const float* __restrict__ QKVc,
                                               const float* __restrict__ conn,
                                               const float* __restrict__ msum,
                                               const float* __restrict__ alpha,
                                               int b0, float* __restrict__ ctx) {
    __shared__ float Qs[AQT][66];
    __shared__ float Ks[64][66];
    __shared__ float Vs[64][66];
    __shared__ float Es[AQT][66];
    int i0 = blockIdx.x * AQT;
    int h = blockIdx.y, bl = blockIdx.z;
    int b = b0 + bl;
    int t = threadIdx.x;
    int q = t >> 3, sub = t & 7;
    int gi = i0 + q;
    float a2 = 0.5f * alpha[0];
    float mterm = a2 * msum[b];
    // stage Q tile (replicate last row for OOB; outputs guarded)
    {
        int src_row = (gi < Nc) ? gi : (Nc - 1);
        int d0 = sub * 8;
        const float* src = QKVc + ((size_t)bl * Nc + src_row) * 1536 + h * HDc + d0;
        *(float4*)&Qs[q][d0]     = *(const float4*)src;
        *(float4*)&Qs[q][d0 + 4] = *(const float4*)(src + 4);
    }
    const float* Crow = conn + ((size_t)b * Nc + (gi < Nc ? gi : Nc - 1)) * Nc;
    float m_run = -3.4e38f, l_run = 0.f;
    float acc[8] = {0.f, 0.f, 0.f, 0.f, 0.f, 0.f, 0.f, 0.f};

    for (int jt = 0; jt < 6; jt++) {
        __syncthreads();   // protect LDS reuse across iterations (also covers Q staging, iter 0)
        {   // stage K + V tiles 64x64
            int j = t >> 2, d0 = (t & 3) * 16;
            int gj = jt * 64 + j;
            int sr = (gj < Nc) ? gj : (Nc - 1);
            const float* kp = QKVc + ((size_t)bl * Nc + sr) * 1536 + Hc + h * HDc + d0;
            const float* vp = kp + Hc;
            *(float4*)&Ks[j][d0]      = *(const float4*)(kp);
            *(float4*)&Ks[j][d0 + 4]  = *(const float4*)(kp + 4);
            *(float4*)&Ks[j][d0 + 8]  = *(const float4*)(kp + 8);
            *(float4*)&Ks[j][d0 + 12] = *(const float4*)(kp + 12);
            *(float4*)&Vs[j][d0]      = *(const float4*)(vp);
            *(float4*)&Vs[j][d0 + 4]  = *(const float4*)(vp + 4);
            *(float4*)&Vs[j][d0 + 8]  = *(const float4*)(vp + 8);
            *(float4*)&Vs[j][d0 + 12] = *(const float4*)(vp + 12);
        }
        __syncthreads();
        // scores: 8 j's per thread (j = sub + 8*jj)
        float s[8] = {0.f, 0.f, 0.f, 0.f, 0.f, 0.f, 0.f, 0.f};
#pragma unroll 4
        for (int d4 = 0; d4 < 16; d4++) {
            float4 qv = *(float4*)&Qs[q][d4 * 4];
#pragma unroll
            for (int jj = 0; jj < 8; jj++) {
                float4 kv = *(float4*)&Ks[sub + 8 * jj][d4 * 4];
                s[jj] += qv.x * kv.x + qv.y * kv.y + qv.z * kv.z + qv.w * kv.w;
            }
        }
        float tile_max = -3.4e38f;
#pragma unroll
        for (int jj = 0; jj < 8; jj++) {
            int gj = jt * 64 + sub + 8 * jj;
            if (gj < Nc && gi < Nc) {
                float mk = tanhf(mterm + (1.f - a2) * Crow[gj]);
                s[jj] = s[jj] * 0.125f * (1.f + mk);
            } else s[jj] = -3.4e38f;
            tile_max = fmaxf(tile_max, s[jj]);
        }
#pragma unroll
        for (int off = 1; off < 8; off <<= 1)
            tile_max = fmaxf(tile_max, __shfl_xor(tile_max, off, 64));
        float m_new = fmaxf(m_run, tile_max);
        float esum = 0.f;
#pragma unroll
        for (int jj = 0; jj < 8; jj++) {
            float e = __expf(s[jj] - m_new);
            Es[q][sub + 8 * jj] = e;
            esum += e;
        }
#pragma unroll
        for (int off = 1; off < 8; off <<= 1)
            esum += __shfl_xor(esum, off, 64);
        float scl = __expf(m_run - m_new);
        l_run = l_run * scl + esum;
        m_run = m_new;
        __syncthreads();  // Es visible
        // PV: thread d-slice d0 = sub*8
#pragma unroll
        for (int dd = 0; dd < 8; dd++) acc[dd] *= scl;
        int d0 = sub * 8;
#pragma unroll 4
        for (int j4 = 0; j4 < 16; j4++) {
            float4 ev = *(float4*)&Es[q][j4 * 4];
#pragma unroll
            for (int u = 0; u < 4; u++) {
                float e = (u == 0) ? ev.x : (u == 1) ? ev.y : (u == 2) ? ev.z : ev.w;
                float4 v0 = *(float4*)&Vs[j4 * 4 + u][d0];
                float4 v1 = *(float4*)&Vs[j4 * 4 + u][d0 + 4];
                acc[0] += e * v0.x; acc[1] += e * v0.y; acc[2] += e * v0.z; acc[3] += e * v0.w;
                acc[4] += e * v1.x; acc[5] += e * v1.y; acc[6] += e * v1.z; acc[7] += e * v1.w;
            }
        }
    }
    if (gi < Nc) {
        float inv = 1.f / l_run;
        float* dst = ctx + ((size_t)b * Nc + gi) * Hc + h * HDc + sub * 8;
        float4 o0 = make_float4(acc[0] * inv, acc[1] * inv, acc[2] * inv, acc[3] * inv);
        float4 o1 = make_float4(acc[4] * inv, acc[5] * inv, acc[6] * inv, acc[7] * inv);
        *(float4*)dst = o0;
        *(float4*)(dst + 4) = o1;
    }
}

__global__ void add3_k(const float* __restrict__ x, float* __restrict__ ctx,
                       const float* __restrict__ fn, size_t count) {
    size_t idx = (size_t)blockIdx.x * blockDim.x + threadIdx.x;
    if (idx >= count) return;
    ctx[idx] = x[idx] + ctx[idx] + fn[idx];
}

__global__ void final_k(const float* __restrict__ AO, const float* __restrict__ FF,
                        const float* __restrict__ dw,
                        float* __restrict__ xout, float* __restrict__ proj, size_t count) {
    size_t idx = (size_t)blockIdx.x * blockDim.x + threadIdx.x;
    if (idx >= count) return;
    float w = dw[0];
    float ff = FF[idx];
    float xn = AO[idx] + ff;
    xout[idx] = xn;
    proj[idx] = w * ff + (1.f - w) * xn;
}

__global__ __launch_bounds__(256) void final_kl_k(const float* __restrict__ AO,
                                                  const float* __restrict__ FF,
                                                  const float* __restrict__ dw,
                                                  const float* __restrict__ PF,
                                                  float* __restrict__ xout,
                                                  float* __restrict__ acc) {
    __shared__ float sh[4];
    int r = blockIdx.x, t = threadIdx.x;
    size_t base = (size_t)r * Hc;
    float w = dw[1];
    float ff0 = FF[base + t], ff1 = FF[base + t + 256];
    float ao0 = AO[base + t], ao1 = AO[base + t + 256];
    float xn0 = ao0 + ff0, xn1 = ao1 + ff1;
    xout[base + t] = xn0;
    xout[base + t + 256] = xn1;
    float s0 = w * ff0 + (1.f - w) * xn0;
    float s1 = w * ff1 + (1.f - w) * xn1;
    float f0 = PF[base + t], f1 = PF[base + t + 256];
    float mf = blk_max(fmaxf(f0, f1), sh);
    float ms = blk_max(fmaxf(s0, s1), sh);
    float ef = expf(f0 - mf) + expf(f1 - mf);
    float es = expf(s0 - ms) + expf(s1 - ms);
    float sf = blk_sum(ef, sh);
    float ss = blk_sum(es, sh);
    float lsef = mf + logf(sf), lses = ms + logf(ss);
    float lf0 = f0 - lsef, lf1 = f1 - lsef, ls0 = s0 - lses, ls1 = s1 - lses;
    float tsum = expf(ls0) * (ls0 - lf0) + expf(ls1) * (ls1 - lf1)
               + expf(lf0) * (lf0 - ls0) + expf(lf1) * (lf1 - ls1);
    tsum = blk_sum(tsum, sh);
    if (t == 0) atomicAdd(acc, tsum);
}

__global__ void kl_final_k(const float* __restrict__ acc, float* __restrict__ out) {
    out[0] = 0.5f * acc[0] * (1.0f / (float)ROWS_BN);
}

// ---------------- launch ----------------
extern "C" void kernel_launch(void* const* d_in, const int* in_sizes, int n_in,
                              void* d_out, int out_size, void* d_ws, size_t ws_size,
                              hipStream_t stream) {
    (void)in_sizes; (void)n_in; (void)out_size; (void)ws_size;
    const float* x[2]    = {(const float*)d_in[0], (const float*)d_in[1]};
    const float* pri[2]  = {(const float*)d_in[2], (const float*)d_in[3]};
    const float* conn[2] = {(const float*)d_in[4], (const float*)d_in[5]};
    const float* dw      = (const float*)d_in[6];
    const float* wqkv[2] = {(const float*)d_in[7], (const float*)d_in[8]};
    const float* ln_g    = (const float*)d_in[9];
    const float* ln_b    = (const float*)d_in[10];
    const float* ffn_w1  = (const float*)d_in[11];
    const float* ffn_b1  = (const float*)d_in[12];
    const float* ffn_w2  = (const float*)d_in[13];
    const float* ffn_b2  = (const float*)d_in[14];
    const float* pw      = (const float*)d_in[15];
    const float* pb      = (const float*)d_in[16];
    const float* f1w     = (const float*)d_in[17];
    const float* f1b     = (const float*)d_in[18];
    const float* f2w     = (const float*)d_in[19];
    const float* f2b     = (const float*)d_in[20];
    const float* ipw     = (const float*)d_in[21];
    const float* ipb     = (const float*)d_in[22];
    const float* alpha   = (const float*)d_in[23];
    float* out = (float*)d_out;

    // --- workspace arena (~150 MB) ---
    float* W = (float*)d_ws;
    size_t o = 0;
    auto alloc = [&](size_t n) { float* p = W + o; o += n; return p; };
    float* Z     = alloc(BNH);
    float* CTX   = alloc(BNH);
    float* FN    = alloc(BNH);
    float* PROJ0 = alloc(BNH);
    float* R     = alloc(12417024);          // shared transient region
    float* TOK   = alloc((size_t)96 * Hc);
    float* QKVWG = alloc((size_t)96 * 1536);
    float* MASS  = alloc(96); float* DOT = alloc(96); float* NRMP = alloc(96);
    float* NRMC  = alloc(32); float* SW  = alloc(96); float* INVM = alloc(96);
    float* MSUM  = alloc(32);
    float* KLACC = alloc(1);

    // R overlays (disjoint lifetimes; same-stream ordering serializes):
    float* PEc  = R;                          // 4,657,152
    float* H1c  = R + PEC_SZ;                 // 4,657,152
    float* ZFc  = R + 2 * PEC_SZ;             // 1,552,384
    float* QKVc = R;                          // 4,657,152
    float* HIDc = R;                          // 6,209,536
    float* FFNOUT = R + HIDC_SZ;              // 6,207,488
    // tokens partial buffer: lives in H1c region (free after bgemm<1> of each chunk)
    float* TOKP = H1c;                        // 24*TSPLIT*512 = 196,608 floats

    const size_t OUT_DISTILL = 2 * BNH;
    const size_t OUT_AW = 2 * BNH + 1;

    hipMemsetAsync(KLACC, 0, sizeof(float), stream);

    int eb = 256;
    int gBNH = (int)((BNH + eb - 1) / eb);
    int gCHK = (int)((CHUNK_NH + eb - 1) / eb);

    for (int s = 0; s < 2; s++) {
        ln_k<<<ROWS_BN, 256, 0, stream>>>(x[s], ln_g + s * Hc, ln_b + s * Hc, Z);
        // zero MASS/DOT/NRMP/NRMC (contiguous 320 floats) for split-atomic accumulation
        hipMemsetAsync(MASS, 0, 320 * sizeof(float), stream);
        wg_stats_k<<<dim3(Bc * (Pc + 1), WGS_SPLIT), 256, 0, stream>>>(
            pri[s], conn[s], MASS, DOT, NRMP, NRMC);
        wg_sw_k<<<1, 64, 0, stream>>>(MASS, DOT, NRMP, NRMC, SW, INVM);

        // ---- weight-gen pipeline, chunked over batches ----
        for (int c = 0; c < NCHUNK; c++) {
            const float* pric = pri[s] + (size_t)c * ROWS_WG * Nc;
            launch_bgemm<0>(Z + (size_t)c * ROWS_CHUNK * Hc, f1w + (size_t)Hc * Hc, ZFc,
                            ROWS_CHUNK, Hc, Hc, nullptr, nullptr, 0, nullptr, 0, 0, stream);
            launch_bgemm<4>(pric, pw, PEc, ROWS_WG, Hc, Nc, pb, INVM + c * CB * Pc, Nc,
                            nullptr, 0, 0, stream);
            fused_nh_k<<<gCHK, eb, 0, stream>>>(PEc, SW + c * CB * Pc, FN + (size_t)c * CHUNK_NH, CHUNK_NH);
            launch_bgemm<3>(PEc, f1w, H1c, ROWS_WG, Hc, Hc, f1b, nullptr, 0, ZFc, Pc, Nc, stream);
            launch_bgemm<1>(H1c, f2w, PEc, ROWS_WG, Hc, Hc, f2b, nullptr, 0, nullptr, 0, 0, stream);
            // tokens: split over n for parallelism (H1c free here; reused as partial buffer)
            tokens_part_k<<<dim3(CB * Pc, TSPLIT), 512, 0, stream>>>(PEc, TOKP);
            tokens_red_k<<<CB * Pc, 512, 0, stream>>>(TOKP, TOK + (size_t)c * CB * Pc * Hc);
        }
        launch_bgemm<1>(TOK, ipw, QKVWG, Bc * Pc, 3 * Hc, Hc, ipb, nullptr, 0, nullptr, 0, 0, stream);
        wg_attn_k<<<Bc, 64, 0, stream>>>(QKVWG, out + OUT_AW + (size_t)s * (Bc * Pc), MSUM);

        // ---- main attention, chunked over batches ----
        for (int c = 0; c < NCHUNK; c++) {
            launch_bgemm<0>(Z + (size_t)c * ROWS_CHUNK * Hc, wqkv[s], QKVc,
                            ROWS_CHUNK, 3 * Hc, Hc, nullptr, nullptr, 0, nullptr, 0, 0, stream);
            fattn_k<<<dim3((Nc + AQT - 1) / AQT, NHc, CB), 256, 0, stream>>>(
                QKVc, conn[s], MSUM, alpha, c * CB, CTX);
        }
        add3_k<<<gBNH, eb, 0, stream>>>(x[s], CTX, FN, BNH);

        // ---- FFN, chunked rows ----
        ln_k<<<ROWS_BN, 256, 0, stream>>>(CTX, ln_g + (2 + s) * Hc, ln_b + (2 + s) * Hc, Z);
        for (int c = 0; c < NCHUNK; c++) {
            launch_bgemm<2>(Z + (size_t)c * ROWS_CHUNK * Hc, ffn_w1 + (size_t)s * Hc * 4 * Hc, HIDc,
                            ROWS_CHUNK, 4 * Hc, Hc, ffn_b1 + (size_t)s * 4 * Hc,
                            nullptr, 0, nullptr, 0, 0, stream);
            launch_bgemm<1>(HIDc, ffn_w2 + (size_t)s * 4 * Hc * Hc, FFNOUT + (size_t)c * ROWS_CHUNK * Hc,
                            ROWS_CHUNK, Hc, 4 * Hc, ffn_b2 + (size_t)s * Hc,
                            nullptr, 0, nullptr, 0, 0, stream);
        }
        if (s == 0) {
            final_k<<<gBNH, eb, 0, stream>>>(CTX, FFNOUT, dw, out, PROJ0, BNH);
        } else {
            final_kl_k<<<ROWS_BN, 256, 0, stream>>>(CTX, FFNOUT, dw, PROJ0, out + BNH, KLACC);
        }
    }
    kl_final_k<<<1, 1, 0, stream>>>(KLACC, out + OUT_DISTILL);
}

// Round 2
// 6939.191 us; speedup vs baseline: 1.0968x; 1.0804x over previous
//
#include <hip/hip_runtime.h>
#include <math.h>

// ---------------- constants ----------------
#define Bc   32
#define Nc   379
#define Hc   512
#define NHc  8
#define Pc   3
#define HDc  64          // H/NH
#define NNc  (Nc*Nc)     // 143641
#define CB   8           // batch chunk
#define NCHUNK 4
static const size_t NH_f  = (size_t)Nc*Hc;           // 194,048
static const size_t BNH   = (size_t)Bc*Nc*Hc;        // 6,207,488
#define ROWS_BN   12128   // B*N
#define ROWS_CHUNK 3032   // CB*N
#define ROWS_WG    9096   // CB*P*N
static const size_t CHUNK_NH = (size_t)CB*Nc*Hc;     // 1,552,384
static const size_t PEC_SZ   = (size_t)ROWS_WG*Hc;   // 4,657,152
static const size_t HIDC_SZ  = (size_t)ROWS_CHUNK*4*Hc; // 6,209,536

#define WGS_SPLIT 16     // blocks per (b,r) row in wg_stats
#define TSPLIT 16        // n-splits in tokens reduction
#define KPAD 384         // pri K (379) padded to multiple of BK, 16B-aligned rows

typedef __attribute__((ext_vector_type(8))) short bf16x8;
typedef __attribute__((ext_vector_type(4))) float f32x4;

__device__ inline float gelu_f(float x) {
    return 0.5f * x * (1.0f + erff(x * 0.7071067811865476f));
}

// fp32 -> bf16 bits, round-to-nearest-even
__device__ inline short f2bf(float f) {
    unsigned u = __float_as_uint(f);
    unsigned r = u + 0x7fffu + ((u >> 16) & 1u);
    return (short)(r >> 16);
}

// block reductions (blockDim == 256)
__device__ inline float blk_sum(float v, float* sh) {
#pragma unroll
    for (int off = 32; off; off >>= 1) v += __shfl_xor(v, off, 64);
    int w = threadIdx.x >> 6;
    __syncthreads();
    if ((threadIdx.x & 63) == 0) sh[w] = v;
    __syncthreads();
    return sh[0] + sh[1] + sh[2] + sh[3];
}
__device__ inline float blk_max(float v, float* sh) {
#pragma unroll
    for (int off = 32; off; off >>= 1) v = fmaxf(v, __shfl_xor(v, off, 64));
    int w = threadIdx.x >> 6;
    __syncthreads();
    if ((threadIdx.x & 63) == 0) sh[w] = v;
    __syncthreads();
    return fmaxf(fmaxf(sh[0], sh[1]), fmaxf(sh[2], sh[3]));
}

// ---------------- bf16 MFMA GEMM ----------------
// C(M,N) = A(M,K)@B(K,N), A,B fp32 in global, converted to bf16 in LDS, fp32 acc.
// Requires N % 128 == 0. M,K arbitrary (guarded / zero-padded).
// Epilogues: 0 none; 1 +bias; 2 gelu(+bias); 3 gelu(+bias + addsrc P-broadcast); 4 *rowscale[row/rs_div]+bias
#define BM 128
#define BN 128
#define BK 32
#define LDK 40   // padded k-stride (bf16 elems)

template<int EPI>
__global__ __launch_bounds__(256) void bgemm_k(
    const float* __restrict__ A, const float* __restrict__ B, float* __restrict__ C,
    int M, int N, int K,
    const float* __restrict__ bias,
    const float* __restrict__ rowscale, int rs_div,
    const float* __restrict__ addsrc, int addP, int addN)
{
    __shared__ __attribute__((aligned(16))) short As[BM * LDK];
    __shared__ __attribute__((aligned(16))) short Bs[BN * LDK];
    int tid = threadIdx.x;
    int wave = tid >> 6, lane = tid & 63;
    int wr = wave >> 1, wc = wave & 1;         // 2x2 waves, each 64x64
    int m0 = blockIdx.y * BM, n0 = blockIdx.x * BN;
    int quad = lane >> 4, l16 = lane & 15;
    bool k_vec = ((K & 3) == 0);

    f32x4 acc[4][4] = {};

    for (int k0 = 0; k0 < K; k0 += BK) {
        // ---- stage A tile: 128 x 32, fp32 -> bf16 ----
        {
            int row = tid >> 3;            // 0..31
            int kk  = (tid & 7) * 4;       // 0..28
#pragma unroll
            for (int rr = 0; rr < 4; rr++) {
                int m = row + rr * 32;
                int gm = m0 + m;
                float4 v = make_float4(0.f, 0.f, 0.f, 0.f);
                if (gm < M) {
                    int gk = k0 + kk;
                    const float* src = A + (size_t)gm * K + gk;
                    if (k_vec && gk + 3 < K) v = *(const float4*)src;
                    else {
                        if (gk     < K) v.x = src[0];
                        if (gk + 1 < K) v.y = src[1];
                        if (gk + 2 < K) v.z = src[2];
                        if (gk + 3 < K) v.w = src[3];
                    }
                }
                short* dst = &As[m * LDK + kk];
                dst[0] = f2bf(v.x); dst[1] = f2bf(v.y);
                dst[2] = f2bf(v.z); dst[3] = f2bf(v.w);
            }
        }
        // ---- stage B tile transposed: Bs[n][k], 128 n x 32 k ----
        {
            int kk = tid >> 5;             // 0..7
            int nn = (tid & 31) * 4;       // 0..124
#pragma unroll
            for (int rr = 0; rr < 4; rr++) {
                int k = kk + rr * 8;
                int gk = k0 + k;
                float4 v = make_float4(0.f, 0.f, 0.f, 0.f);
                if (gk < K) v = *(const float4*)(B + (size_t)gk * N + n0 + nn);
                Bs[(nn + 0) * LDK + k] = f2bf(v.x);
                Bs[(nn + 1) * LDK + k] = f2bf(v.y);
                Bs[(nn + 2) * LDK + k] = f2bf(v.z);
                Bs[(nn + 3) * LDK + k] = f2bf(v.w);
            }
        }
        __syncthreads();
        bf16x8 afr[4], bfr[4];
#pragma unroll
        for (int mt = 0; mt < 4; mt++)
            afr[mt] = *(const bf16x8*)&As[(wr * 64 + mt * 16 + l16) * LDK + quad * 8];
#pragma unroll
        for (int nt = 0; nt < 4; nt++)
            bfr[nt] = *(const bf16x8*)&Bs[(wc * 64 + nt * 16 + l16) * LDK + quad * 8];
#pragma unroll
        for (int mt = 0; mt < 4; mt++)
#pragma unroll
            for (int nt = 0; nt < 4; nt++)
                acc[mt][nt] = __builtin_amdgcn_mfma_f32_16x16x32_bf16(
                    afr[mt], bfr[nt], acc[mt][nt], 0, 0, 0);
        __syncthreads();
    }
    // ---- epilogue: C/D layout col=lane&15, row=quad*4+reg ----
#pragma unroll
    for (int mt = 0; mt < 4; mt++) {
#pragma unroll
        for (int nt = 0; nt < 4; nt++) {
#pragma unroll
            for (int r = 0; r < 4; r++) {
                int gm = m0 + wr * 64 + mt * 16 + quad * 4 + r;
                int gn = n0 + wc * 64 + nt * 16 + l16;
                if (gm < M) {
                    float v = acc[mt][nt][r];
                    if (EPI == 1 || EPI == 2 || EPI == 3) v += bias[gn];
                    if (EPI == 4) v = v * rowscale[gm / rs_div] + bias[gn];
                    if (EPI == 3) {
                        int addrow = (gm / (addP * addN)) * addN + (gm % addN);
                        v += addsrc[(size_t)addrow * N + gn];
                    }
                    if (EPI == 2 || EPI == 3) v = gelu_f(v);
                    C[(size_t)gm * N + gn] = v;
                }
            }
        }
    }
}

template<int EPI>
static void launch_bgemm(const float* A, const float* B, float* C, int M, int N, int K,
                         const float* bias, const float* rowscale, int rs_div,
                         const float* addsrc, int addP, int addN, hipStream_t st) {
    dim3 grid(N / 128, (M + 127) / 128);
    bgemm_k<EPI><<<grid, 256, 0, st>>>(A, B, C, M, N, K, bias, rowscale, rs_div, addsrc, addP, addN);
}

// ---------------- pri pre-pack: fp32 [rows][379] -> bf16 [rows][384] (zero pad) ----------------
__global__ __launch_bounds__(256) void pack_pri_k(const float* __restrict__ src,
                                                  short* __restrict__ dst, int rows) {
    int idx = blockIdx.x * blockDim.x + threadIdx.x;
    int total = rows * (KPAD / 8);
    if (idx >= total) return;
    int row = idx / (KPAD / 8);
    int c8  = (idx % (KPAD / 8)) * 8;
    const float* s = src + (size_t)row * Nc + c8;
    bf16x8 v;
#pragma unroll
    for (int j = 0; j < 8; j++) v[j] = (c8 + j < Nc) ? f2bf(s[j]) : (short)0;
    *(bf16x8*)(dst + (size_t)row * KPAD + c8) = v;
}

// ---------------- packed-A bf16 GEMM, EPI4 epilogue (v*rowscale[gm/rs_div]+bias) ----------------
// A: bf16 [M][KPAD], zero-padded cols KB..KPAD-1. B: fp32 [KB][N]. N%128==0.
__global__ __launch_bounds__(256) void bgemm_pa_k(
    const short* __restrict__ Ab, const float* __restrict__ B, float* __restrict__ C,
    int M, int N, int KB,
    const float* __restrict__ bias, const float* __restrict__ rowscale, int rs_div)
{
    __shared__ __attribute__((aligned(16))) short As[BM * LDK];
    __shared__ __attribute__((aligned(16))) short Bs[BN * LDK];
    int tid = threadIdx.x;
    int wave = tid >> 6, lane = tid & 63;
    int wr = wave >> 1, wc = wave & 1;
    int m0 = blockIdx.y * BM, n0 = blockIdx.x * BN;
    int quad = lane >> 4, l16 = lane & 15;

    f32x4 acc[4][4] = {};

    for (int k0 = 0; k0 < KPAD; k0 += BK) {
        // ---- stage A tile: 128 x 32 bf16, two unguarded 16B copies per thread ----
#pragma unroll
        for (int u = 0; u < 2; u++) {
            int ch = tid * 2 + u;          // 0..511
            int m = ch >> 2, cc = ch & 3;  // row 0..127, col-chunk 0..3
            int gm = m0 + m;
            bf16x8 v = {0, 0, 0, 0, 0, 0, 0, 0};
            if (gm < M) v = *(const bf16x8*)(Ab + (size_t)gm * KPAD + k0 + cc * 8);
            *(bf16x8*)&As[m * LDK + cc * 8] = v;
        }
        // ---- stage B tile transposed: Bs[n][k] ----
        {
            int kk = tid >> 5;
            int nn = (tid & 31) * 4;
#pragma unroll
            for (int rr = 0; rr < 4; rr++) {
                int k = kk + rr * 8;
                int gk = k0 + k;
                float4 v = make_float4(0.f, 0.f, 0.f, 0.f);
                if (gk < KB) v = *(const float4*)(B + (size_t)gk * N + n0 + nn);
                Bs[(nn + 0) * LDK + k] = f2bf(v.x);
                Bs[(nn + 1) * LDK + k] = f2bf(v.y);
                Bs[(nn + 2) * LDK + k] = f2bf(v.z);
                Bs[(nn + 3) * LDK + k] = f2bf(v.w);
            }
        }
        __syncthreads();
        bf16x8 afr[4], bfr[4];
#pragma unroll
        for (int mt = 0; mt < 4; mt++)
            afr[mt] = *(const bf16x8*)&As[(wr * 64 + mt * 16 + l16) * LDK + quad * 8];
#pragma unroll
        for (int nt = 0; nt < 4; nt++)
            bfr[nt] = *(const bf16x8*)&Bs[(wc * 64 + nt * 16 + l16) * LDK + quad * 8];
#pragma unroll
        for (int mt = 0; mt < 4; mt++)
#pragma unroll
            for (int nt = 0; nt < 4; nt++)
                acc[mt][nt] = __builtin_amdgcn_mfma_f32_16x16x32_bf16(
                    afr[mt], bfr[nt], acc[mt][nt], 0, 0, 0);
        __syncthreads();
    }
#pragma unroll
    for (int mt = 0; mt < 4; mt++) {
#pragma unroll
        for (int nt = 0; nt < 4; nt++) {
#pragma unroll
            for (int r = 0; r < 4; r++) {
                int gm = m0 + wr * 64 + mt * 16 + quad * 4 + r;
                int gn = n0 + wc * 64 + nt * 16 + l16;
                if (gm < M) {
                    float v = acc[mt][nt][r] * rowscale[gm / rs_div] + bias[gn];
                    C[(size_t)gm * N + gn] = v;
                }
            }
        }
    }
}

// ---------------- LayerNorm (rows of 512) ----------------
__global__ __launch_bounds__(256) void ln_k(const float* __restrict__ x,
                                            const float* __restrict__ g,
                                            const float* __restrict__ b,
                                            float* __restrict__ z) {
    __shared__ float sh[4];
    int r = blockIdx.x, t = threadIdx.x;
    const float* xr = x + (size_t)r * Hc;
    float v0 = xr[t], v1 = xr[t + 256];
    float sum = blk_sum(v0 + v1, sh);
    float sq  = blk_sum(v0 * v0 + v1 * v1, sh);
    float mean = sum * (1.f / Hc);
    float var  = sq * (1.f / Hc) - mean * mean;
    float inv  = rsqrtf(var + 1e-5f);
    float* zr = z + (size_t)r * Hc;
    zr[t]       = (v0 - mean) * inv * g[t]       + b[t];
    zr[t + 256] = (v1 - mean) * inv * g[t + 256] + b[t + 256];
}

// ---------------- weight-gen stats (split + atomic partials) ----------------
__global__ __launch_bounds__(256) void wg_stats_k(const float* __restrict__ pri,
                                                  const float* __restrict__ conn,
                                                  float* __restrict__ mass, float* __restrict__ dot,
                                                  float* __restrict__ nrmp, float* __restrict__ nrmc) {
    __shared__ float sh[4];
    int bp = blockIdx.x;
    int sp = blockIdx.y;
    int b = bp >> 2, r = bp & 3;   // P+1 == 4
    const int per = (NNc + WGS_SPLIT - 1) / WGS_SPLIT;   // 8978
    int i0 = sp * per;
    int i1 = i0 + per; if (i1 > NNc) i1 = NNc;
    const float* c = conn + (size_t)b * NNc;
    if (r < Pc) {
        const float* p = pri + (size_t)(b * Pc + r) * NNc;
        float sa = 0, sq = 0, sd = 0;
        for (int i = i0 + threadIdx.x; i < i1; i += 256) {
            float pv = p[i], cv = c[i];
            sa += fabsf(pv); sq += pv * pv; sd += pv * cv;
        }
        sa = blk_sum(sa, sh);
        sq = blk_sum(sq, sh);
        sd = blk_sum(sd, sh);
        if (threadIdx.x == 0) {
            atomicAdd(&mass[b * Pc + r], sa);
            atomicAdd(&nrmp[b * Pc + r], sq);   // raw sum-of-squares
            atomicAdd(&dot[b * Pc + r], sd);
        }
    } else {
        float sq = 0;
        for (int i = i0 + threadIdx.x; i < i1; i += 256) { float cv = c[i]; sq += cv * cv; }
        sq = blk_sum(sq, sh);
        if (threadIdx.x == 0) atomicAdd(&nrmc[b], sq);  // raw sum-of-squares
    }
}

__global__ void wg_sw_k(const float* mass, const float* dot, const float* nrmp, const float* nrmc,
                        float* sw, float* invm) {
    int b = threadIdx.x;
    if (b >= Bc) return;
    float nc = fmaxf(sqrtf(nrmc[b]), 1e-12f);
    float s[Pc];
    for (int p = 0; p < Pc; p++) s[p] = dot[b * Pc + p] / (nc * fmaxf(sqrtf(nrmp[b * Pc + p]), 1e-12f));
    float m = fmaxf(s[0], fmaxf(s[1], s[2]));
    float e[Pc], sum = 0;
    for (int p = 0; p < Pc; p++) { e[p] = expf(s[p] - m); sum += e[p]; }
    for (int p = 0; p < Pc; p++) {
        sw[b * Pc + p] = e[p] / sum;
        invm[b * Pc + p] = 1.f / mass[b * Pc + p];
    }
}

__global__ void fused_nh_k(const float* __restrict__ PEc, const float* __restrict__ swp,
                           float* __restrict__ FNp, size_t count) {
    size_t idx = (size_t)blockIdx.x * blockDim.x + threadIdx.x;
    if (idx >= count) return;
    int bl = (int)(idx / NH_f);
    size_t within = idx % NH_f;
    const float* sw = swp + bl * Pc;
    size_t base = (size_t)bl * Pc * NH_f + within;
    FNp[idx] = sw[0] * PEc[base] + sw[1] * PEc[base + NH_f] + sw[2] * PEc[base + 2 * NH_f];
}

// ---------------- tokens: mean over N, split for parallelism ----------------
__global__ __launch_bounds__(512) void tokens_part_k(const float* __restrict__ F2,
                                                     float* __restrict__ TOKP) {
    int bp = blockIdx.x, sp = blockIdx.y, h = threadIdx.x;
    const int rows = (Nc + TSPLIT - 1) / TSPLIT;   // 24
    int n0 = sp * rows;
    int n1 = n0 + rows; if (n1 > Nc) n1 = Nc;
    const float* base = F2 + (size_t)bp * NH_f + h;
    float s = 0;
    for (int n = n0; n < n1; n++) s += base[(size_t)n * Hc];
    TOKP[((size_t)bp * TSPLIT + sp) * Hc + h] = s;
}

__global__ __launch_bounds__(512) void tokens_red_k(const float* __restrict__ TOKP,
                                                    float* __restrict__ TOK) {
    int bp = blockIdx.x, h = threadIdx.x;
    float s = 0;
#pragma unroll
    for (int sp = 0; sp < TSPLIT; sp++) s += TOKP[((size_t)bp * TSPLIT + sp) * Hc + h];
    TOK[(size_t)bp * Hc + h] = s * (1.0f / (float)Nc);
}

__global__ __launch_bounds__(64) void wg_attn_k(const float* __restrict__ QW,
                                                float* __restrict__ aw_out, float* __restrict__ msum) {
    int b = blockIdx.x, lane = threadIdx.x;
    float s[4][Pc][Pc];
    for (int h = 0; h < 4; h++)
        for (int i = 0; i < Pc; i++)
            for (int j = 0; j < Pc; j++) {
                const float* q = QW + (size_t)(b * Pc + i) * 1536 + h * 128;
                const float* k = QW + (size_t)(b * Pc + j) * 1536 + 512 + h * 128;
                float p = q[lane] * k[lane] + q[lane + 64] * k[lane + 64];
#pragma unroll
                for (int off = 32; off; off >>= 1) p += __shfl_xor(p, off, 64);
                s[h][i][j] = p * 0.08838834764831845f;  // 1/sqrt(128)
            }
    float aw[Pc] = {0, 0, 0};
    for (int h = 0; h < 4; h++)
        for (int i = 0; i < Pc; i++) {
            float m = fmaxf(s[h][i][0], fmaxf(s[h][i][1], s[h][i][2]));
            float e0 = expf(s[h][i][0] - m), e1 = expf(s[h][i][1] - m), e2 = expf(s[h][i][2] - m);
            float inv = 1.f / (e0 + e1 + e2);
            aw[0] += e0 * inv; aw[1] += e1 * inv; aw[2] += e2 * inv;
        }
    for (int j = 0; j < Pc; j++) aw[j] *= (1.f / 12.f);
    float m2 = fmaxf(aw[0], fmaxf(aw[1], aw[2]));
    float e0 = expf((aw[0] - m2) * 100.f), e1 = expf((aw[1] - m2) * 100.f), e2 = expf((aw[2] - m2) * 100.f);
    float inv = 1.f / (e0 + e1 + e2);
    if (lane == 0) {
        aw_out[b * Pc + 0] = e0 * inv;
        aw_out[b * Pc + 1] = e1 * inv;
        aw_out[b * Pc + 2] = e2 * inv;
        msum[b] = (e0 + e1 + e2) * inv;
    }
}

// ---------------- flash attention ----------------
#define AQT 32
__global__ __launch_bounds__(256) void fattn_k(const float* __restrict__ QKVc,
                                               const float* __restrict__ conn,
                                               const float* __restrict__ msum,
                                               const float* __restrict__ alpha,
                                               int b0, float* __restrict__ ctx) {
    __shared__ float Qs[AQT][66];
    __shared__ float Ks[64][66];
    __shared__ float Vs[64][66];
    __shared__ float Es[AQT][66];
    int i0 = blockIdx.x * AQT;
    int h = blockIdx.y, bl = blockIdx.z;
    int b = b0 + bl;
    int t = threadIdx.x;
    int q = t >> 3, sub = t & 7;
    int gi = i0 + q;
    float a2 = 0.5f * alpha[0];
    float mterm = a2 * msum[b];
    {
        int src_row = (gi < Nc) ? gi : (Nc - 1);
        int d0 = sub * 8;
        const float* src = QKVc + ((size_t)bl * Nc + src_row) * 1536 + h * HDc + d0;
        *(float4*)&Qs[q][d0]     = *(const float4*)src;
        *(float4*)&Qs[q][d0 + 4] = *(const float4*)(src + 4);
    }
    const float* Crow = conn + ((size_t)b * Nc + (gi < Nc ? gi : Nc - 1)) * Nc;
    float m_run = -3.4e38f, l_run = 0.f;
    float acc[8] = {0.f, 0.f, 0.f, 0.f, 0.f, 0.f, 0.f, 0.f};

    for (int jt = 0; jt < 6; jt++) {
        __syncthreads();
        {   // stage K + V tiles 64x64
            int j = t >> 2, d0 = (t & 3) * 16;
            int gj = jt * 64 + j;
            int sr = (gj < Nc) ? gj : (Nc - 1);
            const float* kp = QKVc + ((size_t)bl * Nc + sr) * 1536 + Hc + h * HDc + d0;
            const float* vp = kp + Hc;
            *(float4*)&Ks[j][d0]      = *(const float4*)(kp);
            *(float4*)&Ks[j][d0 + 4]  = *(const float4*)(kp + 4);
            *(float4*)&Ks[j][d0 + 8]  = *(const float4*)(kp + 8);
            *(float4*)&Ks[j][d0 + 12] = *(const float4*)(kp + 12);
            *(float4*)&Vs[j][d0]      = *(const float4*)(vp);
            *(float4*)&Vs[j][d0 + 4]  = *(const float4*)(vp + 4);
            *(float4*)&Vs[j][d0 + 8]  = *(const float4*)(vp + 8);
            *(float4*)&Vs[j][d0 + 12] = *(const float4*)(vp + 12);
        }
        __syncthreads();
        float s[8] = {0.f, 0.f, 0.f, 0.f, 0.f, 0.f, 0.f, 0.f};
#pragma unroll 4
        for (int d4 = 0; d4 < 16; d4++) {
            float4 qv = *(float4*)&Qs[q][d4 * 4];
#pragma unroll
            for (int jj = 0; jj < 8; jj++) {
                float4 kv = *(float4*)&Ks[sub + 8 * jj][d4 * 4];
                s[jj] += qv.x * kv.x + qv.y * kv.y + qv.z * kv.z + qv.w * kv.w;
            }
        }
        float tile_max = -3.4e38f;
#pragma unroll
        for (int jj = 0; jj < 8; jj++) {
            int gj = jt * 64 + sub + 8 * jj;
            if (gj < Nc && gi < Nc) {
                float mk = tanhf(mterm + (1.f - a2) * Crow[gj]);
                s[jj] = s[jj] * 0.125f * (1.f + mk);
            } else s[jj] = -3.4e38f;
            tile_max = fmaxf(tile_max, s[jj]);
        }
#pragma unroll
        for (int off = 1; off < 8; off <<= 1)
            tile_max = fmaxf(tile_max, __shfl_xor(tile_max, off, 64));
        float m_new = fmaxf(m_run, tile_max);
        float esum = 0.f;
#pragma unroll
        for (int jj = 0; jj < 8; jj++) {
            float e = __expf(s[jj] - m_new);
            Es[q][sub + 8 * jj] = e;
            esum += e;
        }
#pragma unroll
        for (int off = 1; off < 8; off <<= 1)
            esum += __shfl_xor(esum, off, 64);
        float scl = __expf(m_run - m_new);
        l_run = l_run * scl + esum;
        m_run = m_new;
        __syncthreads();
#pragma unroll
        for (int dd = 0; dd < 8; dd++) acc[dd] *= scl;
        int d0 = sub * 8;
#pragma unroll 4
        for (int j4 = 0; j4 < 16; j4++) {
            float4 ev = *(float4*)&Es[q][j4 * 4];
#pragma unroll
            for (int u = 0; u < 4; u++) {
                float e = (u == 0) ? ev.x : (u == 1) ? ev.y : (u == 2) ? ev.z : ev.w;
                float4 v0 = *(float4*)&Vs[j4 * 4 + u][d0];
                float4 v1 = *(float4*)&Vs[j4 * 4 + u][d0 + 4];
                acc[0] += e * v0.x; acc[1] += e * v0.y; acc[2] += e * v0.z; acc[3] += e * v0.w;
                acc[4] += e * v1.x; acc[5] += e * v1.y; acc[6] += e * v1.z; acc[7] += e * v1.w;
            }
        }
    }
    if (gi < Nc) {
        float inv = 1.f / l_run;
        float* dst = ctx + ((size_t)b * Nc + gi) * Hc + h * HDc + sub * 8;
        float4 o0 = make_float4(acc[0] * inv, acc[1] * inv, acc[2] * inv, acc[3] * inv);
        float4 o1 = make_float4(acc[4] * inv, acc[5] * inv, acc[6] * inv, acc[7] * inv);
        *(float4*)dst = o0;
        *(float4*)(dst + 4) = o1;
    }
}

__global__ void add3_k(const float* __restrict__ x, float* __restrict__ ctx,
                       const float* __restrict__ fn, size_t count) {
    size_t idx = (size_t)blockIdx.x * blockDim.x + threadIdx.x;
    if (idx >= count) return;
    ctx[idx] = x[idx] + ctx[idx] + fn[idx];
}

__global__ void final_k(const float* __restrict__ AO, const float* __restrict__ FF,
                        const float* __restrict__ dw,
                        float* __restrict__ xout, float* __restrict__ proj, size_t count) {
    size_t idx = (size_t)blockIdx.x * blockDim.x + threadIdx.x;
    if (idx >= count) return;
    float w = dw[0];
    float ff = FF[idx];
    float xn = AO[idx] + ff;
    xout[idx] = xn;
    proj[idx] = w * ff + (1.f - w) * xn;
}

__global__ __launch_bounds__(256) void final_kl_k(const float* __restrict__ AO,
                                                  const float* __restrict__ FF,
                                                  const float* __restrict__ dw,
                                                  const float* __restrict__ PF,
                                                  float* __restrict__ xout,
                                                  float* __restrict__ acc) {
    __shared__ float sh[4];
    int r = blockIdx.x, t = threadIdx.x;
    size_t base = (size_t)r * Hc;
    float w = dw[1];
    float ff0 = FF[base + t], ff1 = FF[base + t + 256];
    float ao0 = AO[base + t], ao1 = AO[base + t + 256];
    float xn0 = ao0 + ff0, xn1 = ao1 + ff1;
    xout[base + t] = xn0;
    xout[base + t + 256] = xn1;
    float s0 = w * ff0 + (1.f - w) * xn0;
    float s1 = w * ff1 + (1.f - w) * xn1;
    float f0 = PF[base + t], f1 = PF[base + t + 256];
    float mf = blk_max(fmaxf(f0, f1), sh);
    float ms = blk_max(fmaxf(s0, s1), sh);
    float ef = expf(f0 - mf) + expf(f1 - mf);
    float es = expf(s0 - ms) + expf(s1 - ms);
    float sf = blk_sum(ef, sh);
    float ss = blk_sum(es, sh);
    float lsef = mf + logf(sf), lses = ms + logf(ss);
    float lf0 = f0 - lsef, lf1 = f1 - lsef, ls0 = s0 - lses, ls1 = s1 - lses;
    float tsum = expf(ls0) * (ls0 - lf0) + expf(ls1) * (ls1 - lf1)
               + expf(lf0) * (lf0 - ls0) + expf(lf1) * (lf1 - ls1);
    tsum = blk_sum(tsum, sh);
    if (t == 0) atomicAdd(acc, tsum);
}

__global__ void kl_final_k(const float* __restrict__ acc, float* __restrict__ out) {
    out[0] = 0.5f * acc[0] * (1.0f / (float)ROWS_BN);
}

// ---------------- launch ----------------
extern "C" void kernel_launch(void* const* d_in, const int* in_sizes, int n_in,
                              void* d_out, int out_size, void* d_ws, size_t ws_size,
                              hipStream_t stream) {
    (void)in_sizes; (void)n_in; (void)out_size; (void)ws_size;
    const float* x[2]    = {(const float*)d_in[0], (const float*)d_in[1]};
    const float* pri[2]  = {(const float*)d_in[2], (const float*)d_in[3]};
    const float* conn[2] = {(const float*)d_in[4], (const float*)d_in[5]};
    const float* dw      = (const float*)d_in[6];
    const float* wqkv[2] = {(const float*)d_in[7], (const float*)d_in[8]};
    const float* ln_g    = (const float*)d_in[9];
    const float* ln_b    = (const float*)d_in[10];
    const float* ffn_w1  = (const float*)d_in[11];
    const float* ffn_b1  = (const float*)d_in[12];
    const float* ffn_w2  = (const float*)d_in[13];
    const float* ffn_b2  = (const float*)d_in[14];
    const float* pw      = (const float*)d_in[15];
    const float* pb      = (const float*)d_in[16];
    const float* f1w     = (const float*)d_in[17];
    const float* f1b     = (const float*)d_in[18];
    const float* f2w     = (const float*)d_in[19];
    const float* f2b     = (const float*)d_in[20];
    const float* ipw     = (const float*)d_in[21];
    const float* ipb     = (const float*)d_in[22];
    const float* alpha   = (const float*)d_in[23];
    float* out = (float*)d_out;

    // --- workspace arena (~150 MB) ---
    float* W = (float*)d_ws;
    size_t o = 0;
    auto alloc = [&](size_t n) { float* p = W + o; o += n; return p; };
    float* Z     = alloc(BNH);
    float* CTX   = alloc(BNH);
    float* FN    = alloc(BNH);
    float* PROJ0 = alloc(BNH);
    float* R     = alloc(12417024);          // shared transient region
    float* TOK   = alloc((size_t)96 * Hc);
    float* QKVWG = alloc((size_t)96 * 1536);
    float* MASS  = alloc(96); float* DOT = alloc(96); float* NRMP = alloc(96);
    float* NRMC  = alloc(32); float* SW  = alloc(96); float* INVM = alloc(96);
    float* MSUM  = alloc(32);
    float* KLACC = alloc(1);

    // R overlays (disjoint lifetimes; same-stream ordering serializes):
    float* PEc  = R;                          // 4,657,152
    float* H1c  = R + PEC_SZ;                 // 4,657,152
    float* ZFc  = R + 2 * PEC_SZ;             // 1,552,384
    float* QKVc = R;                          // 4,657,152
    float* HIDc = R;                          // 6,209,536
    float* FFNOUT = R + HIDC_SZ;              // 6,207,488
    // tokens partial buffer: lives in H1c region (free after bgemm<1> of each chunk)
    float* TOKP = H1c;                        // 24*TSPLIT*512 = 196,608 floats
    // packed pri chunk (bf16): overlays CTX, which is dead from start-of-s until fattn_k.
    // size: 9096 rows x 384 shorts = 6.99 MB << CTX (24.8 MB)
    short* PRIB = (short*)CTX;

    const size_t OUT_DISTILL = 2 * BNH;
    const size_t OUT_AW = 2 * BNH + 1;

    hipMemsetAsync(KLACC, 0, sizeof(float), stream);

    int eb = 256;
    int gBNH = (int)((BNH + eb - 1) / eb);
    int gCHK = (int)((CHUNK_NH + eb - 1) / eb);
    int gPACK = (ROWS_WG * (KPAD / 8) + 255) / 256;   // 1706 blocks

    for (int s = 0; s < 2; s++) {
        ln_k<<<ROWS_BN, 256, 0, stream>>>(x[s], ln_g + s * Hc, ln_b + s * Hc, Z);
        // zero MASS/DOT/NRMP/NRMC (contiguous 320 floats) for split-atomic accumulation
        hipMemsetAsync(MASS, 0, 320 * sizeof(float), stream);
        wg_stats_k<<<dim3(Bc * (Pc + 1), WGS_SPLIT), 256, 0, stream>>>(
            pri[s], conn[s], MASS, DOT, NRMP, NRMC);
        wg_sw_k<<<1, 64, 0, stream>>>(MASS, DOT, NRMP, NRMC, SW, INVM);

        // ---- weight-gen pipeline, chunked over batches ----
        for (int c = 0; c < NCHUNK; c++) {
            const float* pric = pri[s] + (size_t)c * ROWS_WG * Nc;
            launch_bgemm<0>(Z + (size_t)c * ROWS_CHUNK * Hc, f1w + (size_t)Hc * Hc, ZFc,
                            ROWS_CHUNK, Hc, Hc, nullptr, nullptr, 0, nullptr, 0, 0, stream);
            // pre-pack pri chunk to bf16 (K 379 -> 384, zero pad), then packed-A GEMM
            pack_pri_k<<<gPACK, 256, 0, stream>>>(pric, PRIB, ROWS_WG);
            {
                dim3 grid(Hc / 128, (ROWS_WG + 127) / 128);
                bgemm_pa_k<<<grid, 256, 0, stream>>>(PRIB, pw, PEc, ROWS_WG, Hc, Nc,
                                                     pb, INVM + c * CB * Pc, Nc);
            }
            fused_nh_k<<<gCHK, eb, 0, stream>>>(PEc, SW + c * CB * Pc, FN + (size_t)c * CHUNK_NH, CHUNK_NH);
            launch_bgemm<3>(PEc, f1w, H1c, ROWS_WG, Hc, Hc, f1b, nullptr, 0, ZFc, Pc, Nc, stream);
            launch_bgemm<1>(H1c, f2w, PEc, ROWS_WG, Hc, Hc, f2b, nullptr, 0, nullptr, 0, 0, stream);
            // tokens: split over n for parallelism (H1c free here; reused as partial buffer)
            tokens_part_k<<<dim3(CB * Pc, TSPLIT), 512, 0, stream>>>(PEc, TOKP);
            tokens_red_k<<<CB * Pc, 512, 0, stream>>>(TOKP, TOK + (size_t)c * CB * Pc * Hc);
        }
        launch_bgemm<1>(TOK, ipw, QKVWG, Bc * Pc, 3 * Hc, Hc, ipb, nullptr, 0, nullptr, 0, 0, stream);
        wg_attn_k<<<Bc, 64, 0, stream>>>(QKVWG, out + OUT_AW + (size_t)s * (Bc * Pc), MSUM);

        // ---- main attention, chunked over batches ----
        for (int c = 0; c < NCHUNK; c++) {
            launch_bgemm<0>(Z + (size_t)c * ROWS_CHUNK * Hc, wqkv[s], QKVc,
                            ROWS_CHUNK, 3 * Hc, Hc, nullptr, nullptr, 0, nullptr, 0, 0, stream);
            fattn_k<<<dim3((Nc + AQT - 1) / AQT, NHc, CB), 256, 0, stream>>>(
                QKVc, conn[s], MSUM, alpha, c * CB, CTX);
        }
        add3_k<<<gBNH, eb, 0, stream>>>(x[s], CTX, FN, BNH);

        // ---- FFN, chunked rows ----
        ln_k<<<ROWS_BN, 256, 0, stream>>>(CTX, ln_g + (2 + s) * Hc, ln_b + (2 + s) * Hc, Z);
        for (int c = 0; c < NCHUNK; c++) {
            launch_bgemm<2>(Z + (size_t)c * ROWS_CHUNK * Hc, ffn_w1 + (size_t)s * Hc * 4 * Hc, HIDc,
                            ROWS_CHUNK, 4 * Hc, Hc, ffn_b1 + (size_t)s * 4 * Hc,
                            nullptr, 0, nullptr, 0, 0, stream);
            launch_bgemm<1>(HIDc, ffn_w2 + (size_t)s * 4 * Hc * Hc, FFNOUT + (size_t)c * ROWS_CHUNK * Hc,
                            ROWS_CHUNK, Hc, 4 * Hc, ffn_b2 + (size_t)s * Hc,
                            nullptr, 0, nullptr, 0, 0, stream);
        }
        if (s == 0) {
            final_k<<<gBNH, eb, 0, stream>>>(CTX, FFNOUT, dw, out, PROJ0, BNH);
        } else {
            final_kl_k<<<ROWS_BN, 256, 0, stream>>>(CTX, FFNOUT, dw, PROJ0, out + BNH, KLACC);
        }
    }
    kl_final_k<<<1, 1, 0, stream>>>(KLACC, out + OUT_DISTILL);
}

// Round 3
// 3112.018 us; speedup vs baseline: 2.4455x; 2.2298x over previous
//
#include <hip/hip_runtime.h>
#include <math.h>

// ---------------- constants ----------------
#define Bc   32
#define Nc   379
#define Hc   512
#define NHc  8
#define Pc   3
#define HDc  64          // H/NH
#define NNc  (Nc*Nc)     // 143641
#define CB   8           // batch chunk
#define NCHUNK 4
static const size_t NH_f  = (size_t)Nc*Hc;           // 194,048
static const size_t BNH   = (size_t)Bc*Nc*Hc;        // 6,207,488
#define ROWS_BN   12128   // B*N
#define ROWS_CHUNK 3032   // CB*N
#define ROWS_WG    9096   // CB*P*N
static const size_t CHUNK_NH = (size_t)CB*Nc*Hc;     // 1,552,384
static const size_t PEC_SZ   = (size_t)ROWS_WG*Hc;   // 4,657,152

#define WGS_SPLIT 16     // blocks per (b,r) row in wg_stats
#define TSPLIT 16        // n-splits in tokens reduction
#define KPAD 384         // pri K (379) padded to multiple of 32

typedef __attribute__((ext_vector_type(8))) short bf16x8;
typedef __attribute__((ext_vector_type(4))) float f32x4;

__device__ inline float gelu_f(float x) {
    return 0.5f * x * (1.0f + erff(x * 0.7071067811865476f));
}

// fp32 -> bf16 bits, round-to-nearest-even
__device__ inline short f2bf(float f) {
    unsigned u = __float_as_uint(f);
    unsigned r = u + 0x7fffu + ((u >> 16) & 1u);
    return (short)(r >> 16);
}

// block reductions (blockDim == 256)
__device__ inline float blk_sum(float v, float* sh) {
#pragma unroll
    for (int off = 32; off; off >>= 1) v += __shfl_xor(v, off, 64);
    int w = threadIdx.x >> 6;
    __syncthreads();
    if ((threadIdx.x & 63) == 0) sh[w] = v;
    __syncthreads();
    return sh[0] + sh[1] + sh[2] + sh[3];
}
__device__ inline float blk_max(float v, float* sh) {
#pragma unroll
    for (int off = 32; off; off >>= 1) v = fmaxf(v, __shfl_xor(v, off, 64));
    int w = threadIdx.x >> 6;
    __syncthreads();
    if ((threadIdx.x & 63) == 0) sh[w] = v;
    __syncthreads();
    return fmaxf(fmaxf(sh[0], sh[1]), fmaxf(sh[2], sh[3]));
}

// ---------------- weight pre-pack: fp32 [K][N] -> bf16 [N][KP] (zero pad k>=K) ----------------
// wave: 64 consecutive n at same k -> coalesced 256B reads.
__global__ __launch_bounds__(256) void pack_b_k(const float* __restrict__ src,
                                                short* __restrict__ dst,
                                                int K, int N, int KP) {
    int idx = blockIdx.x * blockDim.x + threadIdx.x;
    int total = N * (KP / 8);
    if (idx >= total) return;
    int k8 = idx / N;            // consecutive tid -> consecutive n (coalesced)
    int n  = idx % N;
    int k0 = k8 * 8;
    bf16x8 v;
#pragma unroll
    for (int j = 0; j < 8; j++) {
        int k = k0 + j;
        v[j] = (k < K) ? f2bf(src[(size_t)k * N + n]) : (short)0;
    }
    *(bf16x8*)(dst + (size_t)n * KP + k0) = v;
}

// ---------------- pri pre-pack: fp32 [rows][379] -> bf16 [rows][384] (zero pad) ----------------
__global__ __launch_bounds__(256) void pack_pri_k(const float* __restrict__ src,
                                                  short* __restrict__ dst, int rows) {
    int idx = blockIdx.x * blockDim.x + threadIdx.x;
    int total = rows * (KPAD / 8);
    if (idx >= total) return;
    int row = idx / (KPAD / 8);
    int c8  = (idx % (KPAD / 8)) * 8;
    const float* s = src + (size_t)row * Nc + c8;
    bf16x8 v;
#pragma unroll
    for (int j = 0; j < 8; j++) v[j] = (c8 + j < Nc) ? f2bf(s[j]) : (short)0;
    *(bf16x8*)(dst + (size_t)row * KPAD + c8) = v;
}

// ---------------- g2: bf16 MFMA GEMM, packed-B, double-buffered, reg-prefetch ----------------
// C(M,N) = A(M,K) @ Bpacked(N,K).  B always bf16 [n][KSB] (n-major, k-contig).
// A: ABF=1 -> bf16 [m][KSA]; ABF=0 -> fp32 [m][KSA] (converted in staging).
// C: CBF=1 -> bf16 out; else fp32.  N % 128 == 0, K % 32 == 0. M guarded.
// EPI: 0 none; 1 +bias; 2 gelu(+bias); 3 gelu(+bias+addsrc P-bcast); 4 *rowscale[gm/rs_div]+bias
#define GBM 64
#define GBN 128
#define GBK 32
#define GLD 40   // LDS row stride in shorts (80B): frag b128 reads 2-way (free), stage writes <=4-way

template<int EPI, int ABF, int CBF>
__global__ __launch_bounds__(256) void g2_k(
    const void* __restrict__ Ap, const short* __restrict__ Bp, void* __restrict__ Cp,
    int M, int N, int K, int KSA, int KSB,
    const float* __restrict__ bias,
    const float* __restrict__ rowscale, int rs_div,
    const float* __restrict__ addsrc, int addN)
{
    __shared__ __attribute__((aligned(16))) short As[2][GBM * GLD];
    __shared__ __attribute__((aligned(16))) short Bs[2][GBN * GLD];
    int tid = threadIdx.x;
    int wave = tid >> 6, lane = tid & 63;
    int wr = wave >> 1, wc = wave & 1;          // 2x2 waves; wave tile 32(m) x 64(n)
    int quad = lane >> 4, l16 = lane & 15;
    int m0 = blockIdx.y * GBM, n0 = blockIdx.x * GBN;

    int a_r = tid >> 2, a_k = (tid & 3) * 8;    // A: 64 rows x 32k, 8 elems/thread
    int b_n = tid >> 1, b_k = (tid & 1) * 16;   // B: 128 n x 32k, 16 elems/thread

    const float* Af = (const float*)Ap;
    const short* Ab = (const short*)Ap;

    f32x4 acc[2][4] = {};
    int nk = K / GBK;

    float4 ra0, ra1; bf16x8 rab; bf16x8 rb0, rb1;

    auto loadT = [&](int k0) {
        int gm = m0 + a_r;
        if (ABF) {
            rab = (bf16x8){0, 0, 0, 0, 0, 0, 0, 0};
            if (gm < M) rab = *(const bf16x8*)(Ab + (size_t)gm * KSA + k0 + a_k);
        } else {
            ra0 = make_float4(0.f, 0.f, 0.f, 0.f); ra1 = ra0;
            if (gm < M) {
                const float* s = Af + (size_t)gm * KSA + k0 + a_k;
                ra0 = *(const float4*)s; ra1 = *(const float4*)(s + 4);
            }
        }
        const short* bs = Bp + (size_t)(n0 + b_n) * KSB + k0 + b_k;
        rb0 = *(const bf16x8*)bs; rb1 = *(const bf16x8*)(bs + 8);
    };
    auto storeT = [&](int buf) {
        short* ad = &As[buf][a_r * GLD + a_k];
        if (ABF) {
            *(bf16x8*)ad = rab;
        } else {
            bf16x8 t;
            t[0] = f2bf(ra0.x); t[1] = f2bf(ra0.y); t[2] = f2bf(ra0.z); t[3] = f2bf(ra0.w);
            t[4] = f2bf(ra1.x); t[5] = f2bf(ra1.y); t[6] = f2bf(ra1.z); t[7] = f2bf(ra1.w);
            *(bf16x8*)ad = t;
        }
        short* bd = &Bs[buf][b_n * GLD + b_k];
        *(bf16x8*)bd = rb0; *(bf16x8*)(bd + 8) = rb1;
    };

    loadT(0);
    storeT(0);
    __syncthreads();

    for (int it = 0; it < nk; ++it) {
        int cur = it & 1;
        if (it + 1 < nk) loadT((it + 1) * GBK);   // prefetch in flight over MFMA below
        bf16x8 afr[2], bfr[4];
#pragma unroll
        for (int mt = 0; mt < 2; mt++)
            afr[mt] = *(const bf16x8*)&As[cur][(wr * 32 + mt * 16 + l16) * GLD + quad * 8];
#pragma unroll
        for (int nt = 0; nt < 4; nt++)
            bfr[nt] = *(const bf16x8*)&Bs[cur][(wc * 64 + nt * 16 + l16) * GLD + quad * 8];
#pragma unroll
        for (int mt = 0; mt < 2; mt++)
#pragma unroll
            for (int nt = 0; nt < 4; nt++)
                acc[mt][nt] = __builtin_amdgcn_mfma_f32_16x16x32_bf16(
                    afr[mt], bfr[nt], acc[mt][nt], 0, 0, 0);
        if (it + 1 < nk) {
            storeT(cur ^ 1);    // buffer cur^1 fully consumed at iter it-1 (pre-sync)
            __syncthreads();
        }
    }

    // epilogue: C/D layout col=l16, row=quad*4+r
#pragma unroll
    for (int mt = 0; mt < 2; mt++) {
#pragma unroll
        for (int nt = 0; nt < 4; nt++) {
#pragma unroll
            for (int r = 0; r < 4; r++) {
                int gm = m0 + wr * 32 + mt * 16 + quad * 4 + r;
                int gn = n0 + wc * 64 + nt * 16 + l16;
                if (gm < M) {
                    float v = acc[mt][nt][r];
                    if (EPI == 1 || EPI == 2 || EPI == 3) v += bias[gn];
                    if (EPI == 4) v = v * rowscale[gm / rs_div] + bias[gn];
                    if (EPI == 3) {
                        int addrow = (gm / (3 * addN)) * addN + (gm % addN);
                        v += addsrc[(size_t)addrow * N + gn];
                    }
                    if (EPI == 2 || EPI == 3) v = gelu_f(v);
                    if (CBF) ((short*)Cp)[(size_t)gm * N + gn] = f2bf(v);
                    else     ((float*)Cp)[(size_t)gm * N + gn] = v;
                }
            }
        }
    }
}

template<int EPI, int ABF, int CBF>
static void launch_g2(const void* A, const short* B, void* C, int M, int N, int K,
                      int KSA, int KSB, const float* bias,
                      const float* rowscale, int rs_div,
                      const float* addsrc, int addN, hipStream_t st) {
    dim3 grid(N / GBN, (M + GBM - 1) / GBM);
    g2_k<EPI, ABF, CBF><<<grid, 256, 0, st>>>(A, B, C, M, N, K, KSA, KSB,
                                              bias, rowscale, rs_div, addsrc, addN);
}

// ---------------- legacy fp32-B GEMM (kept only for tiny TOK GEMM, M=96) ----------------
#define BM 128
#define BN 128
#define BK 32
#define LDK 40

template<int EPI>
__global__ __launch_bounds__(256) void bgemm_k(
    const float* __restrict__ A, const float* __restrict__ B, float* __restrict__ C,
    int M, int N, int K,
    const float* __restrict__ bias,
    const float* __restrict__ rowscale, int rs_div,
    const float* __restrict__ addsrc, int addP, int addN)
{
    __shared__ __attribute__((aligned(16))) short As[BM * LDK];
    __shared__ __attribute__((aligned(16))) short Bs[BN * LDK];
    int tid = threadIdx.x;
    int wave = tid >> 6, lane = tid & 63;
    int wr = wave >> 1, wc = wave & 1;
    int m0 = blockIdx.y * BM, n0 = blockIdx.x * BN;
    int quad = lane >> 4, l16 = lane & 15;
    bool k_vec = ((K & 3) == 0);

    f32x4 acc[4][4] = {};

    for (int k0 = 0; k0 < K; k0 += BK) {
        {
            int row = tid >> 3;
            int kk  = (tid & 7) * 4;
#pragma unroll
            for (int rr = 0; rr < 4; rr++) {
                int m = row + rr * 32;
                int gm = m0 + m;
                float4 v = make_float4(0.f, 0.f, 0.f, 0.f);
                if (gm < M) {
                    int gk = k0 + kk;
                    const float* src = A + (size_t)gm * K + gk;
                    if (k_vec && gk + 3 < K) v = *(const float4*)src;
                    else {
                        if (gk     < K) v.x = src[0];
                        if (gk + 1 < K) v.y = src[1];
                        if (gk + 2 < K) v.z = src[2];
                        if (gk + 3 < K) v.w = src[3];
                    }
                }
                short* dst = &As[m * LDK + kk];
                dst[0] = f2bf(v.x); dst[1] = f2bf(v.y);
                dst[2] = f2bf(v.z); dst[3] = f2bf(v.w);
            }
        }
        {
            int kk = tid >> 5;
            int nn = (tid & 31) * 4;
#pragma unroll
            for (int rr = 0; rr < 4; rr++) {
                int k = kk + rr * 8;
                int gk = k0 + k;
                float4 v = make_float4(0.f, 0.f, 0.f, 0.f);
                if (gk < K) v = *(const float4*)(B + (size_t)gk * N + n0 + nn);
                Bs[(nn + 0) * LDK + k] = f2bf(v.x);
                Bs[(nn + 1) * LDK + k] = f2bf(v.y);
                Bs[(nn + 2) * LDK + k] = f2bf(v.z);
                Bs[(nn + 3) * LDK + k] = f2bf(v.w);
            }
        }
        __syncthreads();
        bf16x8 afr[4], bfr[4];
#pragma unroll
        for (int mt = 0; mt < 4; mt++)
            afr[mt] = *(const bf16x8*)&As[(wr * 64 + mt * 16 + l16) * LDK + quad * 8];
#pragma unroll
        for (int nt = 0; nt < 4; nt++)
            bfr[nt] = *(const bf16x8*)&Bs[(wc * 64 + nt * 16 + l16) * LDK + quad * 8];
#pragma unroll
        for (int mt = 0; mt < 4; mt++)
#pragma unroll
            for (int nt = 0; nt < 4; nt++)
                acc[mt][nt] = __builtin_amdgcn_mfma_f32_16x16x32_bf16(
                    afr[mt], bfr[nt], acc[mt][nt], 0, 0, 0);
        __syncthreads();
    }
#pragma unroll
    for (int mt = 0; mt < 4; mt++) {
#pragma unroll
        for (int nt = 0; nt < 4; nt++) {
#pragma unroll
            for (int r = 0; r < 4; r++) {
                int gm = m0 + wr * 64 + mt * 16 + quad * 4 + r;
                int gn = n0 + wc * 64 + nt * 16 + l16;
                if (gm < M) {
                    float v = acc[mt][nt][r];
                    if (EPI == 1 || EPI == 2 || EPI == 3) v += bias[gn];
                    if (EPI == 4) v = v * rowscale[gm / rs_div] + bias[gn];
                    if (EPI == 3) {
                        int addrow = (gm / (addP * addN)) * addN + (gm % addN);
                        v += addsrc[(size_t)addrow * N + gn];
                    }
                    if (EPI == 2 || EPI == 3) v = gelu_f(v);
                    C[(size_t)gm * N + gn] = v;
                }
            }
        }
    }
}

// ---------------- LayerNorm (rows of 512) -> bf16 output (only GEMM-A consumers) ----------------
__global__ __launch_bounds__(256) void ln_bf_k(const float* __restrict__ x,
                                               const float* __restrict__ g,
                                               const float* __restrict__ b,
                                               short* __restrict__ z) {
    __shared__ float sh[4];
    int r = blockIdx.x, t = threadIdx.x;
    const float* xr = x + (size_t)r * Hc;
    float v0 = xr[t], v1 = xr[t + 256];
    float sum = blk_sum(v0 + v1, sh);
    float sq  = blk_sum(v0 * v0 + v1 * v1, sh);
    float mean = sum * (1.f / Hc);
    float var  = sq * (1.f / Hc) - mean * mean;
    float inv  = rsqrtf(var + 1e-5f);
    short* zr = z + (size_t)r * Hc;
    zr[t]       = f2bf((v0 - mean) * inv * g[t]       + b[t]);
    zr[t + 256] = f2bf((v1 - mean) * inv * g[t + 256] + b[t + 256]);
}

// ---------------- weight-gen stats (split + atomic partials) ----------------
__global__ __launch_bounds__(256) void wg_stats_k(const float* __restrict__ pri,
                                                  const float* __restrict__ conn,
                                                  float* __restrict__ mass, float* __restrict__ dot,
                                                  float* __restrict__ nrmp, float* __restrict__ nrmc) {
    __shared__ float sh[4];
    int bp = blockIdx.x;
    int sp = blockIdx.y;
    int b = bp >> 2, r = bp & 3;   // P+1 == 4
    const int per = (NNc + WGS_SPLIT - 1) / WGS_SPLIT;
    int i0 = sp * per;
    int i1 = i0 + per; if (i1 > NNc) i1 = NNc;
    const float* c = conn + (size_t)b * NNc;
    if (r < Pc) {
        const float* p = pri + (size_t)(b * Pc + r) * NNc;
        float sa = 0, sq = 0, sd = 0;
        for (int i = i0 + threadIdx.x; i < i1; i += 256) {
            float pv = p[i], cv = c[i];
            sa += fabsf(pv); sq += pv * pv; sd += pv * cv;
        }
        sa = blk_sum(sa, sh);
        sq = blk_sum(sq, sh);
        sd = blk_sum(sd, sh);
        if (threadIdx.x == 0) {
            atomicAdd(&mass[b * Pc + r], sa);
            atomicAdd(&nrmp[b * Pc + r], sq);
            atomicAdd(&dot[b * Pc + r], sd);
        }
    } else {
        float sq = 0;
        for (int i = i0 + threadIdx.x; i < i1; i += 256) { float cv = c[i]; sq += cv * cv; }
        sq = blk_sum(sq, sh);
        if (threadIdx.x == 0) atomicAdd(&nrmc[b], sq);
    }
}

__global__ void wg_sw_k(const float* mass, const float* dot, const float* nrmp, const float* nrmc,
                        float* sw, float* invm) {
    int b = threadIdx.x;
    if (b >= Bc) return;
    float nc = fmaxf(sqrtf(nrmc[b]), 1e-12f);
    float s[Pc];
    for (int p = 0; p < Pc; p++) s[p] = dot[b * Pc + p] / (nc * fmaxf(sqrtf(nrmp[b * Pc + p]), 1e-12f));
    float m = fmaxf(s[0], fmaxf(s[1], s[2]));
    float e[Pc], sum = 0;
    for (int p = 0; p < Pc; p++) { e[p] = expf(s[p] - m); sum += e[p]; }
    for (int p = 0; p < Pc; p++) {
        sw[b * Pc + p] = e[p] / sum;
        invm[b * Pc + p] = 1.f / mass[b * Pc + p];
    }
}

__global__ void fused_nh_k(const float* __restrict__ PEc, const float* __restrict__ swp,
                           float* __restrict__ FNp, size_t count) {
    size_t idx = (size_t)blockIdx.x * blockDim.x + threadIdx.x;
    if (idx >= count) return;
    int bl = (int)(idx / NH_f);
    size_t within = idx % NH_f;
    const float* sw = swp + bl * Pc;
    size_t base = (size_t)bl * Pc * NH_f + within;
    FNp[idx] = sw[0] * PEc[base] + sw[1] * PEc[base + NH_f] + sw[2] * PEc[base + 2 * NH_f];
}

// ---------------- tokens: mean over N, split ----------------
__global__ __launch_bounds__(512) void tokens_part_k(const float* __restrict__ F2,
                                                     float* __restrict__ TOKP) {
    int bp = blockIdx.x, sp = blockIdx.y, h = threadIdx.x;
    const int rows = (Nc + TSPLIT - 1) / TSPLIT;
    int n0 = sp * rows;
    int n1 = n0 + rows; if (n1 > Nc) n1 = Nc;
    const float* base = F2 + (size_t)bp * NH_f + h;
    float s = 0;
    for (int n = n0; n < n1; n++) s += base[(size_t)n * Hc];
    TOKP[((size_t)bp * TSPLIT + sp) * Hc + h] = s;
}

__global__ __launch_bounds__(512) void tokens_red_k(const float* __restrict__ TOKP,
                                                    float* __restrict__ TOK) {
    int bp = blockIdx.x, h = threadIdx.x;
    float s = 0;
#pragma unroll
    for (int sp = 0; sp < TSPLIT; sp++) s += TOKP[((size_t)bp * TSPLIT + sp) * Hc + h];
    TOK[(size_t)bp * Hc + h] = s * (1.0f / (float)Nc);
}

__global__ __launch_bounds__(64) void wg_attn_k(const float* __restrict__ QW,
                                                float* __restrict__ aw_out, float* __restrict__ msum) {
    int b = blockIdx.x, lane = threadIdx.x;
    float s[4][Pc][Pc];
    for (int h = 0; h < 4; h++)
        for (int i = 0; i < Pc; i++)
            for (int j = 0; j < Pc; j++) {
                const float* q = QW + (size_t)(b * Pc + i) * 1536 + h * 128;
                const float* k = QW + (size_t)(b * Pc + j) * 1536 + 512 + h * 128;
                float p = q[lane] * k[lane] + q[lane + 64] * k[lane + 64];
#pragma unroll
                for (int off = 32; off; off >>= 1) p += __shfl_xor(p, off, 64);
                s[h][i][j] = p * 0.08838834764831845f;
            }
    float aw[Pc] = {0, 0, 0};
    for (int h = 0; h < 4; h++)
        for (int i = 0; i < Pc; i++) {
            float m = fmaxf(s[h][i][0], fmaxf(s[h][i][1], s[h][i][2]));
            float e0 = expf(s[h][i][0] - m), e1 = expf(s[h][i][1] - m), e2 = expf(s[h][i][2] - m);
            float inv = 1.f / (e0 + e1 + e2);
            aw[0] += e0 * inv; aw[1] += e1 * inv; aw[2] += e2 * inv;
        }
    for (int j = 0; j < Pc; j++) aw[j] *= (1.f / 12.f);
    float m2 = fmaxf(aw[0], fmaxf(aw[1], aw[2]));
    float e0 = expf((aw[0] - m2) * 100.f), e1 = expf((aw[1] - m2) * 100.f), e2 = expf((aw[2] - m2) * 100.f);
    float inv = 1.f / (e0 + e1 + e2);
    if (lane == 0) {
        aw_out[b * Pc + 0] = e0 * inv;
        aw_out[b * Pc + 1] = e1 * inv;
        aw_out[b * Pc + 2] = e2 * inv;
        msum[b] = (e0 + e1 + e2) * inv;
    }
}

// ---------------- flash attention ----------------
#define AQT 32
__global__ __launch_bounds__(256) void fattn_k(const float* __restrict__ QKVc,
                                               const float* __restrict__ conn,
                                               const float* __restrict__ msum,
                                               const float* __restrict__ alpha,
                                               int b0, float* __restrict__ ctx) {
    __shared__ float Qs[AQT][66];
    __shared__ float Ks[64][66];
    __shared__ float Vs[64][66];
    __shared__ float Es[AQT][66];
    int i0 = blockIdx.x * AQT;
    int h = blockIdx.y, bl = blockIdx.z;
    int b = b0 + bl;
    int t = threadIdx.x;
    int q = t >> 3, sub = t & 7;
    int gi = i0 + q;
    float a2 = 0.5f * alpha[0];
    float mterm = a2 * msum[b];
    {
        int src_row = (gi < Nc) ? gi : (Nc - 1);
        int d0 = sub * 8;
        const float* src = QKVc + ((size_t)bl * Nc + src_row) * 1536 + h * HDc + d0;
        *(float4*)&Qs[q][d0]     = *(const float4*)src;
        *(float4*)&Qs[q][d0 + 4] = *(const float4*)(src + 4);
    }
    const float* Crow = conn + ((size_t)b * Nc + (gi < Nc ? gi : Nc - 1)) * Nc;
    float m_run = -3.4e38f, l_run = 0.f;
    float acc[8] = {0.f, 0.f, 0.f, 0.f, 0.f, 0.f, 0.f, 0.f};

    for (int jt = 0; jt < 6; jt++) {
        __syncthreads();
        {
            int j = t >> 2, d0 = (t & 3) * 16;
            int gj = jt * 64 + j;
            int sr = (gj < Nc) ? gj : (Nc - 1);
            const float* kp = QKVc + ((size_t)bl * Nc + sr) * 1536 + Hc + h * HDc + d0;
            const float* vp = kp + Hc;
            *(float4*)&Ks[j][d0]      = *(const float4*)(kp);
            *(float4*)&Ks[j][d0 + 4]  = *(const float4*)(kp + 4);
            *(float4*)&Ks[j][d0 + 8]  = *(const float4*)(kp + 8);
            *(float4*)&Ks[j][d0 + 12] = *(const float4*)(kp + 12);
            *(float4*)&Vs[j][d0]      = *(const float4*)(vp);
            *(float4*)&Vs[j][d0 + 4]  = *(const float4*)(vp + 4);
            *(float4*)&Vs[j][d0 + 8]  = *(const float4*)(vp + 8);
            *(float4*)&Vs[j][d0 + 12] = *(const float4*)(vp + 12);
        }
        __syncthreads();
        float s[8] = {0.f, 0.f, 0.f, 0.f, 0.f, 0.f, 0.f, 0.f};
#pragma unroll 4
        for (int d4 = 0; d4 < 16; d4++) {
            float4 qv = *(float4*)&Qs[q][d4 * 4];
#pragma unroll
            for (int jj = 0; jj < 8; jj++) {
                float4 kv = *(float4*)&Ks[sub + 8 * jj][d4 * 4];
                s[jj] += qv.x * kv.x + qv.y * kv.y + qv.z * kv.z + qv.w * kv.w;
            }
        }
        float tile_max = -3.4e38f;
#pragma unroll
        for (int jj = 0; jj < 8; jj++) {
            int gj = jt * 64 + sub + 8 * jj;
            if (gj < Nc && gi < Nc) {
                float mk = tanhf(mterm + (1.f - a2) * Crow[gj]);
                s[jj] = s[jj] * 0.125f * (1.f + mk);
            } else s[jj] = -3.4e38f;
            tile_max = fmaxf(tile_max, s[jj]);
        }
#pragma unroll
        for (int off = 1; off < 8; off <<= 1)
            tile_max = fmaxf(tile_max, __shfl_xor(tile_max, off, 64));
        float m_new = fmaxf(m_run, tile_max);
        float esum = 0.f;
#pragma unroll
        for (int jj = 0; jj < 8; jj++) {
            float e = __expf(s[jj] - m_new);
            Es[q][sub + 8 * jj] = e;
            esum += e;
        }
#pragma unroll
        for (int off = 1; off < 8; off <<= 1)
            esum += __shfl_xor(esum, off, 64);
        float scl = __expf(m_run - m_new);
        l_run = l_run * scl + esum;
        m_run = m_new;
        __syncthreads();
#pragma unroll
        for (int dd = 0; dd < 8; dd++) acc[dd] *= scl;
        int d0 = sub * 8;
#pragma unroll 4
        for (int j4 = 0; j4 < 16; j4++) {
            float4 ev = *(float4*)&Es[q][j4 * 4];
#pragma unroll
            for (int u = 0; u < 4; u++) {
                float e = (u == 0) ? ev.x : (u == 1) ? ev.y : (u == 2) ? ev.z : ev.w;
                float4 v0 = *(float4*)&Vs[j4 * 4 + u][d0];
                float4 v1 = *(float4*)&Vs[j4 * 4 + u][d0 + 4];
                acc[0] += e * v0.x; acc[1] += e * v0.y; acc[2] += e * v0.z; acc[3] += e * v0.w;
                acc[4] += e * v1.x; acc[5] += e * v1.y; acc[6] += e * v1.z; acc[7] += e * v1.w;
            }
        }
    }
    if (gi < Nc) {
        float inv = 1.f / l_run;
        float* dst = ctx + ((size_t)b * Nc + gi) * Hc + h * HDc + sub * 8;
        float4 o0 = make_float4(acc[0] * inv, acc[1] * inv, acc[2] * inv, acc[3] * inv);
        float4 o1 = make_float4(acc[4] * inv, acc[5] * inv, acc[6] * inv, acc[7] * inv);
        *(float4*)dst = o0;
        *(float4*)(dst + 4) = o1;
    }
}

__global__ void add3_k(const float* __restrict__ x, float* __restrict__ ctx,
                       const float* __restrict__ fn, size_t count) {
    size_t idx = (size_t)blockIdx.x * blockDim.x + threadIdx.x;
    if (idx >= count) return;
    ctx[idx] = x[idx] + ctx[idx] + fn[idx];
}

__global__ void final_k(const float* __restrict__ AO, const float* __restrict__ FF,
                        const float* __restrict__ dw,
                        float* __restrict__ xout, float* __restrict__ proj, size_t count) {
    size_t idx = (size_t)blockIdx.x * blockDim.x + threadIdx.x;
    if (idx >= count) return;
    float w = dw[0];
    float ff = FF[idx];
    float xn = AO[idx] + ff;
    xout[idx] = xn;
    proj[idx] = w * ff + (1.f - w) * xn;
}

__global__ __launch_bounds__(256) void final_kl_k(const float* __restrict__ AO,
                                                  const float* __restrict__ FF,
                                                  const float* __restrict__ dw,
                                                  const float* __restrict__ PF,
                                                  float* __restrict__ xout,
                                                  float* __restrict__ acc) {
    __shared__ float sh[4];
    int r = blockIdx.x, t = threadIdx.x;
    size_t base = (size_t)r * Hc;
    float w = dw[1];
    float ff0 = FF[base + t], ff1 = FF[base + t + 256];
    float ao0 = AO[base + t], ao1 = AO[base + t + 256];
    float xn0 = ao0 + ff0, xn1 = ao1 + ff1;
    xout[base + t] = xn0;
    xout[base + t + 256] = xn1;
    float s0 = w * ff0 + (1.f - w) * xn0;
    float s1 = w * ff1 + (1.f - w) * xn1;
    float f0 = PF[base + t], f1 = PF[base + t + 256];
    float mf = blk_max(fmaxf(f0, f1), sh);
    float ms = blk_max(fmaxf(s0, s1), sh);
    float ef = expf(f0 - mf) + expf(f1 - mf);
    float es = expf(s0 - ms) + expf(s1 - ms);
    float sf = blk_sum(ef, sh);
    float ss = blk_sum(es, sh);
    float lsef = mf + logf(sf), lses = ms + logf(ss);
    float lf0 = f0 - lsef, lf1 = f1 - lsef, ls0 = s0 - lses, ls1 = s1 - lses;
    float tsum = expf(ls0) * (ls0 - lf0) + expf(ls1) * (ls1 - lf1)
               + expf(lf0) * (lf0 - ls0) + expf(lf1) * (lf1 - ls1);
    tsum = blk_sum(tsum, sh);
    if (t == 0) atomicAdd(acc, tsum);
}

__global__ void kl_final_k(const float* __restrict__ acc, float* __restrict__ out) {
    out[0] = 0.5f * acc[0] * (1.0f / (float)ROWS_BN);
}

// ---------------- launch ----------------
extern "C" void kernel_launch(void* const* d_in, const int* in_sizes, int n_in,
                              void* d_out, int out_size, void* d_ws, size_t ws_size,
                              hipStream_t stream) {
    (void)in_sizes; (void)n_in; (void)out_size; (void)ws_size;
    const float* x[2]    = {(const float*)d_in[0], (const float*)d_in[1]};
    const float* pri[2]  = {(const float*)d_in[2], (const float*)d_in[3]};
    const float* conn[2] = {(const float*)d_in[4], (const float*)d_in[5]};
    const float* dw      = (const float*)d_in[6];
    const float* wqkv[2] = {(const float*)d_in[7], (const float*)d_in[8]};
    const float* ln_g    = (const float*)d_in[9];
    const float* ln_b    = (const float*)d_in[10];
    const float* ffn_w1  = (const float*)d_in[11];
    const float* ffn_b1  = (const float*)d_in[12];
    const float* ffn_w2  = (const float*)d_in[13];
    const float* ffn_b2  = (const float*)d_in[14];
    const float* pw      = (const float*)d_in[15];
    const float* pb      = (const float*)d_in[16];
    const float* f1w     = (const float*)d_in[17];
    const float* f1b     = (const float*)d_in[18];
    const float* f2w     = (const float*)d_in[19];
    const float* f2b     = (const float*)d_in[20];
    const float* ipw     = (const float*)d_in[21];
    const float* ipb     = (const float*)d_in[22];
    const float* alpha   = (const float*)d_in[23];
    float* out = (float*)d_out;

    // --- workspace arena (~158 MB) ---
    float* W = (float*)d_ws;
    size_t o = 0;
    auto alloc = [&](size_t n) { float* p = W + o; o += n; return p; };
    float* Z     = alloc(BNH);               // bf16 Z lives here (half used)
    float* CTX   = alloc(BNH);
    float* FN    = alloc(BNH);
    float* PROJ0 = alloc(BNH);
    float* R     = alloc(12417024);          // shared transient region
    float* TOK   = alloc((size_t)96 * Hc);
    float* QKVWG = alloc((size_t)96 * 1536);
    float* MASS  = alloc(96); float* DOT = alloc(96); float* NRMP = alloc(96);
    float* NRMC  = alloc(32); float* SW  = alloc(96); float* INVM = alloc(96);
    float* MSUM  = alloc(32);
    float* KLACC = alloc(1);
    // bf16 weight packs (persistent across launch)
    short* W1P  = (short*)alloc(262144);     // f1w  [512n][1024k]
    short* W2P  = (short*)alloc(131072);     // f2w  [512n][512k]
    short* PWP  = (short*)alloc(98304);      // pw   [512n][384k]
    short* QKVP = (short*)alloc(393216);     // wqkv[s] [1536n][512k]
    short* F1P  = (short*)alloc(524288);     // ffn_w1[s] [2048n][512k]
    short* F2P  = (short*)alloc(524288);     // ffn_w2[s] [512n][2048k]

    // R overlays (disjoint lifetimes):
    float* PEc  = R;                               // 4,657,152 fl
    short* H1B  = (short*)(R + PEC_SZ);            // 9096x512 bf16 = 2,328,576 fl
    float* ZFc  = R + PEC_SZ + 2328576;            // 1,552,384 fl (ends at 8.54M)
    float* QKVc = R;                               // 4,657,152 fl
    short* HIDB = (short*)R;                       // 3032x2048 bf16 = 3,104,768 fl
    float* FFNOUT = R + 6209536;                   // 6,207,488 fl (as before)
    float* TOKP = R + PEC_SZ;                      // tokens partials (H1B dead by then)
    short* PRIB = (short*)CTX;                     // packed pri chunk (CTX dead till fattn)
    short* Zb   = (short*)Z;                       // bf16 ln output [12128][512]

    const size_t OUT_DISTILL = 2 * BNH;
    const size_t OUT_AW = 2 * BNH + 1;

    hipMemsetAsync(KLACC, 0, sizeof(float), stream);

    int eb = 256;
    int gBNH = (int)((BNH + eb - 1) / eb);
    int gCHK = (int)((CHUNK_NH + eb - 1) / eb);
    int gPACK = (ROWS_WG * (KPAD / 8) + 255) / 256;

    // one-time weight packs (shared across s)
    pack_b_k<<<(512 * 128 + 255) / 256, 256, 0, stream>>>(f1w, W1P, 1024, 512, 1024);
    pack_b_k<<<(512 * 64  + 255) / 256, 256, 0, stream>>>(f2w, W2P, 512, 512, 512);
    pack_b_k<<<(512 * 48  + 255) / 256, 256, 0, stream>>>(pw,  PWP, Nc, 512, KPAD);

    for (int s = 0; s < 2; s++) {
        // per-s weight packs
        pack_b_k<<<(1536 * 64 + 255) / 256, 256, 0, stream>>>(wqkv[s], QKVP, 512, 1536, 512);
        pack_b_k<<<(2048 * 64 + 255) / 256, 256, 0, stream>>>(ffn_w1 + (size_t)s * Hc * 4 * Hc, F1P, 512, 2048, 512);
        pack_b_k<<<(512 * 256 + 255) / 256, 256, 0, stream>>>(ffn_w2 + (size_t)s * 4 * Hc * Hc, F2P, 2048, 512, 2048);

        ln_bf_k<<<ROWS_BN, 256, 0, stream>>>(x[s], ln_g + s * Hc, ln_b + s * Hc, Zb);
        hipMemsetAsync(MASS, 0, 320 * sizeof(float), stream);
        wg_stats_k<<<dim3(Bc * (Pc + 1), WGS_SPLIT), 256, 0, stream>>>(
            pri[s], conn[s], MASS, DOT, NRMP, NRMC);
        wg_sw_k<<<1, 64, 0, stream>>>(MASS, DOT, NRMP, NRMC, SW, INVM);

        // ---- weight-gen pipeline, chunked over batches ----
        for (int c = 0; c < NCHUNK; c++) {
            const float* pric = pri[s] + (size_t)c * ROWS_WG * Nc;
            const short* Zc = Zb + (size_t)c * ROWS_CHUNK * Hc;
            // xe @ f1w[512:1024] -> ZFc (fp32, consumed in EPI3)
            launch_g2<0, 1, 0>(Zc, W1P + 512, ZFc, ROWS_CHUNK, Hc, Hc, Hc, 1024,
                               nullptr, nullptr, 0, nullptr, 0, stream);
            // pri -> bf16 pack, then pri @ pw (EPI4: *invmass + bias)
            pack_pri_k<<<gPACK, 256, 0, stream>>>(pric, PRIB, ROWS_WG);
            launch_g2<4, 1, 0>(PRIB, PWP, PEc, ROWS_WG, Hc, KPAD, KPAD, KPAD,
                               pb, INVM + c * CB * Pc, Nc, nullptr, 0, stream);
            fused_nh_k<<<gCHK, eb, 0, stream>>>(PEc, SW + c * CB * Pc, FN + (size_t)c * CHUNK_NH, CHUNK_NH);
            // pe @ f1w[0:512] + b + ZFc -> gelu -> H1B (bf16)
            launch_g2<3, 0, 1>(PEc, W1P, H1B, ROWS_WG, Hc, Hc, Hc, 1024,
                               f1b, nullptr, 0, ZFc, Nc, stream);
            // H1 @ f2w + b -> PEc (fp32 for fused/tokens)
            launch_g2<1, 1, 0>(H1B, W2P, PEc, ROWS_WG, Hc, Hc, Hc, Hc,
                               f2b, nullptr, 0, nullptr, 0, stream);
            tokens_part_k<<<dim3(CB * Pc, TSPLIT), 512, 0, stream>>>(PEc, TOKP);
            tokens_red_k<<<CB * Pc, 512, 0, stream>>>(TOKP, TOK + (size_t)c * CB * Pc * Hc);
        }
        {
            dim3 grid(1536 / 128, 1);
            bgemm_k<1><<<grid, 256, 0, stream>>>(TOK, ipw, QKVWG, Bc * Pc, 3 * Hc, Hc,
                                                 ipb, nullptr, 0, nullptr, 0, 0);
        }
        wg_attn_k<<<Bc, 64, 0, stream>>>(QKVWG, out + OUT_AW + (size_t)s * (Bc * Pc), MSUM);

        // ---- main attention, chunked over batches ----
        for (int c = 0; c < NCHUNK; c++) {
            const short* Zc = Zb + (size_t)c * ROWS_CHUNK * Hc;
            launch_g2<0, 1, 0>(Zc, QKVP, QKVc, ROWS_CHUNK, 3 * Hc, Hc, Hc, Hc,
                               nullptr, nullptr, 0, nullptr, 0, stream);
            fattn_k<<<dim3((Nc + AQT - 1) / AQT, NHc, CB), 256, 0, stream>>>(
                QKVc, conn[s], MSUM, alpha, c * CB, CTX);
        }
        add3_k<<<gBNH, eb, 0, stream>>>(x[s], CTX, FN, BNH);

        // ---- FFN, chunked rows ----
        ln_bf_k<<<ROWS_BN, 256, 0, stream>>>(CTX, ln_g + (2 + s) * Hc, ln_b + (2 + s) * Hc, Zb);
        for (int c = 0; c < NCHUNK; c++) {
            const short* Zc = Zb + (size_t)c * ROWS_CHUNK * Hc;
            launch_g2<2, 1, 1>(Zc, F1P, HIDB, ROWS_CHUNK, 4 * Hc, Hc, Hc, Hc,
                               ffn_b1 + (size_t)s * 4 * Hc, nullptr, 0, nullptr, 0, stream);
            launch_g2<1, 1, 0>(HIDB, F2P, FFNOUT + (size_t)c * ROWS_CHUNK * Hc,
                               ROWS_CHUNK, Hc, 4 * Hc, 4 * Hc, 4 * Hc,
                               ffn_b2 + (size_t)s * Hc, nullptr, 0, nullptr, 0, stream);
            // NOTE: HIDB reused per chunk; FFNOUT accumulated per chunk region
        }
        if (s == 0) {
            final_k<<<gBNH, eb, 0, stream>>>(CTX, FFNOUT, dw, out, PROJ0, BNH);
        } else {
            final_kl_k<<<ROWS_BN, 256, 0, stream>>>(CTX, FFNOUT, dw, PROJ0, out + BNH, KLACC);
        }
    }
    kl_final_k<<<1, 1, 0, stream>>>(KLACC, out + OUT_DISTILL);
}

// Round 4
// 3082.899 us; speedup vs baseline: 2.4686x; 1.0094x over previous
//
#include <hip/hip_runtime.h>
#include <math.h>

// ---------------- constants ----------------
#define Bc   32
#define Nc   379
#define Hc   512
#define NHc  8
#define Pc   3
#define HDc  64          // H/NH
#define NNc  (Nc*Nc)     // 143641
#define CB   8           // batch chunk
#define NCHUNK 4
static const size_t NH_f  = (size_t)Nc*Hc;           // 194,048
static const size_t BNH   = (size_t)Bc*Nc*Hc;        // 6,207,488
#define ROWS_BN   12128   // B*N
#define ROWS_CHUNK 3032   // CB*N
#define ROWS_WG    9096   // CB*P*N
static const size_t CHUNK_NH = (size_t)CB*Nc*Hc;     // 1,552,384
static const size_t PEC_SZ   = (size_t)ROWS_WG*Hc;   // 4,657,152

#define WGS_SPLIT 16     // blocks per (b,r) row in wg_stats
#define TSPLIT 16        // n-splits in tokens reduction
#define KPAD 384         // pri K (379) padded to multiple of 32

typedef __attribute__((ext_vector_type(8))) short bf16x8;
typedef __attribute__((ext_vector_type(4))) short bf16x4;
typedef __attribute__((ext_vector_type(4))) float f32x4;

__device__ inline float gelu_f(float x) {
    return 0.5f * x * (1.0f + erff(x * 0.7071067811865476f));
}

// fp32 -> bf16 bits, round-to-nearest-even
__device__ inline short f2bf(float f) {
    unsigned u = __float_as_uint(f);
    unsigned r = u + 0x7fffu + ((u >> 16) & 1u);
    return (short)(r >> 16);
}

// wave (64-lane) reductions — no LDS, no barriers
__device__ inline float wave_sum(float v) {
#pragma unroll
    for (int off = 32; off; off >>= 1) v += __shfl_xor(v, off, 64);
    return v;
}
__device__ inline float wave_max(float v) {
#pragma unroll
    for (int off = 32; off; off >>= 1) v = fmaxf(v, __shfl_xor(v, off, 64));
    return v;
}

// block reduction (blockDim == 256) — still used by wg_stats
__device__ inline float blk_sum(float v, float* sh) {
#pragma unroll
    for (int off = 32; off; off >>= 1) v += __shfl_xor(v, off, 64);
    int w = threadIdx.x >> 6;
    __syncthreads();
    if ((threadIdx.x & 63) == 0) sh[w] = v;
    __syncthreads();
    return sh[0] + sh[1] + sh[2] + sh[3];
}

// ---------------- weight pre-pack: fp32 [K][N] -> bf16 [N][KP] (zero pad k>=K) ----------------
__global__ __launch_bounds__(256) void pack_b_k(const float* __restrict__ src,
                                                short* __restrict__ dst,
                                                int K, int N, int KP) {
    int idx = blockIdx.x * blockDim.x + threadIdx.x;
    int total = N * (KP / 8);
    if (idx >= total) return;
    int k8 = idx / N;            // consecutive tid -> consecutive n (coalesced)
    int n  = idx % N;
    int k0 = k8 * 8;
    bf16x8 v;
#pragma unroll
    for (int j = 0; j < 8; j++) {
        int k = k0 + j;
        v[j] = (k < K) ? f2bf(src[(size_t)k * N + n]) : (short)0;
    }
    *(bf16x8*)(dst + (size_t)n * KP + k0) = v;
}

// ---------------- pri pre-pack: fp32 [rows][379] -> bf16 [rows][384] (zero pad) ----------------
__global__ __launch_bounds__(256) void pack_pri_k(const float* __restrict__ src,
                                                  short* __restrict__ dst, int rows) {
    int idx = blockIdx.x * blockDim.x + threadIdx.x;
    int total = rows * (KPAD / 8);
    if (idx >= total) return;
    int row = idx / (KPAD / 8);
    int c8  = (idx % (KPAD / 8)) * 8;
    const float* s = src + (size_t)row * Nc + c8;
    bf16x8 v;
#pragma unroll
    for (int j = 0; j < 8; j++) v[j] = (c8 + j < Nc) ? f2bf(s[j]) : (short)0;
    *(bf16x8*)(dst + (size_t)row * KPAD + c8) = v;
}

// ---------------- g2: bf16 MFMA GEMM, packed-B, double-buffered, reg-prefetch ----------------
#define GBM 64
#define GBN 128
#define GBK 32
#define GLD 40   // LDS row stride in shorts

template<int EPI, int ABF, int CBF>
__global__ __launch_bounds__(256) void g2_k(
    const void* __restrict__ Ap, const short* __restrict__ Bp, void* __restrict__ Cp,
    int M, int N, int K, int KSA, int KSB,
    const float* __restrict__ bias,
    const float* __restrict__ rowscale, int rs_div,
    const float* __restrict__ addsrc, int addN)
{
    __shared__ __attribute__((aligned(16))) short As[2][GBM * GLD];
    __shared__ __attribute__((aligned(16))) short Bs[2][GBN * GLD];
    int tid = threadIdx.x;
    int wave = tid >> 6, lane = tid & 63;
    int wr = wave >> 1, wc = wave & 1;          // 2x2 waves; wave tile 32(m) x 64(n)
    int quad = lane >> 4, l16 = lane & 15;
    int m0 = blockIdx.y * GBM, n0 = blockIdx.x * GBN;

    int a_r = tid >> 2, a_k = (tid & 3) * 8;    // A: 64 rows x 32k, 8 elems/thread
    int b_n = tid >> 1, b_k = (tid & 1) * 16;   // B: 128 n x 32k, 16 elems/thread

    const float* Af = (const float*)Ap;
    const short* Ab = (const short*)Ap;

    f32x4 acc[2][4] = {};
    int nk = K / GBK;

    float4 ra0, ra1; bf16x8 rab; bf16x8 rb0, rb1;

    auto loadT = [&](int k0) {
        int gm = m0 + a_r;
        if (ABF) {
            rab = (bf16x8){0, 0, 0, 0, 0, 0, 0, 0};
            if (gm < M) rab = *(const bf16x8*)(Ab + (size_t)gm * KSA + k0 + a_k);
        } else {
            ra0 = make_float4(0.f, 0.f, 0.f, 0.f); ra1 = ra0;
            if (gm < M) {
                const float* s = Af + (size_t)gm * KSA + k0 + a_k;
                ra0 = *(const float4*)s; ra1 = *(const float4*)(s + 4);
            }
        }
        const short* bs = Bp + (size_t)(n0 + b_n) * KSB + k0 + b_k;
        rb0 = *(const bf16x8*)bs; rb1 = *(const bf16x8*)(bs + 8);
    };
    auto storeT = [&](int buf) {
        short* ad = &As[buf][a_r * GLD + a_k];
        if (ABF) {
            *(bf16x8*)ad = rab;
        } else {
            bf16x8 t;
            t[0] = f2bf(ra0.x); t[1] = f2bf(ra0.y); t[2] = f2bf(ra0.z); t[3] = f2bf(ra0.w);
            t[4] = f2bf(ra1.x); t[5] = f2bf(ra1.y); t[6] = f2bf(ra1.z); t[7] = f2bf(ra1.w);
            *(bf16x8*)ad = t;
        }
        short* bd = &Bs[buf][b_n * GLD + b_k];
        *(bf16x8*)bd = rb0; *(bf16x8*)(bd + 8) = rb1;
    };

    loadT(0);
    storeT(0);
    __syncthreads();

    for (int it = 0; it < nk; ++it) {
        int cur = it & 1;
        if (it + 1 < nk) loadT((it + 1) * GBK);   // prefetch in flight over MFMA below
        bf16x8 afr[2], bfr[4];
#pragma unroll
        for (int mt = 0; mt < 2; mt++)
            afr[mt] = *(const bf16x8*)&As[cur][(wr * 32 + mt * 16 + l16) * GLD + quad * 8];
#pragma unroll
        for (int nt = 0; nt < 4; nt++)
            bfr[nt] = *(const bf16x8*)&Bs[cur][(wc * 64 + nt * 16 + l16) * GLD + quad * 8];
#pragma unroll
        for (int mt = 0; mt < 2; mt++)
#pragma unroll
            for (int nt = 0; nt < 4; nt++)
                acc[mt][nt] = __builtin_amdgcn_mfma_f32_16x16x32_bf16(
                    afr[mt], bfr[nt], acc[mt][nt], 0, 0, 0);
        if (it + 1 < nk) {
            storeT(cur ^ 1);
            __syncthreads();
        }
    }

    // epilogue: C/D layout col=l16, row=quad*4+r
#pragma unroll
    for (int mt = 0; mt < 2; mt++) {
#pragma unroll
        for (int nt = 0; nt < 4; nt++) {
#pragma unroll
            for (int r = 0; r < 4; r++) {
                int gm = m0 + wr * 32 + mt * 16 + quad * 4 + r;
                int gn = n0 + wc * 64 + nt * 16 + l16;
                if (gm < M) {
                    float v = acc[mt][nt][r];
                    if (EPI == 1 || EPI == 2 || EPI == 3) v += bias[gn];
                    if (EPI == 4) v = v * rowscale[gm / rs_div] + bias[gn];
                    if (EPI == 3) {
                        int addrow = (gm / (3 * addN)) * addN + (gm % addN);
                        v += addsrc[(size_t)addrow * N + gn];
                    }
                    if (EPI == 2 || EPI == 3) v = gelu_f(v);
                    if (CBF) ((short*)Cp)[(size_t)gm * N + gn] = f2bf(v);
                    else     ((float*)Cp)[(size_t)gm * N + gn] = v;
                }
            }
        }
    }
}

template<int EPI, int ABF, int CBF>
static void launch_g2(const void* A, const short* B, void* C, int M, int N, int K,
                      int KSA, int KSB, const float* bias,
                      const float* rowscale, int rs_div,
                      const float* addsrc, int addN, hipStream_t st) {
    dim3 grid(N / GBN, (M + GBM - 1) / GBM);
    g2_k<EPI, ABF, CBF><<<grid, 256, 0, st>>>(A, B, C, M, N, K, KSA, KSB,
                                              bias, rowscale, rs_div, addsrc, addN);
}

// ---------------- LayerNorm: one wave per 512-row, no barriers ----------------
__global__ __launch_bounds__(256) void lnw_bf_k(const float* __restrict__ x,
                                                const float* __restrict__ g,
                                                const float* __restrict__ b,
                                                short* __restrict__ z) {
    int r = blockIdx.x * 4 + (threadIdx.x >> 6);
    int lane = threadIdx.x & 63;
    int d = lane * 4;
    const float* xr = x + (size_t)r * Hc;
    float4 v0 = *(const float4*)(xr + d);
    float4 v1 = *(const float4*)(xr + d + 256);
    const float* p0 = (const float*)&v0;
    const float* p1 = (const float*)&v1;
    float s = 0.f, sq = 0.f;
#pragma unroll
    for (int j = 0; j < 4; j++) {
        s += p0[j] + p1[j];
        sq += p0[j] * p0[j] + p1[j] * p1[j];
    }
    s = wave_sum(s);
    sq = wave_sum(sq);
    float mean = s * (1.f / Hc);
    float var  = sq * (1.f / Hc) - mean * mean;
    float inv  = rsqrtf(var + 1e-5f);
    float4 g0 = *(const float4*)(g + d), g1 = *(const float4*)(g + d + 256);
    float4 b0 = *(const float4*)(b + d), b1 = *(const float4*)(b + d + 256);
    const float* gp0 = (const float*)&g0; const float* gp1 = (const float*)&g1;
    const float* bp0 = (const float*)&b0; const float* bp1 = (const float*)&b1;
    bf16x4 o0, o1;
#pragma unroll
    for (int j = 0; j < 4; j++) {
        o0[j] = f2bf((p0[j] - mean) * inv * gp0[j] + bp0[j]);
        o1[j] = f2bf((p1[j] - mean) * inv * gp1[j] + bp1[j]);
    }
    short* zr = z + (size_t)r * Hc;
    *(bf16x4*)(zr + d)       = o0;
    *(bf16x4*)(zr + d + 256) = o1;
}

// ---------------- weight-gen stats (split + atomic partials) ----------------
__global__ __launch_bounds__(256) void wg_stats_k(const float* __restrict__ pri,
                                                  const float* __restrict__ conn,
                                                  float* __restrict__ mass, float* __restrict__ dot,
                                                  float* __restrict__ nrmp, float* __restrict__ nrmc) {
    __shared__ float sh[4];
    int bp = blockIdx.x;
    int sp = blockIdx.y;
    int b = bp >> 2, r = bp & 3;   // P+1 == 4
    const int per = (NNc + WGS_SPLIT - 1) / WGS_SPLIT;
    int i0 = sp * per;
    int i1 = i0 + per; if (i1 > NNc) i1 = NNc;
    const float* c = conn + (size_t)b * NNc;
    if (r < Pc) {
        const float* p = pri + (size_t)(b * Pc + r) * NNc;
        float sa = 0, sq = 0, sd = 0;
        for (int i = i0 + threadIdx.x; i < i1; i += 256) {
            float pv = p[i], cv = c[i];
            sa += fabsf(pv); sq += pv * pv; sd += pv * cv;
        }
        sa = blk_sum(sa, sh);
        sq = blk_sum(sq, sh);
        sd = blk_sum(sd, sh);
        if (threadIdx.x == 0) {
            atomicAdd(&mass[b * Pc + r], sa);
            atomicAdd(&nrmp[b * Pc + r], sq);
            atomicAdd(&dot[b * Pc + r], sd);
        }
    } else {
        float sq = 0;
        for (int i = i0 + threadIdx.x; i < i1; i += 256) { float cv = c[i]; sq += cv * cv; }
        sq = blk_sum(sq, sh);
        if (threadIdx.x == 0) atomicAdd(&nrmc[b], sq);
    }
}

__global__ void wg_sw_k(const float* mass, const float* dot, const float* nrmp, const float* nrmc,
                        float* sw, float* invm) {
    int b = threadIdx.x;
    if (b >= Bc) return;
    float nc = fmaxf(sqrtf(nrmc[b]), 1e-12f);
    float s[Pc];
    for (int p = 0; p < Pc; p++) s[p] = dot[b * Pc + p] / (nc * fmaxf(sqrtf(nrmp[b * Pc + p]), 1e-12f));
    float m = fmaxf(s[0], fmaxf(s[1], s[2]));
    float e[Pc], sum = 0;
    for (int p = 0; p < Pc; p++) { e[p] = expf(s[p] - m); sum += e[p]; }
    for (int p = 0; p < Pc; p++) {
        sw[b * Pc + p] = e[p] / sum;
        invm[b * Pc + p] = 1.f / mass[b * Pc + p];
    }
}

// ---------------- fused_nh: float4 vectorized ----------------
__global__ void fused_nhv_k(const float4* __restrict__ PE4, const float* __restrict__ swp,
                            float4* __restrict__ FN4, size_t count4) {
    size_t idx = (size_t)blockIdx.x * blockDim.x + threadIdx.x;
    if (idx >= count4) return;
    const size_t row4 = NH_f / 4;
    int bl = (int)(idx / row4);
    size_t within = idx % row4;
    const float* sw = swp + bl * Pc;
    size_t base = (size_t)bl * 3 * row4 + within;
    float4 a = PE4[base], b = PE4[base + row4], c = PE4[base + 2 * row4];
    float4 o;
    o.x = sw[0] * a.x + sw[1] * b.x + sw[2] * c.x;
    o.y = sw[0] * a.y + sw[1] * b.y + sw[2] * c.y;
    o.z = sw[0] * a.z + sw[1] * b.z + sw[2] * c.z;
    o.w = sw[0] * a.w + sw[1] * b.w + sw[2] * c.w;
    FN4[idx] = o;
}

// ---------------- tokens: mean over N, split ----------------
__global__ __launch_bounds__(512) void tokens_part_k(const float* __restrict__ F2,
                                                     float* __restrict__ TOKP) {
    int bp = blockIdx.x, sp = blockIdx.y, h = threadIdx.x;
    const int rows = (Nc + TSPLIT - 1) / TSPLIT;
    int n0 = sp * rows;
    int n1 = n0 + rows; if (n1 > Nc) n1 = Nc;
    const float* base = F2 + (size_t)bp * NH_f + h;
    float s = 0;
    for (int n = n0; n < n1; n++) s += base[(size_t)n * Hc];
    TOKP[((size_t)bp * TSPLIT + sp) * Hc + h] = s;
}

__global__ __launch_bounds__(512) void tokens_red_k(const float* __restrict__ TOKP,
                                                    float* __restrict__ TOK) {
    int bp = blockIdx.x, h = threadIdx.x;
    float s = 0;
#pragma unroll
    for (int sp = 0; sp < TSPLIT; sp++) s += TOKP[((size_t)bp * TSPLIT + sp) * Hc + h];
    TOK[(size_t)bp * Hc + h] = s * (1.0f / (float)Nc);
}

__global__ __launch_bounds__(64) void wg_attn_k(const float* __restrict__ QW,
                                                float* __restrict__ aw_out, float* __restrict__ msum) {
    int b = blockIdx.x, lane = threadIdx.x;
    float s[4][Pc][Pc];
    for (int h = 0; h < 4; h++)
        for (int i = 0; i < Pc; i++)
            for (int j = 0; j < Pc; j++) {
                const float* q = QW + (size_t)(b * Pc + i) * 1536 + h * 128;
                const float* k = QW + (size_t)(b * Pc + j) * 1536 + 512 + h * 128;
                float p = q[lane] * k[lane] + q[lane + 64] * k[lane + 64];
#pragma unroll
                for (int off = 32; off; off >>= 1) p += __shfl_xor(p, off, 64);
                s[h][i][j] = p * 0.08838834764831845f;
            }
    float aw[Pc] = {0, 0, 0};
    for (int h = 0; h < 4; h++)
        for (int i = 0; i < Pc; i++) {
            float m = fmaxf(s[h][i][0], fmaxf(s[h][i][1], s[h][i][2]));
            float e0 = expf(s[h][i][0] - m), e1 = expf(s[h][i][1] - m), e2 = expf(s[h][i][2] - m);
            float inv = 1.f / (e0 + e1 + e2);
            aw[0] += e0 * inv; aw[1] += e1 * inv; aw[2] += e2 * inv;
        }
    for (int j = 0; j < Pc; j++) aw[j] *= (1.f / 12.f);
    float m2 = fmaxf(aw[0], fmaxf(aw[1], aw[2]));
    float e0 = expf((aw[0] - m2) * 100.f), e1 = expf((aw[1] - m2) * 100.f), e2 = expf((aw[2] - m2) * 100.f);
    float inv = 1.f / (e0 + e1 + e2);
    if (lane == 0) {
        aw_out[b * Pc + 0] = e0 * inv;
        aw_out[b * Pc + 1] = e1 * inv;
        aw_out[b * Pc + 2] = e2 * inv;
        msum[b] = (e0 + e1 + e2) * inv;
    }
}

// ---------------- flash attention ----------------
#define AQT 32
__global__ __launch_bounds__(256) void fattn_k(const float* __restrict__ QKVc,
                                               const float* __restrict__ conn,
                                               const float* __restrict__ msum,
                                               const float* __restrict__ alpha,
                                               int b0, float* __restrict__ ctx) {
    __shared__ float Qs[AQT][66];
    __shared__ float Ks[64][66];
    __shared__ float Vs[64][66];
    __shared__ float Es[AQT][66];
    int i0 = blockIdx.x * AQT;
    int h = blockIdx.y, bl = blockIdx.z;
    int b = b0 + bl;
    int t = threadIdx.x;
    int q = t >> 3, sub = t & 7;
    int gi = i0 + q;
    float a2 = 0.5f * alpha[0];
    float mterm = a2 * msum[b];
    {
        int src_row = (gi < Nc) ? gi : (Nc - 1);
        int d0 = sub * 8;
        const float* src = QKVc + ((size_t)bl * Nc + src_row) * 1536 + h * HDc + d0;
        *(float4*)&Qs[q][d0]     = *(const float4*)src;
        *(float4*)&Qs[q][d0 + 4] = *(const float4*)(src + 4);
    }
    const float* Crow = conn + ((size_t)b * Nc + (gi < Nc ? gi : Nc - 1)) * Nc;
    float m_run = -3.4e38f, l_run = 0.f;
    float acc[8] = {0.f, 0.f, 0.f, 0.f, 0.f, 0.f, 0.f, 0.f};

    for (int jt = 0; jt < 6; jt++) {
        __syncthreads();
        {
            int j = t >> 2, d0 = (t & 3) * 16;
            int gj = jt * 64 + j;
            int sr = (gj < Nc) ? gj : (Nc - 1);
            const float* kp = QKVc + ((size_t)bl * Nc + sr) * 1536 + Hc + h * HDc + d0;
            const float* vp = kp + Hc;
            *(float4*)&Ks[j][d0]      = *(const float4*)(kp);
            *(float4*)&Ks[j][d0 + 4]  = *(const float4*)(kp + 4);
            *(float4*)&Ks[j][d0 + 8]  = *(const float4*)(kp + 8);
            *(float4*)&Ks[j][d0 + 12] = *(const float4*)(kp + 12);
            *(float4*)&Vs[j][d0]      = *(const float4*)(vp);
            *(float4*)&Vs[j][d0 + 4]  = *(const float4*)(vp + 4);
            *(float4*)&Vs[j][d0 + 8]  = *(const float4*)(vp + 8);
            *(float4*)&Vs[j][d0 + 12] = *(const float4*)(vp + 12);
        }
        __syncthreads();
        float s[8] = {0.f, 0.f, 0.f, 0.f, 0.f, 0.f, 0.f, 0.f};
#pragma unroll 4
        for (int d4 = 0; d4 < 16; d4++) {
            float4 qv = *(float4*)&Qs[q][d4 * 4];
#pragma unroll
            for (int jj = 0; jj < 8; jj++) {
                float4 kv = *(float4*)&Ks[sub + 8 * jj][d4 * 4];
                s[jj] += qv.x * kv.x + qv.y * kv.y + qv.z * kv.z + qv.w * kv.w;
            }
        }
        float tile_max = -3.4e38f;
#pragma unroll
        for (int jj = 0; jj < 8; jj++) {
            int gj = jt * 64 + sub + 8 * jj;
            if (gj < Nc && gi < Nc) {
                float mk = tanhf(mterm + (1.f - a2) * Crow[gj]);
                s[jj] = s[jj] * 0.125f * (1.f + mk);
            } else s[jj] = -3.4e38f;
            tile_max = fmaxf(tile_max, s[jj]);
        }
#pragma unroll
        for (int off = 1; off < 8; off <<= 1)
            tile_max = fmaxf(tile_max, __shfl_xor(tile_max, off, 64));
        float m_new = fmaxf(m_run, tile_max);
        float esum = 0.f;
#pragma unroll
        for (int jj = 0; jj < 8; jj++) {
            float e = __expf(s[jj] - m_new);
            Es[q][sub + 8 * jj] = e;
            esum += e;
        }
#pragma unroll
        for (int off = 1; off < 8; off <<= 1)
            esum += __shfl_xor(esum, off, 64);
        float scl = __expf(m_run - m_new);
        l_run = l_run * scl + esum;
        m_run = m_new;
        __syncthreads();
#pragma unroll
        for (int dd = 0; dd < 8; dd++) acc[dd] *= scl;
        int d0 = sub * 8;
#pragma unroll 4
        for (int j4 = 0; j4 < 16; j4++) {
            float4 ev = *(float4*)&Es[q][j4 * 4];
#pragma unroll
            for (int u = 0; u < 4; u++) {
                float e = (u == 0) ? ev.x : (u == 1) ? ev.y : (u == 2) ? ev.z : ev.w;
                float4 v0 = *(float4*)&Vs[j4 * 4 + u][d0];
                float4 v1 = *(float4*)&Vs[j4 * 4 + u][d0 + 4];
                acc[0] += e * v0.x; acc[1] += e * v0.y; acc[2] += e * v0.z; acc[3] += e * v0.w;
                acc[4] += e * v1.x; acc[5] += e * v1.y; acc[6] += e * v1.z; acc[7] += e * v1.w;
            }
        }
    }
    if (gi < Nc) {
        float inv = 1.f / l_run;
        float* dst = ctx + ((size_t)b * Nc + gi) * Hc + h * HDc + sub * 8;
        float4 o0 = make_float4(acc[0] * inv, acc[1] * inv, acc[2] * inv, acc[3] * inv);
        float4 o1 = make_float4(acc[4] * inv, acc[5] * inv, acc[6] * inv, acc[7] * inv);
        *(float4*)dst = o0;
        *(float4*)(dst + 4) = o1;
    }
}

// ---------------- vectorized elementwise ----------------
__global__ void add3v_k(const float4* __restrict__ x, float4* __restrict__ ctx,
                        const float4* __restrict__ fn, size_t count4) {
    size_t idx = (size_t)blockIdx.x * blockDim.x + threadIdx.x;
    if (idx >= count4) return;
    float4 a = x[idx], c = ctx[idx], f = fn[idx];
    float4 o;
    o.x = a.x + c.x + f.x; o.y = a.y + c.y + f.y;
    o.z = a.z + c.z + f.z; o.w = a.w + c.w + f.w;
    ctx[idx] = o;
}

__global__ void finalv_k(const float4* __restrict__ AO, const float4* __restrict__ FF,
                         const float* __restrict__ dw,
                         float4* __restrict__ xout, float4* __restrict__ proj, size_t count4) {
    size_t idx = (size_t)blockIdx.x * blockDim.x + threadIdx.x;
    if (idx >= count4) return;
    float w = dw[0];
    float4 ff = FF[idx], ao = AO[idx];
    float4 xn, pr;
    xn.x = ao.x + ff.x; xn.y = ao.y + ff.y; xn.z = ao.z + ff.z; xn.w = ao.w + ff.w;
    pr.x = w * ff.x + (1.f - w) * xn.x; pr.y = w * ff.y + (1.f - w) * xn.y;
    pr.z = w * ff.z + (1.f - w) * xn.z; pr.w = w * ff.w + (1.f - w) * xn.w;
    xout[idx] = xn;
    proj[idx] = pr;
}

// ---------------- final KL: one wave per 512-row, no barriers ----------------
__global__ __launch_bounds__(256) void final_klw_k(const float* __restrict__ AO,
                                                   const float* __restrict__ FF,
                                                   const float* __restrict__ dw,
                                                   const float* __restrict__ PF,
                                                   float* __restrict__ xout,
                                                   float* __restrict__ acc) {
    int r = blockIdx.x * 4 + (threadIdx.x >> 6);
    int lane = threadIdx.x & 63;
    int d = lane * 4;
    size_t base = (size_t)r * Hc;
    float w = dw[1];
    float4 ff0 = *(const float4*)(FF + base + d), ff1 = *(const float4*)(FF + base + d + 256);
    float4 ao0 = *(const float4*)(AO + base + d), ao1 = *(const float4*)(AO + base + d + 256);
    float4 pf0 = *(const float4*)(PF + base + d), pf1 = *(const float4*)(PF + base + d + 256);
    float ff[8], ao[8], pf[8];
    *(float4*)&ff[0] = ff0; *(float4*)&ff[4] = ff1;
    *(float4*)&ao[0] = ao0; *(float4*)&ao[4] = ao1;
    *(float4*)&pf[0] = pf0; *(float4*)&pf[4] = pf1;
    float xn[8], sv[8];
    float mf = -3.4e38f, ms = -3.4e38f;
#pragma unroll
    for (int j = 0; j < 8; j++) {
        xn[j] = ao[j] + ff[j];
        sv[j] = w * ff[j] + (1.f - w) * xn[j];
        mf = fmaxf(mf, pf[j]);
        ms = fmaxf(ms, sv[j]);
    }
    *(float4*)(xout + base + d)       = *(float4*)&xn[0];
    *(float4*)(xout + base + d + 256) = *(float4*)&xn[4];
    mf = wave_max(mf);
    ms = wave_max(ms);
    float ef = 0.f, es = 0.f;
#pragma unroll
    for (int j = 0; j < 8; j++) {
        ef += expf(pf[j] - mf);
        es += expf(sv[j] - ms);
    }
    ef = wave_sum(ef);
    es = wave_sum(es);
    float lsef = mf + logf(ef), lses = ms + logf(es);
    float ts = 0.f;
#pragma unroll
    for (int j = 0; j < 8; j++) {
        float lf = pf[j] - lsef, ls = sv[j] - lses;
        ts += expf(ls) * (ls - lf) + expf(lf) * (lf - ls);
    }
    ts = wave_sum(ts);
    if (lane == 0) atomicAdd(acc, ts);
}

__global__ void kl_final_k(const float* __restrict__ acc, float* __restrict__ out) {
    out[0] = 0.5f * acc[0] * (1.0f / (float)ROWS_BN);
}

// ---------------- launch ----------------
extern "C" void kernel_launch(void* const* d_in, const int* in_sizes, int n_in,
                              void* d_out, int out_size, void* d_ws, size_t ws_size,
                              hipStream_t stream) {
    (void)in_sizes; (void)n_in; (void)out_size; (void)ws_size;
    const float* x[2]    = {(const float*)d_in[0], (const float*)d_in[1]};
    const float* pri[2]  = {(const float*)d_in[2], (const float*)d_in[3]};
    const float* conn[2] = {(const float*)d_in[4], (const float*)d_in[5]};
    const float* dw      = (const float*)d_in[6];
    const float* wqkv[2] = {(const float*)d_in[7], (const float*)d_in[8]};
    const float* ln_g    = (const float*)d_in[9];
    const float* ln_b    = (const float*)d_in[10];
    const float* ffn_w1  = (const float*)d_in[11];
    const float* ffn_b1  = (const float*)d_in[12];
    const float* ffn_w2  = (const float*)d_in[13];
    const float* ffn_b2  = (const float*)d_in[14];
    const float* pw      = (const float*)d_in[15];
    const float* pb      = (const float*)d_in[16];
    const float* f1w     = (const float*)d_in[17];
    const float* f1b     = (const float*)d_in[18];
    const float* f2w     = (const float*)d_in[19];
    const float* f2b     = (const float*)d_in[20];
    const float* ipw     = (const float*)d_in[21];
    const float* ipb     = (const float*)d_in[22];
    const float* alpha   = (const float*)d_in[23];
    float* out = (float*)d_out;

    // --- workspace arena ---
    float* W = (float*)d_ws;
    size_t o = 0;
    auto alloc = [&](size_t n) { float* p = W + o; o += n; return p; };
    float* Z     = alloc(BNH);               // bf16 Z lives here (half used)
    float* CTX   = alloc(BNH);
    float* FN    = alloc(BNH);
    float* PROJ0 = alloc(BNH);
    float* R     = alloc(12417024);          // shared transient region
    float* TOK   = alloc((size_t)96 * Hc);
    float* QKVWG = alloc((size_t)96 * 1536);
    float* MASS  = alloc(96); float* DOT = alloc(96); float* NRMP = alloc(96);
    float* NRMC  = alloc(32); float* SW  = alloc(96); float* INVM = alloc(96);
    float* MSUM  = alloc(32);
    float* KLACC = alloc(1);
    // bf16 weight packs (persistent across launch)
    short* W1P  = (short*)alloc(262144);     // f1w  [512n][1024k]
    short* W2P  = (short*)alloc(131072);     // f2w  [512n][512k]
    short* PWP  = (short*)alloc(98304);      // pw   [512n][384k]
    short* IPP  = (short*)alloc(393216);     // ipw  [1536n][512k]
    short* QKVP = (short*)alloc(393216);     // wqkv[s] [1536n][512k]
    short* F1P  = (short*)alloc(524288);     // ffn_w1[s] [2048n][512k]
    short* F2P  = (short*)alloc(524288);     // ffn_w2[s] [512n][2048k]

    // R overlays (disjoint lifetimes):
    float* PEc  = R;                               // 4,657,152 fl
    short* H1B  = (short*)(R + PEC_SZ);            // 9096x512 bf16 = 2,328,576 fl
    float* ZFc  = R + PEC_SZ + 2328576;            // 1,552,384 fl
    float* QKVc = R;                               // 4,657,152 fl
    short* HIDB = (short*)R;                       // 3032x2048 bf16 = 3,104,768 fl
    float* FFNOUT = R + 6209536;                   // 6,207,488 fl
    float* TOKP = R + PEC_SZ;                      // tokens partials (H1B dead by then)
    short* PRIB = (short*)CTX;                     // packed pri chunk (CTX dead till fattn)
    short* Zb   = (short*)Z;                       // bf16 ln output [12128][512]

    const size_t OUT_DISTILL = 2 * BNH;
    const size_t OUT_AW = 2 * BNH + 1;

    hipMemsetAsync(KLACC, 0, sizeof(float), stream);

    int eb = 256;
    size_t cnt4BNH = BNH / 4;                        // 1,551,872
    int g4BNH = (int)((cnt4BNH + eb - 1) / eb);      // 6062
    size_t cnt4CHK = CHUNK_NH / 4;                   // 388,096
    int g4CHK = (int)((cnt4CHK + eb - 1) / eb);      // 1516
    int gPACK = (ROWS_WG * (KPAD / 8) + 255) / 256;
    int gLNW = ROWS_BN / 4;                          // 3032

    // one-time weight packs (shared across s)
    pack_b_k<<<(512 * 128 + 255) / 256, 256, 0, stream>>>(f1w, W1P, 1024, 512, 1024);
    pack_b_k<<<(512 * 64  + 255) / 256, 256, 0, stream>>>(f2w, W2P, 512, 512, 512);
    pack_b_k<<<(512 * 48  + 255) / 256, 256, 0, stream>>>(pw,  PWP, Nc, 512, KPAD);
    pack_b_k<<<(1536 * 64 + 255) / 256, 256, 0, stream>>>(ipw, IPP, 512, 1536, 512);

    for (int s = 0; s < 2; s++) {
        // per-s weight packs
        pack_b_k<<<(1536 * 64 + 255) / 256, 256, 0, stream>>>(wqkv[s], QKVP, 512, 1536, 512);
        pack_b_k<<<(2048 * 64 + 255) / 256, 256, 0, stream>>>(ffn_w1 + (size_t)s * Hc * 4 * Hc, F1P, 512, 2048, 512);
        pack_b_k<<<(512 * 256 + 255) / 256, 256, 0, stream>>>(ffn_w2 + (size_t)s * 4 * Hc * Hc, F2P, 2048, 512, 2048);

        lnw_bf_k<<<gLNW, 256, 0, stream>>>(x[s], ln_g + s * Hc, ln_b + s * Hc, Zb);
        hipMemsetAsync(MASS, 0, 320 * sizeof(float), stream);
        wg_stats_k<<<dim3(Bc * (Pc + 1), WGS_SPLIT), 256, 0, stream>>>(
            pri[s], conn[s], MASS, DOT, NRMP, NRMC);
        wg_sw_k<<<1, 64, 0, stream>>>(MASS, DOT, NRMP, NRMC, SW, INVM);

        // ---- weight-gen pipeline, chunked over batches ----
        for (int c = 0; c < NCHUNK; c++) {
            const float* pric = pri[s] + (size_t)c * ROWS_WG * Nc;
            const short* Zc = Zb + (size_t)c * ROWS_CHUNK * Hc;
            // xe @ f1w[512:1024] -> ZFc (fp32, consumed in EPI3)
            launch_g2<0, 1, 0>(Zc, W1P + 512, ZFc, ROWS_CHUNK, Hc, Hc, Hc, 1024,
                               nullptr, nullptr, 0, nullptr, 0, stream);
            // pri -> bf16 pack, then pri @ pw (EPI4: *invmass + bias)
            pack_pri_k<<<gPACK, 256, 0, stream>>>(pric, PRIB, ROWS_WG);
            launch_g2<4, 1, 0>(PRIB, PWP, PEc, ROWS_WG, Hc, KPAD, KPAD, KPAD,
                               pb, INVM + c * CB * Pc, Nc, nullptr, 0, stream);
            fused_nhv_k<<<g4CHK, eb, 0, stream>>>((const float4*)PEc, SW + c * CB * Pc,
                                                  (float4*)(FN + (size_t)c * CHUNK_NH), cnt4CHK);
            // pe @ f1w[0:512] + b + ZFc -> gelu -> H1B (bf16)
            launch_g2<3, 0, 1>(PEc, W1P, H1B, ROWS_WG, Hc, Hc, Hc, 1024,
                               f1b, nullptr, 0, ZFc, Nc, stream);
            // H1 @ f2w + b -> PEc (fp32 for fused/tokens)
            launch_g2<1, 1, 0>(H1B, W2P, PEc, ROWS_WG, Hc, Hc, Hc, Hc,
                               f2b, nullptr, 0, nullptr, 0, stream);
            tokens_part_k<<<dim3(CB * Pc, TSPLIT), 512, 0, stream>>>(PEc, TOKP);
            tokens_red_k<<<CB * Pc, 512, 0, stream>>>(TOKP, TOK + (size_t)c * CB * Pc * Hc);
        }
        // TOK @ ipw -> QKVWG via g2 (A fp32 path)
        launch_g2<1, 0, 0>(TOK, IPP, QKVWG, Bc * Pc, 3 * Hc, Hc, Hc, Hc,
                           ipb, nullptr, 0, nullptr, 0, stream);
        wg_attn_k<<<Bc, 64, 0, stream>>>(QKVWG, out + OUT_AW + (size_t)s * (Bc * Pc), MSUM);

        // ---- main attention, chunked over batches ----
        for (int c = 0; c < NCHUNK; c++) {
            const short* Zc = Zb + (size_t)c * ROWS_CHUNK * Hc;
            launch_g2<0, 1, 0>(Zc, QKVP, QKVc, ROWS_CHUNK, 3 * Hc, Hc, Hc, Hc,
                               nullptr, nullptr, 0, nullptr, 0, stream);
            fattn_k<<<dim3((Nc + AQT - 1) / AQT, NHc, CB), 256, 0, stream>>>(
                QKVc, conn[s], MSUM, alpha, c * CB, CTX);
        }
        add3v_k<<<g4BNH, eb, 0, stream>>>((const float4*)x[s], (float4*)CTX,
                                          (const float4*)FN, cnt4BNH);

        // ---- FFN, chunked rows ----
        lnw_bf_k<<<gLNW, 256, 0, stream>>>(CTX, ln_g + (2 + s) * Hc, ln_b + (2 + s) * Hc, Zb);
        for (int c = 0; c < NCHUNK; c++) {
            const short* Zc = Zb + (size_t)c * ROWS_CHUNK * Hc;
            launch_g2<2, 1, 1>(Zc, F1P, HIDB, ROWS_CHUNK, 4 * Hc, Hc, Hc, Hc,
                               ffn_b1 + (size_t)s * 4 * Hc, nullptr, 0, nullptr, 0, stream);
            launch_g2<1, 1, 0>(HIDB, F2P, FFNOUT + (size_t)c * ROWS_CHUNK * Hc,
                               ROWS_CHUNK, Hc, 4 * Hc, 4 * Hc, 4 * Hc,
                               ffn_b2 + (size_t)s * Hc, nullptr, 0, nullptr, 0, stream);
        }
        if (s == 0) {
            finalv_k<<<g4BNH, eb, 0, stream>>>((const float4*)CTX, (const float4*)FFNOUT, dw,
                                               (float4*)out, (float4*)PROJ0, cnt4BNH);
        } else {
            final_klw_k<<<gLNW, 256, 0, stream>>>(CTX, FFNOUT, dw, PROJ0, out + BNH, KLACC);
        }
    }
    kl_final_k<<<1, 1, 0, stream>>>(KLACC, out + OUT_DISTILL);
}

// Round 6
// 2845.421 us; speedup vs baseline: 2.6747x; 1.0835x over previous
//
#include <hip/hip_runtime.h>
#include <math.h>

// ---------------- constants ----------------
#define Bc   32
#define Nc   379
#define Hc   512
#define NHc  8
#define Pc   3
#define HDc  64          // H/NH
#define NNc  (Nc*Nc)     // 143641
#define CB   8           // batch chunk
#define NCHUNK 4
static const size_t NH_f  = (size_t)Nc*Hc;           // 194,048
static const size_t BNH   = (size_t)Bc*Nc*Hc;        // 6,207,488
#define ROWS_BN   12128   // B*N
#define ROWS_CHUNK 3032   // CB*N
#define ROWS_WG    9096   // CB*P*N
static const size_t CHUNK_NH = (size_t)CB*Nc*Hc;     // 1,552,384
static const size_t PEC_SZ   = (size_t)ROWS_WG*Hc;   // 4,657,152

#define WGS_SPLIT 16     // blocks per (b,r) row in wg_stats
#define TSPLIT 16        // n-splits in tokens reduction
#define KPAD 384         // pri K (379) padded to multiple of 32
#define KLB  1024        // blocks for final KL (atomic count = KLB)

typedef __attribute__((ext_vector_type(8))) short bf16x8;
typedef __attribute__((ext_vector_type(4))) short bf16x4;
typedef __attribute__((ext_vector_type(4))) float f32x4;

__device__ inline float gelu_f(float x) {
    return 0.5f * x * (1.0f + erff(x * 0.7071067811865476f));
}

// fp32 -> bf16 bits, round-to-nearest-even
__device__ inline short f2bf(float f) {
    unsigned u = __float_as_uint(f);
    unsigned r = u + 0x7fffu + ((u >> 16) & 1u);
    return (short)(r >> 16);
}

// wave (64-lane) reductions — no LDS, no barriers
__device__ inline float wave_sum(float v) {
#pragma unroll
    for (int off = 32; off; off >>= 1) v += __shfl_xor(v, off, 64);
    return v;
}
__device__ inline float wave_max(float v) {
#pragma unroll
    for (int off = 32; off; off >>= 1) v = fmaxf(v, __shfl_xor(v, off, 64));
    return v;
}

// block reduction (blockDim == 256) — still used by wg_stats
__device__ inline float blk_sum(float v, float* sh) {
#pragma unroll
    for (int off = 32; off; off >>= 1) v += __shfl_xor(v, off, 64);
    int w = threadIdx.x >> 6;
    __syncthreads();
    if ((threadIdx.x & 63) == 0) sh[w] = v;
    __syncthreads();
    return sh[0] + sh[1] + sh[2] + sh[3];
}

// ---------------- weight pre-pack: fp32 [K][N] -> bf16 [N][KP] (zero pad k>=K) ----------------
__global__ __launch_bounds__(256) void pack_b_k(const float* __restrict__ src,
                                                short* __restrict__ dst,
                                                int K, int N, int KP) {
    int idx = blockIdx.x * blockDim.x + threadIdx.x;
    int total = N * (KP / 8);
    if (idx >= total) return;
    int k8 = idx / N;            // consecutive tid -> consecutive n (coalesced)
    int n  = idx % N;
    int k0 = k8 * 8;
    bf16x8 v;
#pragma unroll
    for (int j = 0; j < 8; j++) {
        int k = k0 + j;
        v[j] = (k < K) ? f2bf(src[(size_t)k * N + n]) : (short)0;
    }
    *(bf16x8*)(dst + (size_t)n * KP + k0) = v;
}

// ---------------- pri pre-pack: fp32 [rows][379] -> bf16 [rows][384] (zero pad) ----------------
__global__ __launch_bounds__(256) void pack_pri_k(const float* __restrict__ src,
                                                  short* __restrict__ dst, int rows) {
    int idx = blockIdx.x * blockDim.x + threadIdx.x;
    int total = rows * (KPAD / 8);
    if (idx >= total) return;
    int row = idx / (KPAD / 8);
    int c8  = (idx % (KPAD / 8)) * 8;
    const float* s = src + (size_t)row * Nc + c8;
    bf16x8 v;
#pragma unroll
    for (int j = 0; j < 8; j++) v[j] = (c8 + j < Nc) ? f2bf(s[j]) : (short)0;
    *(bf16x8*)(dst + (size_t)row * KPAD + c8) = v;
}

// ---------------- g2: bf16 MFMA GEMM, packed-B, double-buffered, reg-prefetch ----------------
#define GBM 64
#define GBN 128
#define GBK 32
#define GLD 40   // LDS row stride in shorts

template<int EPI, int ABF, int CBF>
__global__ __launch_bounds__(256) void g2_k(
    const void* __restrict__ Ap, const short* __restrict__ Bp, void* __restrict__ Cp,
    int M, int N, int K, int KSA, int KSB,
    const float* __restrict__ bias,
    const float* __restrict__ rowscale, int rs_div,
    const float* __restrict__ addsrc, int addN)
{
    __shared__ __attribute__((aligned(16))) short As[2][GBM * GLD];
    __shared__ __attribute__((aligned(16))) short Bs[2][GBN * GLD];
    int tid = threadIdx.x;
    int wave = tid >> 6, lane = tid & 63;
    int wr = wave >> 1, wc = wave & 1;          // 2x2 waves; wave tile 32(m) x 64(n)
    int quad = lane >> 4, l16 = lane & 15;
    int m0 = blockIdx.y * GBM, n0 = blockIdx.x * GBN;

    int a_r = tid >> 2, a_k = (tid & 3) * 8;    // A: 64 rows x 32k, 8 elems/thread
    int b_n = tid >> 1, b_k = (tid & 1) * 16;   // B: 128 n x 32k, 16 elems/thread

    const float* Af = (const float*)Ap;
    const short* Ab = (const short*)Ap;

    f32x4 acc[2][4] = {};
    int nk = K / GBK;

    float4 ra0, ra1; bf16x8 rab; bf16x8 rb0, rb1;

    auto loadT = [&](int k0) {
        int gm = m0 + a_r;
        if (ABF) {
            rab = (bf16x8){0, 0, 0, 0, 0, 0, 0, 0};
            if (gm < M) rab = *(const bf16x8*)(Ab + (size_t)gm * KSA + k0 + a_k);
        } else {
            ra0 = make_float4(0.f, 0.f, 0.f, 0.f); ra1 = ra0;
            if (gm < M) {
                const float* s = Af + (size_t)gm * KSA + k0 + a_k;
                ra0 = *(const float4*)s; ra1 = *(const float4*)(s + 4);
            }
        }
        const short* bs = Bp + (size_t)(n0 + b_n) * KSB + k0 + b_k;
        rb0 = *(const bf16x8*)bs; rb1 = *(const bf16x8*)(bs + 8);
    };
    auto storeT = [&](int buf) {
        short* ad = &As[buf][a_r * GLD + a_k];
        if (ABF) {
            *(bf16x8*)ad = rab;
        } else {
            bf16x8 t;
            t[0] = f2bf(ra0.x); t[1] = f2bf(ra0.y); t[2] = f2bf(ra0.z); t[3] = f2bf(ra0.w);
            t[4] = f2bf(ra1.x); t[5] = f2bf(ra1.y); t[6] = f2bf(ra1.z); t[7] = f2bf(ra1.w);
            *(bf16x8*)ad = t;
        }
        short* bd = &Bs[buf][b_n * GLD + b_k];
        *(bf16x8*)bd = rb0; *(bf16x8*)(bd + 8) = rb1;
    };

    loadT(0);
    storeT(0);
    __syncthreads();

    for (int it = 0; it < nk; ++it) {
        int cur = it & 1;
        if (it + 1 < nk) loadT((it + 1) * GBK);   // prefetch in flight over MFMA below
        bf16x8 afr[2], bfr[4];
#pragma unroll
        for (int mt = 0; mt < 2; mt++)
            afr[mt] = *(const bf16x8*)&As[cur][(wr * 32 + mt * 16 + l16) * GLD + quad * 8];
#pragma unroll
        for (int nt = 0; nt < 4; nt++)
            bfr[nt] = *(const bf16x8*)&Bs[cur][(wc * 64 + nt * 16 + l16) * GLD + quad * 8];
#pragma unroll
        for (int mt = 0; mt < 2; mt++)
#pragma unroll
            for (int nt = 0; nt < 4; nt++)
                acc[mt][nt] = __builtin_amdgcn_mfma_f32_16x16x32_bf16(
                    afr[mt], bfr[nt], acc[mt][nt], 0, 0, 0);
        if (it + 1 < nk) {
            storeT(cur ^ 1);
            __syncthreads();
        }
    }

    // epilogue: C/D layout col=l16, row=quad*4+r
#pragma unroll
    for (int mt = 0; mt < 2; mt++) {
#pragma unroll
        for (int nt = 0; nt < 4; nt++) {
#pragma unroll
            for (int r = 0; r < 4; r++) {
                int gm = m0 + wr * 32 + mt * 16 + quad * 4 + r;
                int gn = n0 + wc * 64 + nt * 16 + l16;
                if (gm < M) {
                    float v = acc[mt][nt][r];
                    if (EPI == 1 || EPI == 2 || EPI == 3) v += bias[gn];
                    if (EPI == 4) v = v * rowscale[gm / rs_div] + bias[gn];
                    if (EPI == 3) {
                        int addrow = (gm / (3 * addN)) * addN + (gm % addN);
                        v += addsrc[(size_t)addrow * N + gn];
                    }
                    if (EPI == 2 || EPI == 3) v = gelu_f(v);
                    if (CBF) ((short*)Cp)[(size_t)gm * N + gn] = f2bf(v);
                    else     ((float*)Cp)[(size_t)gm * N + gn] = v;
                }
            }
        }
    }
}

template<int EPI, int ABF, int CBF>
static void launch_g2(const void* A, const short* B, void* C, int M, int N, int K,
                      int KSA, int KSB, const float* bias,
                      const float* rowscale, int rs_div,
                      const float* addsrc, int addN, hipStream_t st) {
    dim3 grid(N / GBN, (M + GBM - 1) / GBM);
    g2_k<EPI, ABF, CBF><<<grid, 256, 0, st>>>(A, B, C, M, N, K, KSA, KSB,
                                              bias, rowscale, rs_div, addsrc, addN);
}

// ---------------- LayerNorm: one wave per 512-row, no barriers ----------------
__global__ __launch_bounds__(256) void lnw_bf_k(const float* __restrict__ x,
                                                const float* __restrict__ g,
                                                const float* __restrict__ b,
                                                short* __restrict__ z) {
    int r = blockIdx.x * 4 + (threadIdx.x >> 6);
    int lane = threadIdx.x & 63;
    int d = lane * 4;
    const float* xr = x + (size_t)r * Hc;
    float4 v0 = *(const float4*)(xr + d);
    float4 v1 = *(const float4*)(xr + d + 256);
    const float* p0 = (const float*)&v0;
    const float* p1 = (const float*)&v1;
    float s = 0.f, sq = 0.f;
#pragma unroll
    for (int j = 0; j < 4; j++) {
        s += p0[j] + p1[j];
        sq += p0[j] * p0[j] + p1[j] * p1[j];
    }
    s = wave_sum(s);
    sq = wave_sum(sq);
    float mean = s * (1.f / Hc);
    float var  = sq * (1.f / Hc) - mean * mean;
    float inv  = rsqrtf(var + 1e-5f);
    float4 g0 = *(const float4*)(g + d), g1 = *(const float4*)(g + d + 256);
    float4 b0 = *(const float4*)(b + d), b1 = *(const float4*)(b + d + 256);
    const float* gp0 = (const float*)&g0; const float* gp1 = (const float*)&g1;
    const float* bp0 = (const float*)&b0; const float* bp1 = (const float*)&b1;
    bf16x4 o0, o1;
#pragma unroll
    for (int j = 0; j < 4; j++) {
        o0[j] = f2bf((p0[j] - mean) * inv * gp0[j] + bp0[j]);
        o1[j] = f2bf((p1[j] - mean) * inv * gp1[j] + bp1[j]);
    }
    short* zr = z + (size_t)r * Hc;
    *(bf16x4*)(zr + d)       = o0;
    *(bf16x4*)(zr + d + 256) = o1;
}

// ---------------- fused residual-add + LayerNorm: ctx = x+ctx+fn; z = LN(ctx) ----------------
__global__ __launch_bounds__(256) void add3ln_k(const float* __restrict__ x,
                                                float* __restrict__ ctx,
                                                const float* __restrict__ fn,
                                                const float* __restrict__ g,
                                                const float* __restrict__ b,
                                                short* __restrict__ z) {
    int r = blockIdx.x * 4 + (threadIdx.x >> 6);
    int lane = threadIdx.x & 63;
    int d = lane * 4;
    size_t base = (size_t)r * Hc;
    float4 x0 = *(const float4*)(x + base + d),   x1 = *(const float4*)(x + base + d + 256);
    float4 c0 = *(const float4*)(ctx + base + d), c1 = *(const float4*)(ctx + base + d + 256);
    float4 f0 = *(const float4*)(fn + base + d),  f1 = *(const float4*)(fn + base + d + 256);
    float v[8];
    v[0] = x0.x + c0.x + f0.x; v[1] = x0.y + c0.y + f0.y;
    v[2] = x0.z + c0.z + f0.z; v[3] = x0.w + c0.w + f0.w;
    v[4] = x1.x + c1.x + f1.x; v[5] = x1.y + c1.y + f1.y;
    v[6] = x1.z + c1.z + f1.z; v[7] = x1.w + c1.w + f1.w;
    *(float4*)(ctx + base + d)       = *(float4*)&v[0];
    *(float4*)(ctx + base + d + 256) = *(float4*)&v[4];
    float s = 0.f, sq = 0.f;
#pragma unroll
    for (int j = 0; j < 8; j++) { s += v[j]; sq += v[j] * v[j]; }
    s = wave_sum(s);
    sq = wave_sum(sq);
    float mean = s * (1.f / Hc);
    float var  = sq * (1.f / Hc) - mean * mean;
    float inv  = rsqrtf(var + 1e-5f);
    float4 g0 = *(const float4*)(g + d), g1 = *(const float4*)(g + d + 256);
    float4 b0 = *(const float4*)(b + d), b1 = *(const float4*)(b + d + 256);
    const float* gp0 = (const float*)&g0; const float* gp1 = (const float*)&g1;
    const float* bp0 = (const float*)&b0; const float* bp1 = (const float*)&b1;
    bf16x4 o0, o1;
#pragma unroll
    for (int j = 0; j < 4; j++) {
        o0[j] = f2bf((v[j]     - mean) * inv * gp0[j] + bp0[j]);
        o1[j] = f2bf((v[j + 4] - mean) * inv * gp1[j] + bp1[j]);
    }
    short* zr = z + base;
    *(bf16x4*)(zr + d)       = o0;
    *(bf16x4*)(zr + d + 256) = o1;
}

// ---------------- weight-gen stats (split + atomic partials) ----------------
__global__ __launch_bounds__(256) void wg_stats_k(const float* __restrict__ pri,
                                                  const float* __restrict__ conn,
                                                  float* __restrict__ mass, float* __restrict__ dot,
                                                  float* __restrict__ nrmp, float* __restrict__ nrmc) {
    __shared__ float sh[4];
    int bp = blockIdx.x;
    int sp = blockIdx.y;
    int b = bp >> 2, r = bp & 3;   // P+1 == 4
    const int per = (NNc + WGS_SPLIT - 1) / WGS_SPLIT;
    int i0 = sp * per;
    int i1 = i0 + per; if (i1 > NNc) i1 = NNc;
    const float* c = conn + (size_t)b * NNc;
    if (r < Pc) {
        const float* p = pri + (size_t)(b * Pc + r) * NNc;
        float sa = 0, sq = 0, sd = 0;
        for (int i = i0 + threadIdx.x; i < i1; i += 256) {
            float pv = p[i], cv = c[i];
            sa += fabsf(pv); sq += pv * pv; sd += pv * cv;
        }
        sa = blk_sum(sa, sh);
        sq = blk_sum(sq, sh);
        sd = blk_sum(sd, sh);
        if (threadIdx.x == 0) {
            atomicAdd(&mass[b * Pc + r], sa);
            atomicAdd(&nrmp[b * Pc + r], sq);
            atomicAdd(&dot[b * Pc + r], sd);
        }
    } else {
        float sq = 0;
        for (int i = i0 + threadIdx.x; i < i1; i += 256) { float cv = c[i]; sq += cv * cv; }
        sq = blk_sum(sq, sh);
        if (threadIdx.x == 0) atomicAdd(&nrmc[b], sq);
    }
}

__global__ void wg_sw_k(const float* mass, const float* dot, const float* nrmp, const float* nrmc,
                        float* sw, float* invm) {
    int b = threadIdx.x;
    if (b >= Bc) return;
    float nc = fmaxf(sqrtf(nrmc[b]), 1e-12f);
    float s[Pc];
    for (int p = 0; p < Pc; p++) s[p] = dot[b * Pc + p] / (nc * fmaxf(sqrtf(nrmp[b * Pc + p]), 1e-12f));
    float m = fmaxf(s[0], fmaxf(s[1], s[2]));
    float e[Pc], sum = 0;
    for (int p = 0; p < Pc; p++) { e[p] = expf(s[p] - m); sum += e[p]; }
    for (int p = 0; p < Pc; p++) {
        sw[b * Pc + p] = e[p] / sum;
        invm[b * Pc + p] = 1.f / mass[b * Pc + p];
    }
}

// ---------------- fused_nh: float4 vectorized ----------------
__global__ void fused_nhv_k(const float4* __restrict__ PE4, const float* __restrict__ swp,
                            float4* __restrict__ FN4, size_t count4) {
    size_t idx = (size_t)blockIdx.x * blockDim.x + threadIdx.x;
    if (idx >= count4) return;
    const size_t row4 = NH_f / 4;
    int bl = (int)(idx / row4);
    size_t within = idx % row4;
    const float* sw = swp + bl * Pc;
    size_t base = (size_t)bl * 3 * row4 + within;
    float4 a = PE4[base], b = PE4[base + row4], c = PE4[base + 2 * row4];
    float4 o;
    o.x = sw[0] * a.x + sw[1] * b.x + sw[2] * c.x;
    o.y = sw[0] * a.y + sw[1] * b.y + sw[2] * c.y;
    o.z = sw[0] * a.z + sw[1] * b.z + sw[2] * c.z;
    o.w = sw[0] * a.w + sw[1] * b.w + sw[2] * c.w;
    FN4[idx] = o;
}

// ---------------- tokens: mean over N, split ----------------
__global__ __launch_bounds__(512) void tokens_part_k(const float* __restrict__ F2,
                                                     float* __restrict__ TOKP) {
    int bp = blockIdx.x, sp = blockIdx.y, h = threadIdx.x;
    const int rows = (Nc + TSPLIT - 1) / TSPLIT;
    int n0 = sp * rows;
    int n1 = n0 + rows; if (n1 > Nc) n1 = Nc;
    const float* base = F2 + (size_t)bp * NH_f + h;
    float s = 0;
    for (int n = n0; n < n1; n++) s += base[(size_t)n * Hc];
    TOKP[((size_t)bp * TSPLIT + sp) * Hc + h] = s;
}

__global__ __launch_bounds__(512) void tokens_red_k(const float* __restrict__ TOKP,
                                                    float* __restrict__ TOK) {
    int bp = blockIdx.x, h = threadIdx.x;
    float s = 0;
#pragma unroll
    for (int sp = 0; sp < TSPLIT; sp++) s += TOKP[((size_t)bp * TSPLIT + sp) * Hc + h];
    TOK[(size_t)bp * Hc + h] = s * (1.0f / (float)Nc);
}

__global__ __launch_bounds__(64) void wg_attn_k(const float* __restrict__ QW,
                                                float* __restrict__ aw_out, float* __restrict__ msum) {
    int b = blockIdx.x, lane = threadIdx.x;
    float s[4][Pc][Pc];
    for (int h = 0; h < 4; h++)
        for (int i = 0; i < Pc; i++)
            for (int j = 0; j < Pc; j++) {
                const float* q = QW + (size_t)(b * Pc + i) * 1536 + h * 128;
                const float* k = QW + (size_t)(b * Pc + j) * 1536 + 512 + h * 128;
                float p = q[lane] * k[lane] + q[lane + 64] * k[lane + 64];
#pragma unroll
                for (int off = 32; off; off >>= 1) p += __shfl_xor(p, off, 64);
                s[h][i][j] = p * 0.08838834764831845f;
            }
    float aw[Pc] = {0, 0, 0};
    for (int h = 0; h < 4; h++)
        for (int i = 0; i < Pc; i++) {
            float m = fmaxf(s[h][i][0], fmaxf(s[h][i][1], s[h][i][2]));
            float e0 = expf(s[h][i][0] - m), e1 = expf(s[h][i][1] - m), e2 = expf(s[h][i][2] - m);
            float inv = 1.f / (e0 + e1 + e2);
            aw[0] += e0 * inv; aw[1] += e1 * inv; aw[2] += e2 * inv;
        }
    for (int j = 0; j < Pc; j++) aw[j] *= (1.f / 12.f);
    float m2 = fmaxf(aw[0], fmaxf(aw[1], aw[2]));
    float e0 = expf((aw[0] - m2) * 100.f), e1 = expf((aw[1] - m2) * 100.f), e2 = expf((aw[2] - m2) * 100.f);
    float inv = 1.f / (e0 + e1 + e2);
    if (lane == 0) {
        aw_out[b * Pc + 0] = e0 * inv;
        aw_out[b * Pc + 1] = e1 * inv;
        aw_out[b * Pc + 2] = e2 * inv;
        msum[b] = (e0 + e1 + e2) * inv;
    }
}

// ---------------- flash attention ----------------
#define AQT 32
__global__ __launch_bounds__(256) void fattn_k(const float* __restrict__ QKVc,
                                               const float* __restrict__ conn,
                                               const float* __restrict__ msum,
                                               const float* __restrict__ alpha,
                                               int b0, float* __restrict__ ctx) {
    __shared__ float Qs[AQT][66];
    __shared__ float Ks[64][66];
    __shared__ float Vs[64][66];
    __shared__ float Es[AQT][66];
    int i0 = blockIdx.x * AQT;
    int h = blockIdx.y, bl = blockIdx.z;
    int b = b0 + bl;
    int t = threadIdx.x;
    int q = t >> 3, sub = t & 7;
    int gi = i0 + q;
    float a2 = 0.5f * alpha[0];
    float mterm = a2 * msum[b];
    {
        int src_row = (gi < Nc) ? gi : (Nc - 1);
        int d0 = sub * 8;
        const float* src = QKVc + ((size_t)bl * Nc + src_row) * 1536 + h * HDc + d0;
        *(float4*)&Qs[q][d0]     = *(const float4*)src;
        *(float4*)&Qs[q][d0 + 4] = *(const float4*)(src + 4);
    }
    const float* Crow = conn + ((size_t)b * Nc + (gi < Nc ? gi : Nc - 1)) * Nc;
    float m_run = -3.4e38f, l_run = 0.f;
    float acc[8] = {0.f, 0.f, 0.f, 0.f, 0.f, 0.f, 0.f, 0.f};

    for (int jt = 0; jt < 6; jt++) {
        __syncthreads();
        {
            int j = t >> 2, d0 = (t & 3) * 16;
            int gj = jt * 64 + j;
            int sr = (gj < Nc) ? gj : (Nc - 1);
            const float* kp = QKVc + ((size_t)bl * Nc + sr) * 1536 + Hc + h * HDc + d0;
            const float* vp = kp + Hc;
            *(float4*)&Ks[j][d0]      = *(const float4*)(kp);
            *(float4*)&Ks[j][d0 + 4]  = *(const float4*)(kp + 4);
            *(float4*)&Ks[j][d0 + 8]  = *(const float4*)(kp + 8);
            *(float4*)&Ks[j][d0 + 12] = *(const float4*)(kp + 12);
            *(float4*)&Vs[j][d0]      = *(const float4*)(vp);
            *(float4*)&Vs[j][d0 + 4]  = *(const float4*)(vp + 4);
            *(float4*)&Vs[j][d0 + 8]  = *(const float4*)(vp + 8);
            *(float4*)&Vs[j][d0 + 12] = *(const float4*)(vp + 12);
        }
        __syncthreads();
        float s[8] = {0.f, 0.f, 0.f, 0.f, 0.f, 0.f, 0.f, 0.f};
#pragma unroll 4
        for (int d4 = 0; d4 < 16; d4++) {
            float4 qv = *(float4*)&Qs[q][d4 * 4];
#pragma unroll
            for (int jj = 0; jj < 8; jj++) {
                float4 kv = *(float4*)&Ks[sub + 8 * jj][d4 * 4];
                s[jj] += qv.x * kv.x + qv.y * kv.y + qv.z * kv.z + qv.w * kv.w;
            }
        }
        float tile_max = -3.4e38f;
#pragma unroll
        for (int jj = 0; jj < 8; jj++) {
            int gj = jt * 64 + sub + 8 * jj;
            if (gj < Nc && gi < Nc) {
                float mk = tanhf(mterm + (1.f - a2) * Crow[gj]);
                s[jj] = s[jj] * 0.125f * (1.f + mk);
            } else s[jj] = -3.4e38f;
            tile_max = fmaxf(tile_max, s[jj]);
        }
#pragma unroll
        for (int off = 1; off < 8; off <<= 1)
            tile_max = fmaxf(tile_max, __shfl_xor(tile_max, off, 64));
        float m_new = fmaxf(m_run, tile_max);
        float esum = 0.f;
#pragma unroll
        for (int jj = 0; jj < 8; jj++) {
            float e = __expf(s[jj] - m_new);
            Es[q][sub + 8 * jj] = e;
            esum += e;
        }
#pragma unroll
        for (int off = 1; off < 8; off <<= 1)
            esum += __shfl_xor(esum, off, 64);
        float scl = __expf(m_run - m_new);
        l_run = l_run * scl + esum;
        m_run = m_new;
        __syncthreads();
#pragma unroll
        for (int dd = 0; dd < 8; dd++) acc[dd] *= scl;
        int d0 = sub * 8;
#pragma unroll 4
        for (int j4 = 0; j4 < 16; j4++) {
            float4 ev = *(float4*)&Es[q][j4 * 4];
#pragma unroll
            for (int u = 0; u < 4; u++) {
                float e = (u == 0) ? ev.x : (u == 1) ? ev.y : (u == 2) ? ev.z : ev.w;
                float4 v0 = *(float4*)&Vs[j4 * 4 + u][d0];
                float4 v1 = *(float4*)&Vs[j4 * 4 + u][d0 + 4];
                acc[0] += e * v0.x; acc[1] += e * v0.y; acc[2] += e * v0.z; acc[3] += e * v0.w;
                acc[4] += e * v1.x; acc[5] += e * v1.y; acc[6] += e * v1.z; acc[7] += e * v1.w;
            }
        }
    }
    if (gi < Nc) {
        float inv = 1.f / l_run;
        float* dst = ctx + ((size_t)b * Nc + gi) * Hc + h * HDc + sub * 8;
        float4 o0 = make_float4(acc[0] * inv, acc[1] * inv, acc[2] * inv, acc[3] * inv);
        float4 o1 = make_float4(acc[4] * inv, acc[5] * inv, acc[6] * inv, acc[7] * inv);
        *(float4*)dst = o0;
        *(float4*)(dst + 4) = o1;
    }
}

// ---------------- vectorized elementwise ----------------
__global__ void finalv_k(const float4* __restrict__ AO, const float4* __restrict__ FF,
                         const float* __restrict__ dw,
                         float4* __restrict__ xout, float4* __restrict__ proj, size_t count4) {
    size_t idx = (size_t)blockIdx.x * blockDim.x + threadIdx.x;
    if (idx >= count4) return;
    float w = dw[0];
    float4 ff = FF[idx], ao = AO[idx];
    float4 xn, pr;
    xn.x = ao.x + ff.x; xn.y = ao.y + ff.y; xn.z = ao.z + ff.z; xn.w = ao.w + ff.w;
    pr.x = w * ff.x + (1.f - w) * xn.x; pr.y = w * ff.y + (1.f - w) * xn.y;
    pr.z = w * ff.z + (1.f - w) * xn.z; pr.w = w * ff.w + (1.f - w) * xn.w;
    xout[idx] = xn;
    proj[idx] = pr;
}

// ---------------- final KL: grid-stride, KLB atomics total (was 12128 same-address atomics:
// 12128 x ~14ns serialized RMW = the whole 172us — Guideline 12) ----------------
__global__ __launch_bounds__(256) void final_klw2_k(const float* __restrict__ AO,
                                                    const float* __restrict__ FF,
                                                    const float* __restrict__ dw,
                                                    const float* __restrict__ PF,
                                                    float* __restrict__ xout,
                                                    float* __restrict__ acc) {
    __shared__ float sh[4];
    int wid = threadIdx.x >> 6, lane = threadIdx.x & 63;
    int gw = blockIdx.x * 4 + wid;      // global wave id, KLB*4 waves
    int d = lane * 4;
    float w = dw[1];
    float ts_acc = 0.f;
    for (int r = gw; r < ROWS_BN; r += KLB * 4) {
        size_t base = (size_t)r * Hc;
        float4 ff0 = *(const float4*)(FF + base + d), ff1 = *(const float4*)(FF + base + d + 256);
        float4 ao0 = *(const float4*)(AO + base + d), ao1 = *(const float4*)(AO + base + d + 256);
        float4 pf0 = *(const float4*)(PF + base + d), pf1 = *(const float4*)(PF + base + d + 256);
        float ff[8], ao[8], pf[8];
        *(float4*)&ff[0] = ff0; *(float4*)&ff[4] = ff1;
        *(float4*)&ao[0] = ao0; *(float4*)&ao[4] = ao1;
        *(float4*)&pf[0] = pf0; *(float4*)&pf[4] = pf1;
        float xn[8], sv[8];
        float mf = -3.4e38f, ms = -3.4e38f;
#pragma unroll
        for (int j = 0; j < 8; j++) {
            xn[j] = ao[j] + ff[j];
            sv[j] = w * ff[j] + (1.f - w) * xn[j];
            mf = fmaxf(mf, pf[j]);
            ms = fmaxf(ms, sv[j]);
        }
        *(float4*)(xout + base + d)       = *(float4*)&xn[0];
        *(float4*)(xout + base + d + 256) = *(float4*)&xn[4];
        mf = wave_max(mf);
        ms = wave_max(ms);
        float ef = 0.f, es = 0.f;
#pragma unroll
        for (int j = 0; j < 8; j++) {
            ef += expf(pf[j] - mf);
            es += expf(sv[j] - ms);
        }
        ef = wave_sum(ef);
        es = wave_sum(es);
        float lsef = mf + logf(ef), lses = ms + logf(es);
        float ts = 0.f;
#pragma unroll
        for (int j = 0; j < 8; j++) {
            float lf = pf[j] - lsef, ls = sv[j] - lses;
            ts += expf(ls) * (ls - lf) + expf(lf) * (lf - ls);
        }
        ts_acc += wave_sum(ts);    // wave-uniform
    }
    if (lane == 0) sh[wid] = ts_acc;
    __syncthreads();
    if (threadIdx.x == 0)
        atomicAdd(acc, sh[0] + sh[1] + sh[2] + sh[3]);
}

__global__ void kl_final_k(const float* __restrict__ acc, float* __restrict__ out) {
    out[0] = 0.5f * acc[0] * (1.0f / (float)ROWS_BN);
}

// ---------------- launch ----------------
extern "C" void kernel_launch(void* const* d_in, const int* in_sizes, int n_in,
                              void* d_out, int out_size, void* d_ws, size_t ws_size,
                              hipStream_t stream) {
    (void)in_sizes; (void)n_in; (void)out_size; (void)ws_size;
    const float* x[2]    = {(const float*)d_in[0], (const float*)d_in[1]};
    const float* pri[2]  = {(const float*)d_in[2], (const float*)d_in[3]};
    const float* conn[2] = {(const float*)d_in[4], (const float*)d_in[5]};
    const float* dw      = (const float*)d_in[6];
    const float* wqkv[2] = {(const float*)d_in[7], (const float*)d_in[8]};
    const float* ln_g    = (const float*)d_in[9];
    const float* ln_b    = (const float*)d_in[10];
    const float* ffn_w1  = (const float*)d_in[11];
    const float* ffn_b1  = (const float*)d_in[12];
    const float* ffn_w2  = (const float*)d_in[13];
    const float* ffn_b2  = (const float*)d_in[14];
    const float* pw      = (const float*)d_in[15];
    const float* pb      = (const float*)d_in[16];
    const float* f1w     = (const float*)d_in[17];
    const float* f1b     = (const float*)d_in[18];
    const float* f2w     = (const float*)d_in[19];
    const float* f2b     = (const float*)d_in[20];
    const float* ipw     = (const float*)d_in[21];
    const float* ipb     = (const float*)d_in[22];
    const float* alpha   = (const float*)d_in[23];
    float* out = (float*)d_out;

    // --- workspace arena ---
    float* W = (float*)d_ws;
    size_t o = 0;
    auto alloc = [&](size_t n) { float* p = W + o; o += n; return p; };
    float* Z     = alloc(BNH);               // bf16 Z lives here (half used)
    float* CTX   = alloc(BNH);
    float* FN    = alloc(BNH);
    float* PROJ0 = alloc(BNH);
    float* R     = alloc(12417024);          // shared transient region
    float* TOK   = alloc((size_t)96 * Hc);
    float* QKVWG = alloc((size_t)96 * 1536);
    float* MASS  = alloc(96); float* DOT = alloc(96); float* NRMP = alloc(96);
    float* NRMC  = alloc(32); float* SW  = alloc(96); float* INVM = alloc(96);
    float* MSUM  = alloc(32);
    float* KLACC = alloc(1);
    // bf16 weight packs (persistent across launch)
    short* W1P  = (short*)alloc(262144);     // f1w  [512n][1024k]
    short* W2P  = (short*)alloc(131072);     // f2w  [512n][512k]
    short* PWP  = (short*)alloc(98304);      // pw   [512n][384k]
    short* IPP  = (short*)alloc(393216);     // ipw  [1536n][512k]
    short* QKVP = (short*)alloc(393216);     // wqkv[s] [1536n][512k]
    short* F1P  = (short*)alloc(524288);     // ffn_w1[s] [2048n][512k]
    short* F2P  = (short*)alloc(524288);     // ffn_w2[s] [512n][2048k]

    // R overlays (disjoint lifetimes):
    float* PEc  = R;                               // 4,657,152 fl
    short* H1B  = (short*)(R + PEC_SZ);            // 9096x512 bf16 = 2,328,576 fl
    float* ZFc  = R + PEC_SZ + 2328576;            // 1,552,384 fl
    float* QKVc = R;                               // 4,657,152 fl
    short* HIDB = (short*)R;                       // 3032x2048 bf16 = 3,104,768 fl
    float* FFNOUT = R + 6209536;                   // 6,207,488 fl
    float* TOKP = R + PEC_SZ;                      // tokens partials (H1B dead by then)
    short* PRIB = (short*)CTX;                     // packed pri chunk (CTX dead till fattn)
    short* Zb   = (short*)Z;                       // bf16 ln output [12128][512]

    const size_t OUT_DISTILL = 2 * BNH;
    const size_t OUT_AW = 2 * BNH + 1;

    hipMemsetAsync(KLACC, 0, sizeof(float), stream);

    int eb = 256;
    size_t cnt4BNH = BNH / 4;                        // 1,551,872
    int g4BNH = (int)((cnt4BNH + eb - 1) / eb);      // 6062
    size_t cnt4CHK = CHUNK_NH / 4;                   // 388,096
    int g4CHK = (int)((cnt4CHK + eb - 1) / eb);      // 1516
    int gPACK = (ROWS_WG * (KPAD / 8) + 255) / 256;
    int gLNW = ROWS_BN / 4;                          // 3032

    // one-time weight packs (shared across s)
    pack_b_k<<<(512 * 128 + 255) / 256, 256, 0, stream>>>(f1w, W1P, 1024, 512, 1024);
    pack_b_k<<<(512 * 64  + 255) / 256, 256, 0, stream>>>(f2w, W2P, 512, 512, 512);
    pack_b_k<<<(512 * 48  + 255) / 256, 256, 0, stream>>>(pw,  PWP, Nc, 512, KPAD);
    pack_b_k<<<(1536 * 64 + 255) / 256, 256, 0, stream>>>(ipw, IPP, 512, 1536, 512);

    for (int s = 0; s < 2; s++) {
        // per-s weight packs
        pack_b_k<<<(1536 * 64 + 255) / 256, 256, 0, stream>>>(wqkv[s], QKVP, 512, 1536, 512);
        pack_b_k<<<(2048 * 64 + 255) / 256, 256, 0, stream>>>(ffn_w1 + (size_t)s * Hc * 4 * Hc, F1P, 512, 2048, 512);
        pack_b_k<<<(512 * 256 + 255) / 256, 256, 0, stream>>>(ffn_w2 + (size_t)s * 4 * Hc * Hc, F2P, 2048, 512, 2048);

        lnw_bf_k<<<gLNW, 256, 0, stream>>>(x[s], ln_g + s * Hc, ln_b + s * Hc, Zb);
        hipMemsetAsync(MASS, 0, 320 * sizeof(float), stream);
        wg_stats_k<<<dim3(Bc * (Pc + 1), WGS_SPLIT), 256, 0, stream>>>(
            pri[s], conn[s], MASS, DOT, NRMP, NRMC);
        wg_sw_k<<<1, 64, 0, stream>>>(MASS, DOT, NRMP, NRMC, SW, INVM);

        // ---- weight-gen pipeline, chunked over batches ----
        for (int c = 0; c < NCHUNK; c++) {
            const float* pric = pri[s] + (size_t)c * ROWS_WG * Nc;
            const short* Zc = Zb + (size_t)c * ROWS_CHUNK * Hc;
            // xe @ f1w[512:1024] -> ZFc (fp32, consumed in EPI3)
            launch_g2<0, 1, 0>(Zc, W1P + 512, ZFc, ROWS_CHUNK, Hc, Hc, Hc, 1024,
                               nullptr, nullptr, 0, nullptr, 0, stream);
            // pri -> bf16 pack, then pri @ pw (EPI4: *invmass + bias)
            pack_pri_k<<<gPACK, 256, 0, stream>>>(pric, PRIB, ROWS_WG);
            launch_g2<4, 1, 0>(PRIB, PWP, PEc, ROWS_WG, Hc, KPAD, KPAD, KPAD,
                               pb, INVM + c * CB * Pc, Nc, nullptr, 0, stream);
            fused_nhv_k<<<g4CHK, eb, 0, stream>>>((const float4*)PEc, SW + c * CB * Pc,
                                                  (float4*)(FN + (size_t)c * CHUNK_NH), cnt4CHK);
            // pe @ f1w[0:512] + b + ZFc -> gelu -> H1B (bf16)
            launch_g2<3, 0, 1>(PEc, W1P, H1B, ROWS_WG, Hc, Hc, Hc, 1024,
                               f1b, nullptr, 0, ZFc, Nc, stream);
            // H1 @ f2w + b -> PEc (fp32 for fused/tokens)
            launch_g2<1, 1, 0>(H1B, W2P, PEc, ROWS_WG, Hc, Hc, Hc, Hc,
                               f2b, nullptr, 0, nullptr, 0, stream);
            tokens_part_k<<<dim3(CB * Pc, TSPLIT), 512, 0, stream>>>(PEc, TOKP);
            tokens_red_k<<<CB * Pc, 512, 0, stream>>>(TOKP, TOK + (size_t)c * CB * Pc * Hc);
        }
        // TOK @ ipw -> QKVWG via g2 (A fp32 path)
        launch_g2<1, 0, 0>(TOK, IPP, QKVWG, Bc * Pc, 3 * Hc, Hc, Hc, Hc,
                           ipb, nullptr, 0, nullptr, 0, stream);
        wg_attn_k<<<Bc, 64, 0, stream>>>(QKVWG, out + OUT_AW + (size_t)s * (Bc * Pc), MSUM);

        // ---- main attention, chunked over batches ----
        for (int c = 0; c < NCHUNK; c++) {
            const short* Zc = Zb + (size_t)c * ROWS_CHUNK * Hc;
            launch_g2<0, 1, 0>(Zc, QKVP, QKVc, ROWS_CHUNK, 3 * Hc, Hc, Hc, Hc,
                               nullptr, nullptr, 0, nullptr, 0, stream);
            fattn_k<<<dim3((Nc + AQT - 1) / AQT, NHc, CB), 256, 0, stream>>>(
                QKVc, conn[s], MSUM, alpha, c * CB, CTX);
        }
        // fused: CTX = x + CTX + FN; Zb = LN(CTX)
        add3ln_k<<<gLNW, 256, 0, stream>>>(x[s], CTX, FN,
                                           ln_g + (2 + s) * Hc, ln_b + (2 + s) * Hc, Zb);

        // ---- FFN, chunked rows ----
        for (int c = 0; c < NCHUNK; c++) {
            const short* Zc = Zb + (size_t)c * ROWS_CHUNK * Hc;
            launch_g2<2, 1, 1>(Zc, F1P, HIDB, ROWS_CHUNK, 4 * Hc, Hc, Hc, Hc,
                               ffn_b1 + (size_t)s * 4 * Hc, nullptr, 0, nullptr, 0, stream);
            launch_g2<1, 1, 0>(HIDB, F2P, FFNOUT + (size_t)c * ROWS_CHUNK * Hc,
                               ROWS_CHUNK, Hc, 4 * Hc, 4 * Hc, 4 * Hc,
                               ffn_b2 + (size_t)s * Hc, nullptr, 0, nullptr, 0, stream);
        }
        if (s == 0) {
            finalv_k<<<g4BNH, eb, 0, stream>>>((const float4*)CTX, (const float4*)FFNOUT, dw,
                                               (float4*)out, (float4*)PROJ0, cnt4BNH);
        } else {
            final_klw2_k<<<KLB, 256, 0, stream>>>(CTX, FFNOUT, dw, PROJ0, out + BNH, KLACC);
        }
    }
    kl_final_k<<<1, 1, 0, stream>>>(KLACC, out + OUT_DISTILL);
}

// Round 7
// 2275.873 us; speedup vs baseline: 3.3440x; 1.2503x over previous
//
#include <hip/hip_runtime.h>
#include <math.h>

// ---------------- constants ----------------
#define Bc   32
#define Nc   379
#define Hc   512
#define NHc  8
#define Pc   3
#define HDc  64          // H/NH
#define NNc  (Nc*Nc)     // 143641
#define CB   8           // batch chunk
#define NCHUNK 4
static const size_t NH_f  = (size_t)Nc*Hc;           // 194,048
static const size_t BNH   = (size_t)Bc*Nc*Hc;        // 6,207,488
#define ROWS_BN   12128   // B*N
#define ROWS_CHUNK 3032   // CB*N
#define ROWS_WG    9096   // CB*P*N
static const size_t CHUNK_NH = (size_t)CB*Nc*Hc;     // 1,552,384
static const size_t PEC_SZ   = (size_t)ROWS_WG*Hc;   // 4,657,152

#define WGS_SPLIT 16     // blocks per (b,r) row in wg_stats
#define TSPLIT 16        // n-splits in tokens reduction
#define KPAD 384         // pri K (379) padded to multiple of 32
#define KLB  1024        // blocks for final KL (atomic count = KLB)

typedef __attribute__((ext_vector_type(8))) short bf16x8;
typedef __attribute__((ext_vector_type(4))) short bf16x4;
typedef __attribute__((ext_vector_type(4))) float f32x4;

__device__ inline float gelu_f(float x) {
    return 0.5f * x * (1.0f + erff(x * 0.7071067811865476f));
}

// fp32 -> bf16 bits, round-to-nearest-even
__device__ inline short f2bf(float f) {
    unsigned u = __float_as_uint(f);
    unsigned r = u + 0x7fffu + ((u >> 16) & 1u);
    return (short)(r >> 16);
}

// wave (64-lane) reductions — no LDS, no barriers
__device__ inline float wave_sum(float v) {
#pragma unroll
    for (int off = 32; off; off >>= 1) v += __shfl_xor(v, off, 64);
    return v;
}
__device__ inline float wave_max(float v) {
#pragma unroll
    for (int off = 32; off; off >>= 1) v = fmaxf(v, __shfl_xor(v, off, 64));
    return v;
}

// block reduction (blockDim == 256) — still used by wg_stats
__device__ inline float blk_sum(float v, float* sh) {
#pragma unroll
    for (int off = 32; off; off >>= 1) v += __shfl_xor(v, off, 64);
    int w = threadIdx.x >> 6;
    __syncthreads();
    if ((threadIdx.x & 63) == 0) sh[w] = v;
    __syncthreads();
    return sh[0] + sh[1] + sh[2] + sh[3];
}

// ---------------- weight pre-pack: fp32 [K][N] -> bf16 [N][KP] (zero pad k>=K) ----------------
__global__ __launch_bounds__(256) void pack_b_k(const float* __restrict__ src,
                                                short* __restrict__ dst,
                                                int K, int N, int KP) {
    int idx = blockIdx.x * blockDim.x + threadIdx.x;
    int total = N * (KP / 8);
    if (idx >= total) return;
    int k8 = idx / N;            // consecutive tid -> consecutive n (coalesced)
    int n  = idx % N;
    int k0 = k8 * 8;
    bf16x8 v;
#pragma unroll
    for (int j = 0; j < 8; j++) {
        int k = k0 + j;
        v[j] = (k < K) ? f2bf(src[(size_t)k * N + n]) : (short)0;
    }
    *(bf16x8*)(dst + (size_t)n * KP + k0) = v;
}

// ---------------- pri pre-pack: fp32 [rows][379] -> bf16 [rows][384] (zero pad) ----------------
__global__ __launch_bounds__(256) void pack_pri_k(const float* __restrict__ src,
                                                  short* __restrict__ dst, int rows) {
    int idx = blockIdx.x * blockDim.x + threadIdx.x;
    int total = rows * (KPAD / 8);
    if (idx >= total) return;
    int row = idx / (KPAD / 8);
    int c8  = (idx % (KPAD / 8)) * 8;
    const float* s = src + (size_t)row * Nc + c8;
    bf16x8 v;
#pragma unroll
    for (int j = 0; j < 8; j++) v[j] = (c8 + j < Nc) ? f2bf(s[j]) : (short)0;
    *(bf16x8*)(dst + (size_t)row * KPAD + c8) = v;
}

// ---------------- g2: bf16 MFMA GEMM, packed-B, double-buffered, reg-prefetch ----------------
#define GBM 64
#define GBN 128
#define GBK 32
#define GLD 40   // LDS row stride in shorts

template<int EPI, int ABF, int CBF>
__global__ __launch_bounds__(256) void g2_k(
    const void* __restrict__ Ap, const short* __restrict__ Bp, void* __restrict__ Cp,
    int M, int N, int K, int KSA, int KSB,
    const float* __restrict__ bias,
    const float* __restrict__ rowscale, int rs_div,
    const float* __restrict__ addsrc, int addN)
{
    __shared__ __attribute__((aligned(16))) short As[2][GBM * GLD];
    __shared__ __attribute__((aligned(16))) short Bs[2][GBN * GLD];
    int tid = threadIdx.x;
    int wave = tid >> 6, lane = tid & 63;
    int wr = wave >> 1, wc = wave & 1;          // 2x2 waves; wave tile 32(m) x 64(n)
    int quad = lane >> 4, l16 = lane & 15;
    int m0 = blockIdx.y * GBM, n0 = blockIdx.x * GBN;

    int a_r = tid >> 2, a_k = (tid & 3) * 8;    // A: 64 rows x 32k, 8 elems/thread
    int b_n = tid >> 1, b_k = (tid & 1) * 16;   // B: 128 n x 32k, 16 elems/thread

    const float* Af = (const float*)Ap;
    const short* Ab = (const short*)Ap;

    f32x4 acc[2][4] = {};
    int nk = K / GBK;

    float4 ra0, ra1; bf16x8 rab; bf16x8 rb0, rb1;

    auto loadT = [&](int k0) {
        int gm = m0 + a_r;
        if (ABF) {
            rab = (bf16x8){0, 0, 0, 0, 0, 0, 0, 0};
            if (gm < M) rab = *(const bf16x8*)(Ab + (size_t)gm * KSA + k0 + a_k);
        } else {
            ra0 = make_float4(0.f, 0.f, 0.f, 0.f); ra1 = ra0;
            if (gm < M) {
                const float* s = Af + (size_t)gm * KSA + k0 + a_k;
                ra0 = *(const float4*)s; ra1 = *(const float4*)(s + 4);
            }
        }
        const short* bs = Bp + (size_t)(n0 + b_n) * KSB + k0 + b_k;
        rb0 = *(const bf16x8*)bs; rb1 = *(const bf16x8*)(bs + 8);
    };
    auto storeT = [&](int buf) {
        short* ad = &As[buf][a_r * GLD + a_k];
        if (ABF) {
            *(bf16x8*)ad = rab;
        } else {
            bf16x8 t;
            t[0] = f2bf(ra0.x); t[1] = f2bf(ra0.y); t[2] = f2bf(ra0.z); t[3] = f2bf(ra0.w);
            t[4] = f2bf(ra1.x); t[5] = f2bf(ra1.y); t[6] = f2bf(ra1.z); t[7] = f2bf(ra1.w);
            *(bf16x8*)ad = t;
        }
        short* bd = &Bs[buf][b_n * GLD + b_k];
        *(bf16x8*)bd = rb0; *(bf16x8*)(bd + 8) = rb1;
    };

    loadT(0);
    storeT(0);
    __syncthreads();

    for (int it = 0; it < nk; ++it) {
        int cur = it & 1;
        if (it + 1 < nk) loadT((it + 1) * GBK);   // prefetch in flight over MFMA below
        bf16x8 afr[2], bfr[4];
#pragma unroll
        for (int mt = 0; mt < 2; mt++)
            afr[mt] = *(const bf16x8*)&As[cur][(wr * 32 + mt * 16 + l16) * GLD + quad * 8];
#pragma unroll
        for (int nt = 0; nt < 4; nt++)
            bfr[nt] = *(const bf16x8*)&Bs[cur][(wc * 64 + nt * 16 + l16) * GLD + quad * 8];
#pragma unroll
        for (int mt = 0; mt < 2; mt++)
#pragma unroll
            for (int nt = 0; nt < 4; nt++)
                acc[mt][nt] = __builtin_amdgcn_mfma_f32_16x16x32_bf16(
                    afr[mt], bfr[nt], acc[mt][nt], 0, 0, 0);
        if (it + 1 < nk) {
            storeT(cur ^ 1);
            __syncthreads();
        }
    }

    // epilogue: C/D layout col=l16, row=quad*4+r
#pragma unroll
    for (int mt = 0; mt < 2; mt++) {
#pragma unroll
        for (int nt = 0; nt < 4; nt++) {
#pragma unroll
            for (int r = 0; r < 4; r++) {
                int gm = m0 + wr * 32 + mt * 16 + quad * 4 + r;
                int gn = n0 + wc * 64 + nt * 16 + l16;
                if (gm < M) {
                    float v = acc[mt][nt][r];
                    if (EPI == 1 || EPI == 2 || EPI == 3) v += bias[gn];
                    if (EPI == 4) v = v * rowscale[gm / rs_div] + bias[gn];
                    if (EPI == 3) {
                        int addrow = (gm / (3 * addN)) * addN + (gm % addN);
                        v += addsrc[(size_t)addrow * N + gn];
                    }
                    if (EPI == 2 || EPI == 3) v = gelu_f(v);
                    if (CBF) ((short*)Cp)[(size_t)gm * N + gn] = f2bf(v);
                    else     ((float*)Cp)[(size_t)gm * N + gn] = v;
                }
            }
        }
    }
}

template<int EPI, int ABF, int CBF>
static void launch_g2(const void* A, const short* B, void* C, int M, int N, int K,
                      int KSA, int KSB, const float* bias,
                      const float* rowscale, int rs_div,
                      const float* addsrc, int addN, hipStream_t st) {
    dim3 grid(N / GBN, (M + GBM - 1) / GBM);
    g2_k<EPI, ABF, CBF><<<grid, 256, 0, st>>>(A, B, C, M, N, K, KSA, KSB,
                                              bias, rowscale, rs_div, addsrc, addN);
}

// ---------------- LayerNorm: one wave per 512-row, no barriers ----------------
__global__ __launch_bounds__(256) void lnw_bf_k(const float* __restrict__ x,
                                                const float* __restrict__ g,
                                                const float* __restrict__ b,
                                                short* __restrict__ z) {
    int r = blockIdx.x * 4 + (threadIdx.x >> 6);
    int lane = threadIdx.x & 63;
    int d = lane * 4;
    const float* xr = x + (size_t)r * Hc;
    float4 v0 = *(const float4*)(xr + d);
    float4 v1 = *(const float4*)(xr + d + 256);
    const float* p0 = (const float*)&v0;
    const float* p1 = (const float*)&v1;
    float s = 0.f, sq = 0.f;
#pragma unroll
    for (int j = 0; j < 4; j++) {
        s += p0[j] + p1[j];
        sq += p0[j] * p0[j] + p1[j] * p1[j];
    }
    s = wave_sum(s);
    sq = wave_sum(sq);
    float mean = s * (1.f / Hc);
    float var  = sq * (1.f / Hc) - mean * mean;
    float inv  = rsqrtf(var + 1e-5f);
    float4 g0 = *(const float4*)(g + d), g1 = *(const float4*)(g + d + 256);
    float4 b0 = *(const float4*)(b + d), b1 = *(const float4*)(b + d + 256);
    const float* gp0 = (const float*)&g0; const float* gp1 = (const float*)&g1;
    const float* bp0 = (const float*)&b0; const float* bp1 = (const float*)&b1;
    bf16x4 o0, o1;
#pragma unroll
    for (int j = 0; j < 4; j++) {
        o0[j] = f2bf((p0[j] - mean) * inv * gp0[j] + bp0[j]);
        o1[j] = f2bf((p1[j] - mean) * inv * gp1[j] + bp1[j]);
    }
    short* zr = z + (size_t)r * Hc;
    *(bf16x4*)(zr + d)       = o0;
    *(bf16x4*)(zr + d + 256) = o1;
}

// ---------------- fused residual-add + LayerNorm ----------------
__global__ __launch_bounds__(256) void add3ln_k(const float* __restrict__ x,
                                                float* __restrict__ ctx,
                                                const float* __restrict__ fn,
                                                const float* __restrict__ g,
                                                const float* __restrict__ b,
                                                short* __restrict__ z) {
    int r = blockIdx.x * 4 + (threadIdx.x >> 6);
    int lane = threadIdx.x & 63;
    int d = lane * 4;
    size_t base = (size_t)r * Hc;
    float4 x0 = *(const float4*)(x + base + d),   x1 = *(const float4*)(x + base + d + 256);
    float4 c0 = *(const float4*)(ctx + base + d), c1 = *(const float4*)(ctx + base + d + 256);
    float4 f0 = *(const float4*)(fn + base + d),  f1 = *(const float4*)(fn + base + d + 256);
    float v[8];
    v[0] = x0.x + c0.x + f0.x; v[1] = x0.y + c0.y + f0.y;
    v[2] = x0.z + c0.z + f0.z; v[3] = x0.w + c0.w + f0.w;
    v[4] = x1.x + c1.x + f1.x; v[5] = x1.y + c1.y + f1.y;
    v[6] = x1.z + c1.z + f1.z; v[7] = x1.w + c1.w + f1.w;
    *(float4*)(ctx + base + d)       = *(float4*)&v[0];
    *(float4*)(ctx + base + d + 256) = *(float4*)&v[4];
    float s = 0.f, sq = 0.f;
#pragma unroll
    for (int j = 0; j < 8; j++) { s += v[j]; sq += v[j] * v[j]; }
    s = wave_sum(s);
    sq = wave_sum(sq);
    float mean = s * (1.f / Hc);
    float var  = sq * (1.f / Hc) - mean * mean;
    float inv  = rsqrtf(var + 1e-5f);
    float4 g0 = *(const float4*)(g + d), g1 = *(const float4*)(g + d + 256);
    float4 b0 = *(const float4*)(b + d), b1 = *(const float4*)(b + d + 256);
    const float* gp0 = (const float*)&g0; const float* gp1 = (const float*)&g1;
    const float* bp0 = (const float*)&b0; const float* bp1 = (const float*)&b1;
    bf16x4 o0, o1;
#pragma unroll
    for (int j = 0; j < 4; j++) {
        o0[j] = f2bf((v[j]     - mean) * inv * gp0[j] + bp0[j]);
        o1[j] = f2bf((v[j + 4] - mean) * inv * gp1[j] + bp1[j]);
    }
    short* zr = z + base;
    *(bf16x4*)(zr + d)       = o0;
    *(bf16x4*)(zr + d + 256) = o1;
}

// ---------------- weight-gen stats (split + atomic partials) ----------------
__global__ __launch_bounds__(256) void wg_stats_k(const float* __restrict__ pri,
                                                  const float* __restrict__ conn,
                                                  float* __restrict__ mass, float* __restrict__ dot,
                                                  float* __restrict__ nrmp, float* __restrict__ nrmc) {
    __shared__ float sh[4];
    int bp = blockIdx.x;
    int sp = blockIdx.y;
    int b = bp >> 2, r = bp & 3;   // P+1 == 4
    const int per = (NNc + WGS_SPLIT - 1) / WGS_SPLIT;
    int i0 = sp * per;
    int i1 = i0 + per; if (i1 > NNc) i1 = NNc;
    const float* c = conn + (size_t)b * NNc;
    if (r < Pc) {
        const float* p = pri + (size_t)(b * Pc + r) * NNc;
        float sa = 0, sq = 0, sd = 0;
        for (int i = i0 + threadIdx.x; i < i1; i += 256) {
            float pv = p[i], cv = c[i];
            sa += fabsf(pv); sq += pv * pv; sd += pv * cv;
        }
        sa = blk_sum(sa, sh);
        sq = blk_sum(sq, sh);
        sd = blk_sum(sd, sh);
        if (threadIdx.x == 0) {
            atomicAdd(&mass[b * Pc + r], sa);
            atomicAdd(&nrmp[b * Pc + r], sq);
            atomicAdd(&dot[b * Pc + r], sd);
        }
    } else {
        float sq = 0;
        for (int i = i0 + threadIdx.x; i < i1; i += 256) { float cv = c[i]; sq += cv * cv; }
        sq = blk_sum(sq, sh);
        if (threadIdx.x == 0) atomicAdd(&nrmc[b], sq);
    }
}

__global__ void wg_sw_k(const float* mass, const float* dot, const float* nrmp, const float* nrmc,
                        float* sw, float* invm) {
    int b = threadIdx.x;
    if (b >= Bc) return;
    float nc = fmaxf(sqrtf(nrmc[b]), 1e-12f);
    float s[Pc];
    for (int p = 0; p < Pc; p++) s[p] = dot[b * Pc + p] / (nc * fmaxf(sqrtf(nrmp[b * Pc + p]), 1e-12f));
    float m = fmaxf(s[0], fmaxf(s[1], s[2]));
    float e[Pc], sum = 0;
    for (int p = 0; p < Pc; p++) { e[p] = expf(s[p] - m); sum += e[p]; }
    for (int p = 0; p < Pc; p++) {
        sw[b * Pc + p] = e[p] / sum;
        invm[b * Pc + p] = 1.f / mass[b * Pc + p];
    }
}

// ---------------- fused_nh: float4 vectorized ----------------
__global__ void fused_nhv_k(const float4* __restrict__ PE4, const float* __restrict__ swp,
                            float4* __restrict__ FN4, size_t count4) {
    size_t idx = (size_t)blockIdx.x * blockDim.x + threadIdx.x;
    if (idx >= count4) return;
    const size_t row4 = NH_f / 4;
    int bl = (int)(idx / row4);
    size_t within = idx % row4;
    const float* sw = swp + bl * Pc;
    size_t base = (size_t)bl * 3 * row4 + within;
    float4 a = PE4[base], b = PE4[base + row4], c = PE4[base + 2 * row4];
    float4 o;
    o.x = sw[0] * a.x + sw[1] * b.x + sw[2] * c.x;
    o.y = sw[0] * a.y + sw[1] * b.y + sw[2] * c.y;
    o.z = sw[0] * a.z + sw[1] * b.z + sw[2] * c.z;
    o.w = sw[0] * a.w + sw[1] * b.w + sw[2] * c.w;
    FN4[idx] = o;
}

// ---------------- tokens: mean over N, split ----------------
__global__ __launch_bounds__(512) void tokens_part_k(const float* __restrict__ F2,
                                                     float* __restrict__ TOKP) {
    int bp = blockIdx.x, sp = blockIdx.y, h = threadIdx.x;
    const int rows = (Nc + TSPLIT - 1) / TSPLIT;
    int n0 = sp * rows;
    int n1 = n0 + rows; if (n1 > Nc) n1 = Nc;
    const float* base = F2 + (size_t)bp * NH_f + h;
    float s = 0;
    for (int n = n0; n < n1; n++) s += base[(size_t)n * Hc];
    TOKP[((size_t)bp * TSPLIT + sp) * Hc + h] = s;
}

__global__ __launch_bounds__(512) void tokens_red_k(const float* __restrict__ TOKP,
                                                    float* __restrict__ TOK) {
    int bp = blockIdx.x, h = threadIdx.x;
    float s = 0;
#pragma unroll
    for (int sp = 0; sp < TSPLIT; sp++) s += TOKP[((size_t)bp * TSPLIT + sp) * Hc + h];
    TOK[(size_t)bp * Hc + h] = s * (1.0f / (float)Nc);
}

__global__ __launch_bounds__(64) void wg_attn_k(const float* __restrict__ QW,
                                                float* __restrict__ aw_out, float* __restrict__ msum) {
    int b = blockIdx.x, lane = threadIdx.x;
    float s[4][Pc][Pc];
    for (int h = 0; h < 4; h++)
        for (int i = 0; i < Pc; i++)
            for (int j = 0; j < Pc; j++) {
                const float* q = QW + (size_t)(b * Pc + i) * 1536 + h * 128;
                const float* k = QW + (size_t)(b * Pc + j) * 1536 + 512 + h * 128;
                float p = q[lane] * k[lane] + q[lane + 64] * k[lane + 64];
#pragma unroll
                for (int off = 32; off; off >>= 1) p += __shfl_xor(p, off, 64);
                s[h][i][j] = p * 0.08838834764831845f;
            }
    float aw[Pc] = {0, 0, 0};
    for (int h = 0; h < 4; h++)
        for (int i = 0; i < Pc; i++) {
            float m = fmaxf(s[h][i][0], fmaxf(s[h][i][1], s[h][i][2]));
            float e0 = expf(s[h][i][0] - m), e1 = expf(s[h][i][1] - m), e2 = expf(s[h][i][2] - m);
            float inv = 1.f / (e0 + e1 + e2);
            aw[0] += e0 * inv; aw[1] += e1 * inv; aw[2] += e2 * inv;
        }
    for (int j = 0; j < Pc; j++) aw[j] *= (1.f / 12.f);
    float m2 = fmaxf(aw[0], fmaxf(aw[1], aw[2]));
    float e0 = expf((aw[0] - m2) * 100.f), e1 = expf((aw[1] - m2) * 100.f), e2 = expf((aw[2] - m2) * 100.f);
    float inv = 1.f / (e0 + e1 + e2);
    if (lane == 0) {
        aw_out[b * Pc + 0] = e0 * inv;
        aw_out[b * Pc + 1] = e1 * inv;
        aw_out[b * Pc + 2] = e2 * inv;
        msum[b] = (e0 + e1 + e2) * inv;
    }
}

// ---------------- mask precompute: MK[b][i][j] = 0.125*(1+tanh(a/2*msum[b] + (1-a/2)*conn)) ----
// (head-independent: was computed 8x redundantly inside fattn)
__global__ __launch_bounds__(256) void mask_k(const float* __restrict__ conn,
                                              const float* __restrict__ msum,
                                              const float* __restrict__ alpha,
                                              float* __restrict__ MK) {
    int b = blockIdx.y;
    int i = blockIdx.x * 256 + threadIdx.x;
    if (i >= NNc) return;
    float a2 = 0.5f * alpha[0];
    float mterm = a2 * msum[b];
    size_t idx = (size_t)b * NNc + i;
    MK[idx] = 0.125f * (1.f + tanhf(mterm + (1.f - a2) * conn[idx]));
}

// ---------------- MFMA flash attention ----------------
// block = (32 queries, head, batch-local). 4 waves.
// Pass 1: S = Q K^T via mfma (A=Q lane=row/d-contig, B=K lane=col/d-contig — g2-verified layout).
//   Wave w owns key columns kt*64 + w*16 + l16 across all 6 key tiles; full S row-block in regs.
// Softmax: mask-mult (precomputed MK), 16-lane shfl row-reduce + LDS cross-wave combine.
// P (unnormalized exp) -> LDS bf16 (pair-packed u32). Pass 2: O = P V via mfma with V
// transpose-staged (Vt[d][k] u32-paired). Normalize by 1/l at store.
#define ATQ 32
#define PSTR 196   // P32 row stride (u32): %4==0 (b128 align), 196%32=4 -> 2-way banks
#define VSTR 36    // Vt row stride (u32)
__global__ __launch_bounds__(256) void fattn_mfma_k(const short* __restrict__ QKVb,
                                                    const float* __restrict__ MK,
                                                    int b0, float* __restrict__ ctx) {
    __shared__ __attribute__((aligned(16))) short KVb[64 * 72];   // K tile [64][72] bf16; union with Vt
    __shared__ __attribute__((aligned(16))) unsigned P32[32 * PSTR];
    __shared__ float redm[4][32];
    __shared__ float reds[4][32];
    unsigned* Vt = (unsigned*)KVb;   // Vt[64 d][VSTR] u32 (2 bf16 k-pair each) — 9216B both

    int i0 = blockIdx.x * ATQ;
    int h = blockIdx.y, bl = blockIdx.z;
    int b = b0 + bl;
    int t = threadIdx.x;
    int w = t >> 6, lane = t & 63;
    int quad = lane >> 4, l16 = lane & 15;

    // ---- Q fragments: lane l16 = q-row, quad*8 = d-chunk (A-layout)
    bf16x8 qf[2][2];
#pragma unroll
    for (int mt = 0; mt < 2; mt++) {
        int gi = i0 + mt * 16 + l16; if (gi >= Nc) gi = Nc - 1;
        const short* qp = QKVb + ((size_t)bl * Nc + gi) * 1536 + h * HDc;
#pragma unroll
        for (int ks = 0; ks < 2; ks++)
            qf[mt][ks] = *(const bf16x8*)(qp + ks * 32 + quad * 8);
    }

    // ---- Pass 1: S over all 6 key tiles (wave's columns: kt*64 + w*16 + l16)
    f32x4 sacc[6][2] = {};
#pragma unroll
    for (int kt = 0; kt < 6; kt++) {
        __syncthreads();
        {   // stage K tile [64][64] bf16 -> KVb[64][72]
            int j = t >> 2, d0 = (t & 3) * 16;
            int gj = kt * 64 + j; if (gj >= Nc) gj = Nc - 1;
            const short* kp = QKVb + ((size_t)bl * Nc + gj) * 1536 + 512 + h * HDc + d0;
            *(bf16x8*)&KVb[j * 72 + d0]     = *(const bf16x8*)kp;
            *(bf16x8*)&KVb[j * 72 + d0 + 8] = *(const bf16x8*)(kp + 8);
        }
        __syncthreads();
        int kl = w * 16 + l16;
#pragma unroll
        for (int ks = 0; ks < 2; ks++) {
            bf16x8 kf = *(const bf16x8*)&KVb[kl * 72 + ks * 32 + quad * 8];
            sacc[kt][0] = __builtin_amdgcn_mfma_f32_16x16x32_bf16(qf[0][ks], kf, sacc[kt][0], 0, 0, 0);
            sacc[kt][1] = __builtin_amdgcn_mfma_f32_16x16x32_bf16(qf[1][ks], kf, sacc[kt][1], 0, 0, 0);
        }
    }

    // ---- mask-mult + local row max (lane holds S[q=mt*16+quad*4+r][k=kt*64+w*16+l16])
    float mmax[2][4];
#pragma unroll
    for (int mt = 0; mt < 2; mt++)
#pragma unroll
        for (int r = 0; r < 4; r++) mmax[mt][r] = -3.4e38f;
    int kcol = w * 16 + l16;
#pragma unroll
    for (int kt = 0; kt < 6; kt++) {
        int k = kt * 64 + kcol;
        bool kin = (k < Nc);
#pragma unroll
        for (int mt = 0; mt < 2; mt++)
#pragma unroll
            for (int r = 0; r < 4; r++) {
                int q = i0 + mt * 16 + quad * 4 + r; if (q >= Nc) q = Nc - 1;
                float s = sacc[kt][mt][r];
                s = kin ? s * MK[((size_t)b * Nc + q) * Nc + k] : -3.4e38f;
                sacc[kt][mt][r] = s;
                mmax[mt][r] = fmaxf(mmax[mt][r], s);
            }
    }
    // 16-lane (column-group) reduce, then cross-wave combine via LDS
#pragma unroll
    for (int mt = 0; mt < 2; mt++)
#pragma unroll
        for (int r = 0; r < 4; r++) {
            float v = mmax[mt][r];
            v = fmaxf(v, __shfl_xor(v, 1, 64));
            v = fmaxf(v, __shfl_xor(v, 2, 64));
            v = fmaxf(v, __shfl_xor(v, 4, 64));
            v = fmaxf(v, __shfl_xor(v, 8, 64));
            mmax[mt][r] = v;
        }
    if (l16 == 0) {
#pragma unroll
        for (int mt = 0; mt < 2; mt++)
#pragma unroll
            for (int r = 0; r < 4; r++)
                redm[w][mt * 16 + quad * 4 + r] = mmax[mt][r];
    }
    __syncthreads();
    float gmax[2][4], lsum[2][4];
#pragma unroll
    for (int mt = 0; mt < 2; mt++)
#pragma unroll
        for (int r = 0; r < 4; r++) {
            int qq = mt * 16 + quad * 4 + r;
            gmax[mt][r] = fmaxf(fmaxf(redm[0][qq], redm[1][qq]), fmaxf(redm[2][qq], redm[3][qq]));
            lsum[mt][r] = 0.f;
        }
    // exp (in place) + local sum
#pragma unroll
    for (int kt = 0; kt < 6; kt++)
#pragma unroll
        for (int mt = 0; mt < 2; mt++)
#pragma unroll
            for (int r = 0; r < 4; r++) {
                float p = __expf(sacc[kt][mt][r] - gmax[mt][r]);
                sacc[kt][mt][r] = p;
                lsum[mt][r] += p;
            }
#pragma unroll
    for (int mt = 0; mt < 2; mt++)
#pragma unroll
        for (int r = 0; r < 4; r++) {
            float v = lsum[mt][r];
            v += __shfl_xor(v, 1, 64);
            v += __shfl_xor(v, 2, 64);
            v += __shfl_xor(v, 4, 64);
            v += __shfl_xor(v, 8, 64);
            lsum[mt][r] = v;
        }
    if (l16 == 0) {
#pragma unroll
        for (int mt = 0; mt < 2; mt++)
#pragma unroll
            for (int r = 0; r < 4; r++)
                reds[w][mt * 16 + quad * 4 + r] = lsum[mt][r];
    }
    // P -> LDS bf16 (pair-pack via neighbor shuffle; even l16 writes u32)
#pragma unroll
    for (int kt = 0; kt < 6; kt++)
#pragma unroll
        for (int mt = 0; mt < 2; mt++)
#pragma unroll
            for (int r = 0; r < 4; r++) {
                float p = sacc[kt][mt][r];
                float nb = __shfl_xor(p, 1, 64);
                if ((l16 & 1) == 0) {
                    unsigned lo = (unsigned)(unsigned short)f2bf(p);
                    unsigned hi = (unsigned)(unsigned short)f2bf(nb);
                    int q = mt * 16 + quad * 4 + r;
                    P32[q * PSTR + kt * 32 + w * 8 + (l16 >> 1)] = lo | (hi << 16);
                }
            }
    __syncthreads();   // reds + P32 visible; KVb free for V reuse

    // global sums -> linv for this wave's PV rows (mt = w>>1)
    int mtw = w >> 1, ntb = (w & 1) * 2;
    float linv[4];
#pragma unroll
    for (int r = 0; r < 4; r++) {
        int qq = mtw * 16 + quad * 4 + r;
        linv[r] = 1.f / (reds[0][qq] + reds[1][qq] + reds[2][qq] + reds[3][qq]);
    }

    // ---- Pass 2: O = P V. Wave w: m-tile mtw, n-tiles {ntb, ntb+1} (d-dim)
    f32x4 oacc[2] = {};
#pragma unroll
    for (int kt = 0; kt < 6; kt++) {
        __syncthreads();
        {   // stage V transposed: Vt[d][kpair] u32 = (V[2kp][d], V[2kp+1][d])
            int kp = t & 31, dg = t >> 5;    // dg 0..7 -> d0 = dg*8
            int g0 = kt * 64 + 2 * kp, g1 = g0 + 1;
            if (g0 >= Nc) g0 = Nc - 1;
            if (g1 >= Nc) g1 = Nc - 1;
            const short* v0p = QKVb + ((size_t)bl * Nc + g0) * 1536 + 1024 + h * HDc + dg * 8;
            const short* v1p = QKVb + ((size_t)bl * Nc + g1) * 1536 + 1024 + h * HDc + dg * 8;
            bf16x8 v0 = *(const bf16x8*)v0p;
            bf16x8 v1 = *(const bf16x8*)v1p;
#pragma unroll
            for (int i = 0; i < 8; i++)
                Vt[(dg * 8 + i) * VSTR + kp] =
                    ((unsigned)(unsigned short)v0[i]) | (((unsigned)(unsigned short)v1[i]) << 16);
        }
        __syncthreads();
#pragma unroll
        for (int ks = 0; ks < 2; ks++) {
            bf16x8 pf = *(const bf16x8*)&P32[(mtw * 16 + l16) * PSTR + kt * 32 + ks * 16 + quad * 4];
#pragma unroll
            for (int nt2 = 0; nt2 < 2; nt2++) {
                int d = (ntb + nt2) * 16 + l16;
                bf16x8 vf = *(const bf16x8*)&Vt[d * VSTR + ks * 16 + quad * 4];
                oacc[nt2] = __builtin_amdgcn_mfma_f32_16x16x32_bf16(pf, vf, oacc[nt2], 0, 0, 0);
            }
        }
    }
    // ---- store (C layout: row=q=quad*4+r, col=d=l16)
#pragma unroll
    for (int nt2 = 0; nt2 < 2; nt2++)
#pragma unroll
        for (int r = 0; r < 4; r++) {
            int gi = i0 + mtw * 16 + quad * 4 + r;
            if (gi < Nc) {
                int d = (ntb + nt2) * 16 + l16;
                ctx[((size_t)b * Nc + gi) * Hc + h * HDc + d] = oacc[nt2][r] * linv[r];
            }
        }
}

// ---------------- vectorized elementwise ----------------
__global__ void finalv_k(const float4* __restrict__ AO, const float4* __restrict__ FF,
                         const float* __restrict__ dw,
                         float4* __restrict__ xout, float4* __restrict__ proj, size_t count4) {
    size_t idx = (size_t)blockIdx.x * blockDim.x + threadIdx.x;
    if (idx >= count4) return;
    float w = dw[0];
    float4 ff = FF[idx], ao = AO[idx];
    float4 xn, pr;
    xn.x = ao.x + ff.x; xn.y = ao.y + ff.y; xn.z = ao.z + ff.z; xn.w = ao.w + ff.w;
    pr.x = w * ff.x + (1.f - w) * xn.x; pr.y = w * ff.y + (1.f - w) * xn.y;
    pr.z = w * ff.z + (1.f - w) * xn.z; pr.w = w * ff.w + (1.f - w) * xn.w;
    xout[idx] = xn;
    proj[idx] = pr;
}

// ---------------- final KL: grid-stride, KLB atomics total ----------------
__global__ __launch_bounds__(256) void final_klw2_k(const float* __restrict__ AO,
                                                    const float* __restrict__ FF,
                                                    const float* __restrict__ dw,
                                                    const float* __restrict__ PF,
                                                    float* __restrict__ xout,
                                                    float* __restrict__ acc) {
    __shared__ float sh[4];
    int wid = threadIdx.x >> 6, lane = threadIdx.x & 63;
    int gw = blockIdx.x * 4 + wid;
    int d = lane * 4;
    float w = dw[1];
    float ts_acc = 0.f;
    for (int r = gw; r < ROWS_BN; r += KLB * 4) {
        size_t base = (size_t)r * Hc;
        float4 ff0 = *(const float4*)(FF + base + d), ff1 = *(const float4*)(FF + base + d + 256);
        float4 ao0 = *(const float4*)(AO + base + d), ao1 = *(const float4*)(AO + base + d + 256);
        float4 pf0 = *(const float4*)(PF + base + d), pf1 = *(const float4*)(PF + base + d + 256);
        float ff[8], ao[8], pf[8];
        *(float4*)&ff[0] = ff0; *(float4*)&ff[4] = ff1;
        *(float4*)&ao[0] = ao0; *(float4*)&ao[4] = ao1;
        *(float4*)&pf[0] = pf0; *(float4*)&pf[4] = pf1;
        float xn[8], sv[8];
        float mf = -3.4e38f, ms = -3.4e38f;
#pragma unroll
        for (int j = 0; j < 8; j++) {
            xn[j] = ao[j] + ff[j];
            sv[j] = w * ff[j] + (1.f - w) * xn[j];
            mf = fmaxf(mf, pf[j]);
            ms = fmaxf(ms, sv[j]);
        }
        *(float4*)(xout + base + d)       = *(float4*)&xn[0];
        *(float4*)(xout + base + d + 256) = *(float4*)&xn[4];
        mf = wave_max(mf);
        ms = wave_max(ms);
        float ef = 0.f, es = 0.f;
#pragma unroll
        for (int j = 0; j < 8; j++) {
            ef += expf(pf[j] - mf);
            es += expf(sv[j] - ms);
        }
        ef = wave_sum(ef);
        es = wave_sum(es);
        float lsef = mf + logf(ef), lses = ms + logf(es);
        float ts = 0.f;
#pragma unroll
        for (int j = 0; j < 8; j++) {
            float lf = pf[j] - lsef, ls = sv[j] - lses;
            ts += expf(ls) * (ls - lf) + expf(lf) * (lf - ls);
        }
        ts_acc += wave_sum(ts);
    }
    if (lane == 0) sh[wid] = ts_acc;
    __syncthreads();
    if (threadIdx.x == 0)
        atomicAdd(acc, sh[0] + sh[1] + sh[2] + sh[3]);
}

__global__ void kl_final_k(const float* __restrict__ acc, float* __restrict__ out) {
    out[0] = 0.5f * acc[0] * (1.0f / (float)ROWS_BN);
}

// ---------------- launch ----------------
extern "C" void kernel_launch(void* const* d_in, const int* in_sizes, int n_in,
                              void* d_out, int out_size, void* d_ws, size_t ws_size,
                              hipStream_t stream) {
    (void)in_sizes; (void)n_in; (void)out_size; (void)ws_size;
    const float* x[2]    = {(const float*)d_in[0], (const float*)d_in[1]};
    const float* pri[2]  = {(const float*)d_in[2], (const float*)d_in[3]};
    const float* conn[2] = {(const float*)d_in[4], (const float*)d_in[5]};
    const float* dw      = (const float*)d_in[6];
    const float* wqkv[2] = {(const float*)d_in[7], (const float*)d_in[8]};
    const float* ln_g    = (const float*)d_in[9];
    const float* ln_b    = (const float*)d_in[10];
    const float* ffn_w1  = (const float*)d_in[11];
    const float* ffn_b1  = (const float*)d_in[12];
    const float* ffn_w2  = (const float*)d_in[13];
    const float* ffn_b2  = (const float*)d_in[14];
    const float* pw      = (const float*)d_in[15];
    const float* pb      = (const float*)d_in[16];
    const float* f1w     = (const float*)d_in[17];
    const float* f1b     = (const float*)d_in[18];
    const float* f2w     = (const float*)d_in[19];
    const float* f2b     = (const float*)d_in[20];
    const float* ipw     = (const float*)d_in[21];
    const float* ipb     = (const float*)d_in[22];
    const float* alpha   = (const float*)d_in[23];
    float* out = (float*)d_out;

    // --- workspace arena ---
    float* W = (float*)d_ws;
    size_t o = 0;
    auto alloc = [&](size_t n) { float* p = W + o; o += n; return p; };
    float* Z     = alloc(BNH);               // bf16 Z lives here (half used)
    float* CTX   = alloc(BNH);
    float* FN    = alloc(BNH);
    float* PROJ0 = alloc(BNH);
    float* R     = alloc(12417024);          // shared transient region
    float* TOK   = alloc((size_t)96 * Hc);
    float* QKVWG = alloc((size_t)96 * 1536);
    float* MASS  = alloc(96); float* DOT = alloc(96); float* NRMP = alloc(96);
    float* NRMC  = alloc(32); float* SW  = alloc(96); float* INVM = alloc(96);
    float* MSUM  = alloc(32);
    float* KLACC = alloc(1);
    // bf16 weight packs (persistent across launch)
    short* W1P  = (short*)alloc(262144);     // f1w  [512n][1024k]
    short* W2P  = (short*)alloc(131072);     // f2w  [512n][512k]
    short* PWP  = (short*)alloc(98304);      // pw   [512n][384k]
    short* IPP  = (short*)alloc(393216);     // ipw  [1536n][512k]
    short* QKVP = (short*)alloc(393216);     // wqkv[s] [1536n][512k]
    short* F1P  = (short*)alloc(524288);     // ffn_w1[s] [2048n][512k]
    short* F2P  = (short*)alloc(524288);     // ffn_w2[s] [512n][2048k]

    // R overlays (disjoint lifetimes):
    float* PEc  = R;                               // 4,657,152 fl (wg phase)
    short* H1B  = (short*)(R + PEC_SZ);            // wg phase
    float* ZFc  = R + PEC_SZ + 2328576;            // wg phase
    short* QKVcB = (short*)R;                      // attn phase: 3032x1536 bf16 = 2,328,576 fl
    float* MKbuf = R + 2400000;                    // attn phase: 32*379*379 fl -> ends 6,996,512
    short* HIDB = (short*)R;                       // FFN phase
    float* FFNOUT = R + 6209536;                   // FFN phase
    float* TOKP = R + PEC_SZ;                      // tokens partials (wg phase)
    short* PRIB = (short*)CTX;                     // packed pri chunk (CTX dead till fattn)
    short* Zb   = (short*)Z;                       // bf16 ln output [12128][512]

    const size_t OUT_DISTILL = 2 * BNH;
    const size_t OUT_AW = 2 * BNH + 1;

    hipMemsetAsync(KLACC, 0, sizeof(float), stream);

    int eb = 256;
    size_t cnt4BNH = BNH / 4;
    int g4BNH = (int)((cnt4BNH + eb - 1) / eb);
    size_t cnt4CHK = CHUNK_NH / 4;
    int g4CHK = (int)((cnt4CHK + eb - 1) / eb);
    int gPACK = (ROWS_WG * (KPAD / 8) + 255) / 256;
    int gLNW = ROWS_BN / 4;

    // one-time weight packs (shared across s)
    pack_b_k<<<(512 * 128 + 255) / 256, 256, 0, stream>>>(f1w, W1P, 1024, 512, 1024);
    pack_b_k<<<(512 * 64  + 255) / 256, 256, 0, stream>>>(f2w, W2P, 512, 512, 512);
    pack_b_k<<<(512 * 48  + 255) / 256, 256, 0, stream>>>(pw,  PWP, Nc, 512, KPAD);
    pack_b_k<<<(1536 * 64 + 255) / 256, 256, 0, stream>>>(ipw, IPP, 512, 1536, 512);

    for (int s = 0; s < 2; s++) {
        // per-s weight packs
        pack_b_k<<<(1536 * 64 + 255) / 256, 256, 0, stream>>>(wqkv[s], QKVP, 512, 1536, 512);
        pack_b_k<<<(2048 * 64 + 255) / 256, 256, 0, stream>>>(ffn_w1 + (size_t)s * Hc * 4 * Hc, F1P, 512, 2048, 512);
        pack_b_k<<<(512 * 256 + 255) / 256, 256, 0, stream>>>(ffn_w2 + (size_t)s * 4 * Hc * Hc, F2P, 2048, 512, 2048);

        lnw_bf_k<<<gLNW, 256, 0, stream>>>(x[s], ln_g + s * Hc, ln_b + s * Hc, Zb);
        hipMemsetAsync(MASS, 0, 320 * sizeof(float), stream);
        wg_stats_k<<<dim3(Bc * (Pc + 1), WGS_SPLIT), 256, 0, stream>>>(
            pri[s], conn[s], MASS, DOT, NRMP, NRMC);
        wg_sw_k<<<1, 64, 0, stream>>>(MASS, DOT, NRMP, NRMC, SW, INVM);

        // ---- weight-gen pipeline, chunked over batches ----
        for (int c = 0; c < NCHUNK; c++) {
            const float* pric = pri[s] + (size_t)c * ROWS_WG * Nc;
            const short* Zc = Zb + (size_t)c * ROWS_CHUNK * Hc;
            launch_g2<0, 1, 0>(Zc, W1P + 512, ZFc, ROWS_CHUNK, Hc, Hc, Hc, 1024,
                               nullptr, nullptr, 0, nullptr, 0, stream);
            pack_pri_k<<<gPACK, 256, 0, stream>>>(pric, PRIB, ROWS_WG);
            launch_g2<4, 1, 0>(PRIB, PWP, PEc, ROWS_WG, Hc, KPAD, KPAD, KPAD,
                               pb, INVM + c * CB * Pc, Nc, nullptr, 0, stream);
            fused_nhv_k<<<g4CHK, eb, 0, stream>>>((const float4*)PEc, SW + c * CB * Pc,
                                                  (float4*)(FN + (size_t)c * CHUNK_NH), cnt4CHK);
            launch_g2<3, 0, 1>(PEc, W1P, H1B, ROWS_WG, Hc, Hc, Hc, 1024,
                               f1b, nullptr, 0, ZFc, Nc, stream);
            launch_g2<1, 1, 0>(H1B, W2P, PEc, ROWS_WG, Hc, Hc, Hc, Hc,
                               f2b, nullptr, 0, nullptr, 0, stream);
            tokens_part_k<<<dim3(CB * Pc, TSPLIT), 512, 0, stream>>>(PEc, TOKP);
            tokens_red_k<<<CB * Pc, 512, 0, stream>>>(TOKP, TOK + (size_t)c * CB * Pc * Hc);
        }
        launch_g2<1, 0, 0>(TOK, IPP, QKVWG, Bc * Pc, 3 * Hc, Hc, Hc, Hc,
                           ipb, nullptr, 0, nullptr, 0, stream);
        wg_attn_k<<<Bc, 64, 0, stream>>>(QKVWG, out + OUT_AW + (size_t)s * (Bc * Pc), MSUM);

        // ---- mask precompute (needs MSUM), then main attention chunks ----
        mask_k<<<dim3((NNc + 255) / 256, Bc), 256, 0, stream>>>(conn[s], MSUM, alpha, MKbuf);
        for (int c = 0; c < NCHUNK; c++) {
            const short* Zc = Zb + (size_t)c * ROWS_CHUNK * Hc;
            launch_g2<0, 1, 1>(Zc, QKVP, QKVcB, ROWS_CHUNK, 3 * Hc, Hc, Hc, Hc,
                               nullptr, nullptr, 0, nullptr, 0, stream);
            fattn_mfma_k<<<dim3((Nc + ATQ - 1) / ATQ, NHc, CB), 256, 0, stream>>>(
                QKVcB, MKbuf, c * CB, CTX);
        }
        // fused: CTX = x + CTX + FN; Zb = LN(CTX)
        add3ln_k<<<gLNW, 256, 0, stream>>>(x[s], CTX, FN,
                                           ln_g + (2 + s) * Hc, ln_b + (2 + s) * Hc, Zb);

        // ---- FFN, chunked rows ----
        for (int c = 0; c < NCHUNK; c++) {
            const short* Zc = Zb + (size_t)c * ROWS_CHUNK * Hc;
            launch_g2<2, 1, 1>(Zc, F1P, HIDB, ROWS_CHUNK, 4 * Hc, Hc, Hc, Hc,
                               ffn_b1 + (size_t)s * 4 * Hc, nullptr, 0, nullptr, 0, stream);
            launch_g2<1, 1, 0>(HIDB, F2P, FFNOUT + (size_t)c * ROWS_CHUNK * Hc,
                               ROWS_CHUNK, Hc, 4 * Hc, 4 * Hc, 4 * Hc,
                               ffn_b2 + (size_t)s * Hc, nullptr, 0, nullptr, 0, stream);
        }
        if (s == 0) {
            finalv_k<<<g4BNH, eb, 0, stream>>>((const float4*)CTX, (const float4*)FFNOUT, dw,
                                               (float4*)out, (float4*)PROJ0, cnt4BNH);
        } else {
            final_klw2_k<<<KLB, 256, 0, stream>>>(CTX, FFNOUT, dw, PROJ0, out + BNH, KLACC);
        }
    }
    kl_final_k<<<1, 1, 0, stream>>>(KLACC, out + OUT_DISTILL);
}

// Round 8
// 1939.239 us; speedup vs baseline: 3.9245x; 1.1736x over previous
//
#include <hip/hip_runtime.h>
#include <math.h>

// ---------------- constants ----------------
#define Bc   32
#define Nc   379
#define Hc   512
#define NHc  8
#define Pc   3
#define HDc  64          // H/NH
#define NNc  (Nc*Nc)     // 143641
#define CB   8           // batch chunk
#define NCHUNK 4
static const size_t NH_f  = (size_t)Nc*Hc;           // 194,048
static const size_t BNH   = (size_t)Bc*Nc*Hc;        // 6,207,488
#define ROWS_BN   12128   // B*N
#define ROWS_CHUNK 3032   // CB*N
#define ROWS_WG    9096   // CB*P*N
static const size_t CHUNK_NH = (size_t)CB*Nc*Hc;     // 1,552,384
static const size_t PEC_SZ   = (size_t)ROWS_WG*Hc;   // 4,657,152

#define WGS_SPLIT 16     // blocks per (b,r) row in wg_stats
#define TSPLIT 16        // n-splits in tokens reduction
#define KPAD 384         // pri K (379) padded to multiple of 32
#define KLB  1024        // blocks for final KL (atomic count = KLB)

typedef __attribute__((ext_vector_type(8))) short bf16x8;
typedef __attribute__((ext_vector_type(4))) short bf16x4;
typedef __attribute__((ext_vector_type(4))) float f32x4;

__device__ inline float gelu_f(float x) {
    return 0.5f * x * (1.0f + erff(x * 0.7071067811865476f));
}

// fp32 -> bf16 bits, round-to-nearest-even
__device__ inline short f2bf(float f) {
    unsigned u = __float_as_uint(f);
    unsigned r = u + 0x7fffu + ((u >> 16) & 1u);
    return (short)(r >> 16);
}
__device__ inline float bf2f(short s) {
    return __uint_as_float(((unsigned)(unsigned short)s) << 16);
}

// wave (64-lane) reductions — no LDS, no barriers
__device__ inline float wave_sum(float v) {
#pragma unroll
    for (int off = 32; off; off >>= 1) v += __shfl_xor(v, off, 64);
    return v;
}
__device__ inline float wave_max(float v) {
#pragma unroll
    for (int off = 32; off; off >>= 1) v = fmaxf(v, __shfl_xor(v, off, 64));
    return v;
}

// block reduction (blockDim == 256) — still used by wg_stats
__device__ inline float blk_sum(float v, float* sh) {
#pragma unroll
    for (int off = 32; off; off >>= 1) v += __shfl_xor(v, off, 64);
    int w = threadIdx.x >> 6;
    __syncthreads();
    if ((threadIdx.x & 63) == 0) sh[w] = v;
    __syncthreads();
    return sh[0] + sh[1] + sh[2] + sh[3];
}

// ---------------- weight pre-pack: fp32 [K][N] -> bf16 [N][KP] (zero pad k>=K) ----------------
__global__ __launch_bounds__(256) void pack_b_k(const float* __restrict__ src,
                                                short* __restrict__ dst,
                                                int K, int N, int KP) {
    int idx = blockIdx.x * blockDim.x + threadIdx.x;
    int total = N * (KP / 8);
    if (idx >= total) return;
    int k8 = idx / N;            // consecutive tid -> consecutive n (coalesced)
    int n  = idx % N;
    int k0 = k8 * 8;
    bf16x8 v;
#pragma unroll
    for (int j = 0; j < 8; j++) {
        int k = k0 + j;
        v[j] = (k < K) ? f2bf(src[(size_t)k * N + n]) : (short)0;
    }
    *(bf16x8*)(dst + (size_t)n * KP + k0) = v;
}

// ---------------- pri pre-pack: fp32 [rows][379] -> bf16 [rows][384] (zero pad) ----------------
__global__ __launch_bounds__(256) void pack_pri_k(const float* __restrict__ src,
                                                  short* __restrict__ dst, int rows) {
    int idx = blockIdx.x * blockDim.x + threadIdx.x;
    int total = rows * (KPAD / 8);
    if (idx >= total) return;
    int row = idx / (KPAD / 8);
    int c8  = (idx % (KPAD / 8)) * 8;
    const float* s = src + (size_t)row * Nc + c8;
    bf16x8 v;
#pragma unroll
    for (int j = 0; j < 8; j++) v[j] = (c8 + j < Nc) ? f2bf(s[j]) : (short)0;
    *(bf16x8*)(dst + (size_t)row * KPAD + c8) = v;
}

// ---------------- g2: bf16 MFMA GEMM, packed-B, double-buffered, reg-prefetch ----------------
#define GBM 64
#define GBN 128
#define GBK 32
#define GLD 40   // LDS row stride in shorts

template<int EPI, int ABF, int CBF>
__global__ __launch_bounds__(256) void g2_k(
    const void* __restrict__ Ap, const short* __restrict__ Bp, void* __restrict__ Cp,
    int M, int N, int K, int KSA, int KSB,
    const float* __restrict__ bias,
    const float* __restrict__ rowscale, int rs_div,
    const float* __restrict__ addsrc, int addN)
{
    __shared__ __attribute__((aligned(16))) short As[2][GBM * GLD];
    __shared__ __attribute__((aligned(16))) short Bs[2][GBN * GLD];
    int tid = threadIdx.x;
    int wave = tid >> 6, lane = tid & 63;
    int wr = wave >> 1, wc = wave & 1;          // 2x2 waves; wave tile 32(m) x 64(n)
    int quad = lane >> 4, l16 = lane & 15;
    int m0 = blockIdx.y * GBM, n0 = blockIdx.x * GBN;

    int a_r = tid >> 2, a_k = (tid & 3) * 8;    // A: 64 rows x 32k, 8 elems/thread
    int b_n = tid >> 1, b_k = (tid & 1) * 16;   // B: 128 n x 32k, 16 elems/thread

    const float* Af = (const float*)Ap;
    const short* Ab = (const short*)Ap;

    f32x4 acc[2][4] = {};
    int nk = K / GBK;

    float4 ra0, ra1; bf16x8 rab; bf16x8 rb0, rb1;

    auto loadT = [&](int k0) {
        int gm = m0 + a_r;
        if (ABF) {
            rab = (bf16x8){0, 0, 0, 0, 0, 0, 0, 0};
            if (gm < M) rab = *(const bf16x8*)(Ab + (size_t)gm * KSA + k0 + a_k);
        } else {
            ra0 = make_float4(0.f, 0.f, 0.f, 0.f); ra1 = ra0;
            if (gm < M) {
                const float* s = Af + (size_t)gm * KSA + k0 + a_k;
                ra0 = *(const float4*)s; ra1 = *(const float4*)(s + 4);
            }
        }
        const short* bs = Bp + (size_t)(n0 + b_n) * KSB + k0 + b_k;
        rb0 = *(const bf16x8*)bs; rb1 = *(const bf16x8*)(bs + 8);
    };
    auto storeT = [&](int buf) {
        short* ad = &As[buf][a_r * GLD + a_k];
        if (ABF) {
            *(bf16x8*)ad = rab;
        } else {
            bf16x8 t;
            t[0] = f2bf(ra0.x); t[1] = f2bf(ra0.y); t[2] = f2bf(ra0.z); t[3] = f2bf(ra0.w);
            t[4] = f2bf(ra1.x); t[5] = f2bf(ra1.y); t[6] = f2bf(ra1.z); t[7] = f2bf(ra1.w);
            *(bf16x8*)ad = t;
        }
        short* bd = &Bs[buf][b_n * GLD + b_k];
        *(bf16x8*)bd = rb0; *(bf16x8*)(bd + 8) = rb1;
    };

    loadT(0);
    storeT(0);
    __syncthreads();

    for (int it = 0; it < nk; ++it) {
        int cur = it & 1;
        if (it + 1 < nk) loadT((it + 1) * GBK);   // prefetch in flight over MFMA below
        bf16x8 afr[2], bfr[4];
#pragma unroll
        for (int mt = 0; mt < 2; mt++)
            afr[mt] = *(const bf16x8*)&As[cur][(wr * 32 + mt * 16 + l16) * GLD + quad * 8];
#pragma unroll
        for (int nt = 0; nt < 4; nt++)
            bfr[nt] = *(const bf16x8*)&Bs[cur][(wc * 64 + nt * 16 + l16) * GLD + quad * 8];
#pragma unroll
        for (int mt = 0; mt < 2; mt++)
#pragma unroll
            for (int nt = 0; nt < 4; nt++)
                acc[mt][nt] = __builtin_amdgcn_mfma_f32_16x16x32_bf16(
                    afr[mt], bfr[nt], acc[mt][nt], 0, 0, 0);
        if (it + 1 < nk) {
            storeT(cur ^ 1);
            __syncthreads();
        }
    }

    // epilogue: C/D layout col=l16, row=quad*4+r
#pragma unroll
    for (int mt = 0; mt < 2; mt++) {
#pragma unroll
        for (int nt = 0; nt < 4; nt++) {
#pragma unroll
            for (int r = 0; r < 4; r++) {
                int gm = m0 + wr * 32 + mt * 16 + quad * 4 + r;
                int gn = n0 + wc * 64 + nt * 16 + l16;
                if (gm < M) {
                    float v = acc[mt][nt][r];
                    if (EPI == 1 || EPI == 2 || EPI == 3) v += bias[gn];
                    if (EPI == 4) v = v * rowscale[gm / rs_div] + bias[gn];
                    if (EPI == 3) {
                        int addrow = (gm / (3 * addN)) * addN + (gm % addN);
                        v += addsrc[(size_t)addrow * N + gn];
                    }
                    if (EPI == 2 || EPI == 3) v = gelu_f(v);
                    if (CBF) ((short*)Cp)[(size_t)gm * N + gn] = f2bf(v);
                    else     ((float*)Cp)[(size_t)gm * N + gn] = v;
                }
            }
        }
    }
}

template<int EPI, int ABF, int CBF>
static void launch_g2(const void* A, const short* B, void* C, int M, int N, int K,
                      int KSA, int KSB, const float* bias,
                      const float* rowscale, int rs_div,
                      const float* addsrc, int addN, hipStream_t st) {
    dim3 grid(N / GBN, (M + GBM - 1) / GBM);
    g2_k<EPI, ABF, CBF><<<grid, 256, 0, st>>>(A, B, C, M, N, K, KSA, KSB,
                                              bias, rowscale, rs_div, addsrc, addN);
}

// ---------------- LayerNorm: one wave per 512-row, no barriers ----------------
__global__ __launch_bounds__(256) void lnw_bf_k(const float* __restrict__ x,
                                                const float* __restrict__ g,
                                                const float* __restrict__ b,
                                                short* __restrict__ z) {
    int r = blockIdx.x * 4 + (threadIdx.x >> 6);
    int lane = threadIdx.x & 63;
    int d = lane * 4;
    const float* xr = x + (size_t)r * Hc;
    float4 v0 = *(const float4*)(xr + d);
    float4 v1 = *(const float4*)(xr + d + 256);
    const float* p0 = (const float*)&v0;
    const float* p1 = (const float*)&v1;
    float s = 0.f, sq = 0.f;
#pragma unroll
    for (int j = 0; j < 4; j++) {
        s += p0[j] + p1[j];
        sq += p0[j] * p0[j] + p1[j] * p1[j];
    }
    s = wave_sum(s);
    sq = wave_sum(sq);
    float mean = s * (1.f / Hc);
    float var  = sq * (1.f / Hc) - mean * mean;
    float inv  = rsqrtf(var + 1e-5f);
    float4 g0 = *(const float4*)(g + d), g1 = *(const float4*)(g + d + 256);
    float4 b0 = *(const float4*)(b + d), b1 = *(const float4*)(b + d + 256);
    const float* gp0 = (const float*)&g0; const float* gp1 = (const float*)&g1;
    const float* bp0 = (const float*)&b0; const float* bp1 = (const float*)&b1;
    bf16x4 o0, o1;
#pragma unroll
    for (int j = 0; j < 4; j++) {
        o0[j] = f2bf((p0[j] - mean) * inv * gp0[j] + bp0[j]);
        o1[j] = f2bf((p1[j] - mean) * inv * gp1[j] + bp1[j]);
    }
    short* zr = z + (size_t)r * Hc;
    *(bf16x4*)(zr + d)       = o0;
    *(bf16x4*)(zr + d + 256) = o1;
}

// ---------------- fused residual-add + LayerNorm ----------------
__global__ __launch_bounds__(256) void add3ln_k(const float* __restrict__ x,
                                                float* __restrict__ ctx,
                                                const float* __restrict__ fn,
                                                const float* __restrict__ g,
                                                const float* __restrict__ b,
                                                short* __restrict__ z) {
    int r = blockIdx.x * 4 + (threadIdx.x >> 6);
    int lane = threadIdx.x & 63;
    int d = lane * 4;
    size_t base = (size_t)r * Hc;
    float4 x0 = *(const float4*)(x + base + d),   x1 = *(const float4*)(x + base + d + 256);
    float4 c0 = *(const float4*)(ctx + base + d), c1 = *(const float4*)(ctx + base + d + 256);
    float4 f0 = *(const float4*)(fn + base + d),  f1 = *(const float4*)(fn + base + d + 256);
    float v[8];
    v[0] = x0.x + c0.x + f0.x; v[1] = x0.y + c0.y + f0.y;
    v[2] = x0.z + c0.z + f0.z; v[3] = x0.w + c0.w + f0.w;
    v[4] = x1.x + c1.x + f1.x; v[5] = x1.y + c1.y + f1.y;
    v[6] = x1.z + c1.z + f1.z; v[7] = x1.w + c1.w + f1.w;
    *(float4*)(ctx + base + d)       = *(float4*)&v[0];
    *(float4*)(ctx + base + d + 256) = *(float4*)&v[4];
    float s = 0.f, sq = 0.f;
#pragma unroll
    for (int j = 0; j < 8; j++) { s += v[j]; sq += v[j] * v[j]; }
    s = wave_sum(s);
    sq = wave_sum(sq);
    float mean = s * (1.f / Hc);
    float var  = sq * (1.f / Hc) - mean * mean;
    float inv  = rsqrtf(var + 1e-5f);
    float4 g0 = *(const float4*)(g + d), g1 = *(const float4*)(g + d + 256);
    float4 b0 = *(const float4*)(b + d), b1 = *(const float4*)(b + d + 256);
    const float* gp0 = (const float*)&g0; const float* gp1 = (const float*)&g1;
    const float* bp0 = (const float*)&b0; const float* bp1 = (const float*)&b1;
    bf16x4 o0, o1;
#pragma unroll
    for (int j = 0; j < 4; j++) {
        o0[j] = f2bf((v[j]     - mean) * inv * gp0[j] + bp0[j]);
        o1[j] = f2bf((v[j + 4] - mean) * inv * gp1[j] + bp1[j]);
    }
    short* zr = z + base;
    *(bf16x4*)(zr + d)       = o0;
    *(bf16x4*)(zr + d + 256) = o1;
}

// ---------------- weight-gen stats (split + atomic partials) ----------------
__global__ __launch_bounds__(256) void wg_stats_k(const float* __restrict__ pri,
                                                  const float* __restrict__ conn,
                                                  float* __restrict__ mass, float* __restrict__ dot,
                                                  float* __restrict__ nrmp, float* __restrict__ nrmc) {
    __shared__ float sh[4];
    int bp = blockIdx.x;
    int sp = blockIdx.y;
    int b = bp >> 2, r = bp & 3;   // P+1 == 4
    const int per = (NNc + WGS_SPLIT - 1) / WGS_SPLIT;
    int i0 = sp * per;
    int i1 = i0 + per; if (i1 > NNc) i1 = NNc;
    const float* c = conn + (size_t)b * NNc;
    if (r < Pc) {
        const float* p = pri + (size_t)(b * Pc + r) * NNc;
        float sa = 0, sq = 0, sd = 0;
        for (int i = i0 + threadIdx.x; i < i1; i += 256) {
            float pv = p[i], cv = c[i];
            sa += fabsf(pv); sq += pv * pv; sd += pv * cv;
        }
        sa = blk_sum(sa, sh);
        sq = blk_sum(sq, sh);
        sd = blk_sum(sd, sh);
        if (threadIdx.x == 0) {
            atomicAdd(&mass[b * Pc + r], sa);
            atomicAdd(&nrmp[b * Pc + r], sq);
            atomicAdd(&dot[b * Pc + r], sd);
        }
    } else {
        float sq = 0;
        for (int i = i0 + threadIdx.x; i < i1; i += 256) { float cv = c[i]; sq += cv * cv; }
        sq = blk_sum(sq, sh);
        if (threadIdx.x == 0) atomicAdd(&nrmc[b], sq);
    }
}

__global__ void wg_sw_k(const float* mass, const float* dot, const float* nrmp, const float* nrmc,
                        float* sw, float* invm) {
    int b = threadIdx.x;
    if (b >= Bc) return;
    float nc = fmaxf(sqrtf(nrmc[b]), 1e-12f);
    float s[Pc];
    for (int p = 0; p < Pc; p++) s[p] = dot[b * Pc + p] / (nc * fmaxf(sqrtf(nrmp[b * Pc + p]), 1e-12f));
    float m = fmaxf(s[0], fmaxf(s[1], s[2]));
    float e[Pc], sum = 0;
    for (int p = 0; p < Pc; p++) { e[p] = expf(s[p] - m); sum += e[p]; }
    for (int p = 0; p < Pc; p++) {
        sw[b * Pc + p] = e[p] / sum;
        invm[b * Pc + p] = 1.f / mass[b * Pc + p];
    }
}

// ---------------- fused_nh: float4 vectorized ----------------
__global__ void fused_nhv_k(const float4* __restrict__ PE4, const float* __restrict__ swp,
                            float4* __restrict__ FN4, size_t count4) {
    size_t idx = (size_t)blockIdx.x * blockDim.x + threadIdx.x;
    if (idx >= count4) return;
    const size_t row4 = NH_f / 4;
    int bl = (int)(idx / row4);
    size_t within = idx % row4;
    const float* sw = swp + bl * Pc;
    size_t base = (size_t)bl * 3 * row4 + within;
    float4 a = PE4[base], b = PE4[base + row4], c = PE4[base + 2 * row4];
    float4 o;
    o.x = sw[0] * a.x + sw[1] * b.x + sw[2] * c.x;
    o.y = sw[0] * a.y + sw[1] * b.y + sw[2] * c.y;
    o.z = sw[0] * a.z + sw[1] * b.z + sw[2] * c.z;
    o.w = sw[0] * a.w + sw[1] * b.w + sw[2] * c.w;
    FN4[idx] = o;
}

// ---------------- tokens: mean over N of H1 (bf16), split ----------------
// tokens = mean_n(gelu_out H1) @ f2w + f2b  (mean-linearity: the full EPI1 GEMM over
// 9096 rows is unnecessary — only its column means were consumed)
__global__ __launch_bounds__(512) void tokens_part_bf_k(const short* __restrict__ H1,
                                                        float* __restrict__ TOKP) {
    int bp = blockIdx.x, sp = blockIdx.y, h = threadIdx.x;
    const int rows = (Nc + TSPLIT - 1) / TSPLIT;
    int n0 = sp * rows;
    int n1 = n0 + rows; if (n1 > Nc) n1 = Nc;
    const short* base = H1 + (size_t)bp * NH_f + h;
    float s = 0;
    for (int n = n0; n < n1; n++) s += bf2f(base[(size_t)n * Hc]);
    TOKP[((size_t)bp * TSPLIT + sp) * Hc + h] = s;
}

__global__ __launch_bounds__(512) void tokens_red_k(const float* __restrict__ TOKP,
                                                    float* __restrict__ TOKPRE, int bpoff) {
    int bp = blockIdx.x, h = threadIdx.x;
    float s = 0;
#pragma unroll
    for (int sp = 0; sp < TSPLIT; sp++) s += TOKP[((size_t)bp * TSPLIT + sp) * Hc + h];
    TOKPRE[(size_t)(bpoff + bp) * Hc + h] = s * (1.0f / (float)Nc);
}

// tiny fp32 GEMM: TOK2[r][n] = sum_k TOKPRE[r][k]*f2w[k][n] + f2b[n]  (96x512x512)
// fp32 weights: strictly closer to reference than the bf16-packed EPI1 it replaces.
__global__ __launch_bounds__(512) void tok2_k(const float* __restrict__ TP,
                                              const float* __restrict__ f2w,
                                              const float* __restrict__ f2b,
                                              float* __restrict__ TOK2) {
    __shared__ float row[Hc];
    int r = blockIdx.x, n = threadIdx.x;
    row[n] = TP[(size_t)r * Hc + n];
    __syncthreads();
    float acc = f2b[n];
#pragma unroll 8
    for (int k = 0; k < Hc; k++)
        acc = fmaf(row[k], f2w[(size_t)k * Hc + n], acc);
    TOK2[(size_t)r * Hc + n] = acc;
}

__global__ __launch_bounds__(64) void wg_attn_k(const float* __restrict__ QW,
                                                float* __restrict__ aw_out, float* __restrict__ msum) {
    int b = blockIdx.x, lane = threadIdx.x;
    float s[4][Pc][Pc];
    for (int h = 0; h < 4; h++)
        for (int i = 0; i < Pc; i++)
            for (int j = 0; j < Pc; j++) {
                const float* q = QW + (size_t)(b * Pc + i) * 1536 + h * 128;
                const float* k = QW + (size_t)(b * Pc + j) * 1536 + 512 + h * 128;
                float p = q[lane] * k[lane] + q[lane + 64] * k[lane + 64];
#pragma unroll
                for (int off = 32; off; off >>= 1) p += __shfl_xor(p, off, 64);
                s[h][i][j] = p * 0.08838834764831845f;
            }
    float aw[Pc] = {0, 0, 0};
    for (int h = 0; h < 4; h++)
        for (int i = 0; i < Pc; i++) {
            float m = fmaxf(s[h][i][0], fmaxf(s[h][i][1], s[h][i][2]));
            float e0 = expf(s[h][i][0] - m), e1 = expf(s[h][i][1] - m), e2 = expf(s[h][i][2] - m);
            float inv = 1.f / (e0 + e1 + e2);
            aw[0] += e0 * inv; aw[1] += e1 * inv; aw[2] += e2 * inv;
        }
    for (int j = 0; j < Pc; j++) aw[j] *= (1.f / 12.f);
    float m2 = fmaxf(aw[0], fmaxf(aw[1], aw[2]));
    float e0 = expf((aw[0] - m2) * 100.f), e1 = expf((aw[1] - m2) * 100.f), e2 = expf((aw[2] - m2) * 100.f);
    float inv = 1.f / (e0 + e1 + e2);
    if (lane == 0) {
        aw_out[b * Pc + 0] = e0 * inv;
        aw_out[b * Pc + 1] = e1 * inv;
        aw_out[b * Pc + 2] = e2 * inv;
        msum[b] = (e0 + e1 + e2) * inv;
    }
}

// ---------------- mask precompute ----------------
__global__ __launch_bounds__(256) void mask_k(const float* __restrict__ conn,
                                              const float* __restrict__ msum,
                                              const float* __restrict__ alpha,
                                              float* __restrict__ MK) {
    int b = blockIdx.y;
    int i = blockIdx.x * 256 + threadIdx.x;
    if (i >= NNc) return;
    float a2 = 0.5f * alpha[0];
    float mterm = a2 * msum[b];
    size_t idx = (size_t)b * NNc + i;
    MK[idx] = 0.125f * (1.f + tanhf(mterm + (1.f - a2) * conn[idx]));
}

// ---------------- MFMA flash attention ----------------
#define ATQ 32
#define PSTR 196   // P32 row stride (u32)
#define VSTR 36    // Vt row stride (u32)
__global__ __launch_bounds__(256) void fattn_mfma_k(const short* __restrict__ QKVb,
                                                    const float* __restrict__ MK,
                                                    int b0, float* __restrict__ ctx) {
    __shared__ __attribute__((aligned(16))) short KVb[64 * 72];
    __shared__ __attribute__((aligned(16))) unsigned P32[32 * PSTR];
    __shared__ float redm[4][32];
    __shared__ float reds[4][32];
    unsigned* Vt = (unsigned*)KVb;

    int i0 = blockIdx.x * ATQ;
    int h = blockIdx.y, bl = blockIdx.z;
    int b = b0 + bl;
    int t = threadIdx.x;
    int w = t >> 6, lane = t & 63;
    int quad = lane >> 4, l16 = lane & 15;

    bf16x8 qf[2][2];
#pragma unroll
    for (int mt = 0; mt < 2; mt++) {
        int gi = i0 + mt * 16 + l16; if (gi >= Nc) gi = Nc - 1;
        const short* qp = QKVb + ((size_t)bl * Nc + gi) * 1536 + h * HDc;
#pragma unroll
        for (int ks = 0; ks < 2; ks++)
            qf[mt][ks] = *(const bf16x8*)(qp + ks * 32 + quad * 8);
    }

    f32x4 sacc[6][2] = {};
#pragma unroll
    for (int kt = 0; kt < 6; kt++) {
        __syncthreads();
        {
            int j = t >> 2, d0 = (t & 3) * 16;
            int gj = kt * 64 + j; if (gj >= Nc) gj = Nc - 1;
            const short* kp = QKVb + ((size_t)bl * Nc + gj) * 1536 + 512 + h * HDc + d0;
            *(bf16x8*)&KVb[j * 72 + d0]     = *(const bf16x8*)kp;
            *(bf16x8*)&KVb[j * 72 + d0 + 8] = *(const bf16x8*)(kp + 8);
        }
        __syncthreads();
        int kl = w * 16 + l16;
#pragma unroll
        for (int ks = 0; ks < 2; ks++) {
            bf16x8 kf = *(const bf16x8*)&KVb[kl * 72 + ks * 32 + quad * 8];
            sacc[kt][0] = __builtin_amdgcn_mfma_f32_16x16x32_bf16(qf[0][ks], kf, sacc[kt][0], 0, 0, 0);
            sacc[kt][1] = __builtin_amdgcn_mfma_f32_16x16x32_bf16(qf[1][ks], kf, sacc[kt][1], 0, 0, 0);
        }
    }

    float mmax[2][4];
#pragma unroll
    for (int mt = 0; mt < 2; mt++)
#pragma unroll
        for (int r = 0; r < 4; r++) mmax[mt][r] = -3.4e38f;
    int kcol = w * 16 + l16;
#pragma unroll
    for (int kt = 0; kt < 6; kt++) {
        int k = kt * 64 + kcol;
        bool kin = (k < Nc);
#pragma unroll
        for (int mt = 0; mt < 2; mt++)
#pragma unroll
            for (int r = 0; r < 4; r++) {
                int q = i0 + mt * 16 + quad * 4 + r; if (q >= Nc) q = Nc - 1;
                float s = sacc[kt][mt][r];
                s = kin ? s * MK[((size_t)b * Nc + q) * Nc + k] : -3.4e38f;
                sacc[kt][mt][r] = s;
                mmax[mt][r] = fmaxf(mmax[mt][r], s);
            }
    }
#pragma unroll
    for (int mt = 0; mt < 2; mt++)
#pragma unroll
        for (int r = 0; r < 4; r++) {
            float v = mmax[mt][r];
            v = fmaxf(v, __shfl_xor(v, 1, 64));
            v = fmaxf(v, __shfl_xor(v, 2, 64));
            v = fmaxf(v, __shfl_xor(v, 4, 64));
            v = fmaxf(v, __shfl_xor(v, 8, 64));
            mmax[mt][r] = v;
        }
    if (l16 == 0) {
#pragma unroll
        for (int mt = 0; mt < 2; mt++)
#pragma unroll
            for (int r = 0; r < 4; r++)
                redm[w][mt * 16 + quad * 4 + r] = mmax[mt][r];
    }
    __syncthreads();
    float gmax[2][4], lsum[2][4];
#pragma unroll
    for (int mt = 0; mt < 2; mt++)
#pragma unroll
        for (int r = 0; r < 4; r++) {
            int qq = mt * 16 + quad * 4 + r;
            gmax[mt][r] = fmaxf(fmaxf(redm[0][qq], redm[1][qq]), fmaxf(redm[2][qq], redm[3][qq]));
            lsum[mt][r] = 0.f;
        }
#pragma unroll
    for (int kt = 0; kt < 6; kt++)
#pragma unroll
        for (int mt = 0; mt < 2; mt++)
#pragma unroll
            for (int r = 0; r < 4; r++) {
                float p = __expf(sacc[kt][mt][r] - gmax[mt][r]);
                sacc[kt][mt][r] = p;
                lsum[mt][r] += p;
            }
#pragma unroll
    for (int mt = 0; mt < 2; mt++)
#pragma unroll
        for (int r = 0; r < 4; r++) {
            float v = lsum[mt][r];
            v += __shfl_xor(v, 1, 64);
            v += __shfl_xor(v, 2, 64);
            v += __shfl_xor(v, 4, 64);
            v += __shfl_xor(v, 8, 64);
            lsum[mt][r] = v;
        }
    if (l16 == 0) {
#pragma unroll
        for (int mt = 0; mt < 2; mt++)
#pragma unroll
            for (int r = 0; r < 4; r++)
                reds[w][mt * 16 + quad * 4 + r] = lsum[mt][r];
    }
#pragma unroll
    for (int kt = 0; kt < 6; kt++)
#pragma unroll
        for (int mt = 0; mt < 2; mt++)
#pragma unroll
            for (int r = 0; r < 4; r++) {
                float p = sacc[kt][mt][r];
                float nb = __shfl_xor(p, 1, 64);
                if ((l16 & 1) == 0) {
                    unsigned lo = (unsigned)(unsigned short)f2bf(p);
                    unsigned hi = (unsigned)(unsigned short)f2bf(nb);
                    int q = mt * 16 + quad * 4 + r;
                    P32[q * PSTR + kt * 32 + w * 8 + (l16 >> 1)] = lo | (hi << 16);
                }
            }
    __syncthreads();

    int mtw = w >> 1, ntb = (w & 1) * 2;
    float linv[4];
#pragma unroll
    for (int r = 0; r < 4; r++) {
        int qq = mtw * 16 + quad * 4 + r;
        linv[r] = 1.f / (reds[0][qq] + reds[1][qq] + reds[2][qq] + reds[3][qq]);
    }

    f32x4 oacc[2] = {};
#pragma unroll
    for (int kt = 0; kt < 6; kt++) {
        __syncthreads();
        {
            int kp = t & 31, dg = t >> 5;
            int g0 = kt * 64 + 2 * kp, g1 = g0 + 1;
            if (g0 >= Nc) g0 = Nc - 1;
            if (g1 >= Nc) g1 = Nc - 1;
            const short* v0p = QKVb + ((size_t)bl * Nc + g0) * 1536 + 1024 + h * HDc + dg * 8;
            const short* v1p = QKVb + ((size_t)bl * Nc + g1) * 1536 + 1024 + h * HDc + dg * 8;
            bf16x8 v0 = *(const bf16x8*)v0p;
            bf16x8 v1 = *(const bf16x8*)v1p;
#pragma unroll
            for (int i = 0; i < 8; i++)
                Vt[(dg * 8 + i) * VSTR + kp] =
                    ((unsigned)(unsigned short)v0[i]) | (((unsigned)(unsigned short)v1[i]) << 16);
        }
        __syncthreads();
#pragma unroll
        for (int ks = 0; ks < 2; ks++) {
            bf16x8 pf = *(const bf16x8*)&P32[(mtw * 16 + l16) * PSTR + kt * 32 + ks * 16 + quad * 4];
#pragma unroll
            for (int nt2 = 0; nt2 < 2; nt2++) {
                int d = (ntb + nt2) * 16 + l16;
                bf16x8 vf = *(const bf16x8*)&Vt[d * VSTR + ks * 16 + quad * 4];
                oacc[nt2] = __builtin_amdgcn_mfma_f32_16x16x32_bf16(pf, vf, oacc[nt2], 0, 0, 0);
            }
        }
    }
#pragma unroll
    for (int nt2 = 0; nt2 < 2; nt2++)
#pragma unroll
        for (int r = 0; r < 4; r++) {
            int gi = i0 + mtw * 16 + quad * 4 + r;
            if (gi < Nc) {
                int d = (ntb + nt2) * 16 + l16;
                ctx[((size_t)b * Nc + gi) * Hc + h * HDc + d] = oacc[nt2][r] * linv[r];
            }
        }
}

// ---------------- vectorized elementwise ----------------
__global__ void finalv_k(const float4* __restrict__ AO, const float4* __restrict__ FF,
                         const float* __restrict__ dw,
                         float4* __restrict__ xout, float4* __restrict__ proj, size_t count4) {
    size_t idx = (size_t)blockIdx.x * blockDim.x + threadIdx.x;
    if (idx >= count4) return;
    float w = dw[0];
    float4 ff = FF[idx], ao = AO[idx];
    float4 xn, pr;
    xn.x = ao.x + ff.x; xn.y = ao.y + ff.y; xn.z = ao.z + ff.z; xn.w = ao.w + ff.w;
    pr.x = w * ff.x + (1.f - w) * xn.x; pr.y = w * ff.y + (1.f - w) * xn.y;
    pr.z = w * ff.z + (1.f - w) * xn.z; pr.w = w * ff.w + (1.f - w) * xn.w;
    xout[idx] = xn;
    proj[idx] = pr;
}

// ---------------- final KL: grid-stride, KLB atomics total ----------------
__global__ __launch_bounds__(256) void final_klw2_k(const float* __restrict__ AO,
                                                    const float* __restrict__ FF,
                                                    const float* __restrict__ dw,
                                                    const float* __restrict__ PF,
                                                    float* __restrict__ xout,
                                                    float* __restrict__ acc) {
    __shared__ float sh[4];
    int wid = threadIdx.x >> 6, lane = threadIdx.x & 63;
    int gw = blockIdx.x * 4 + wid;
    int d = lane * 4;
    float w = dw[1];
    float ts_acc = 0.f;
    for (int r = gw; r < ROWS_BN; r += KLB * 4) {
        size_t base = (size_t)r * Hc;
        float4 ff0 = *(const float4*)(FF + base + d), ff1 = *(const float4*)(FF + base + d + 256);
        float4 ao0 = *(const float4*)(AO + base + d), ao1 = *(const float4*)(AO + base + d + 256);
        float4 pf0 = *(const float4*)(PF + base + d), pf1 = *(const float4*)(PF + base + d + 256);
        float ff[8], ao[8], pf[8];
        *(float4*)&ff[0] = ff0; *(float4*)&ff[4] = ff1;
        *(float4*)&ao[0] = ao0; *(float4*)&ao[4] = ao1;
        *(float4*)&pf[0] = pf0; *(float4*)&pf[4] = pf1;
        float xn[8], sv[8];
        float mf = -3.4e38f, ms = -3.4e38f;
#pragma unroll
        for (int j = 0; j < 8; j++) {
            xn[j] = ao[j] + ff[j];
            sv[j] = w * ff[j] + (1.f - w) * xn[j];
            mf = fmaxf(mf, pf[j]);
            ms = fmaxf(ms, sv[j]);
        }
        *(float4*)(xout + base + d)       = *(float4*)&xn[0];
        *(float4*)(xout + base + d + 256) = *(float4*)&xn[4];
        mf = wave_max(mf);
        ms = wave_max(ms);
        float ef = 0.f, es = 0.f;
#pragma unroll
        for (int j = 0; j < 8; j++) {
            ef += expf(pf[j] - mf);
            es += expf(sv[j] - ms);
        }
        ef = wave_sum(ef);
        es = wave_sum(es);
        float lsef = mf + logf(ef), lses = ms + logf(es);
        float ts = 0.f;
#pragma unroll
        for (int j = 0; j < 8; j++) {
            float lf = pf[j] - lsef, ls = sv[j] - lses;
            ts += expf(ls) * (ls - lf) + expf(lf) * (lf - ls);
        }
        ts_acc += wave_sum(ts);
    }
    if (lane == 0) sh[wid] = ts_acc;
    __syncthreads();
    if (threadIdx.x == 0)
        atomicAdd(acc, sh[0] + sh[1] + sh[2] + sh[3]);
}

__global__ void kl_final_k(const float* __restrict__ acc, float* __restrict__ out) {
    out[0] = 0.5f * acc[0] * (1.0f / (float)ROWS_BN);
}

// ---------------- launch ----------------
extern "C" void kernel_launch(void* const* d_in, const int* in_sizes, int n_in,
                              void* d_out, int out_size, void* d_ws, size_t ws_size,
                              hipStream_t stream) {
    (void)in_sizes; (void)n_in; (void)out_size; (void)ws_size;
    const float* x[2]    = {(const float*)d_in[0], (const float*)d_in[1]};
    const float* pri[2]  = {(const float*)d_in[2], (const float*)d_in[3]};
    const float* conn[2] = {(const float*)d_in[4], (const float*)d_in[5]};
    const float* dw      = (const float*)d_in[6];
    const float* wqkv[2] = {(const float*)d_in[7], (const float*)d_in[8]};
    const float* ln_g    = (const float*)d_in[9];
    const float* ln_b    = (const float*)d_in[10];
    const float* ffn_w1  = (const float*)d_in[11];
    const float* ffn_b1  = (const float*)d_in[12];
    const float* ffn_w2  = (const float*)d_in[13];
    const float* ffn_b2  = (const float*)d_in[14];
    const float* pw      = (const float*)d_in[15];
    const float* pb      = (const float*)d_in[16];
    const float* f1w     = (const float*)d_in[17];
    const float* f1b     = (const float*)d_in[18];
    const float* f2w     = (const float*)d_in[19];
    const float* f2b     = (const float*)d_in[20];
    const float* ipw     = (const float*)d_in[21];
    const float* ipb     = (const float*)d_in[22];
    const float* alpha   = (const float*)d_in[23];
    float* out = (float*)d_out;

    // --- workspace arena ---
    float* W = (float*)d_ws;
    size_t o = 0;
    auto alloc = [&](size_t n) { float* p = W + o; o += n; return p; };
    float* Z     = alloc(BNH);               // bf16 Zb (wg/attn) then fp32 FFNOUT (ffn/final)
    float* CTX   = alloc(BNH);
    float* FN    = alloc(BNH);
    float* PROJ0 = alloc(BNH);
    float* R     = alloc(12420096);          // shared transient region (fits full-M HIDB)
    float* TOK   = alloc((size_t)96 * Hc);   // mean_n(H1) = tokens_pre
    float* TOK2  = alloc((size_t)96 * Hc);   // tokens (post f2w)
    float* QKVWG = alloc((size_t)96 * 1536);
    float* MASS  = alloc(96); float* DOT = alloc(96); float* NRMP = alloc(96);
    float* NRMC  = alloc(32); float* SW  = alloc(96); float* INVM = alloc(96);
    float* MSUM  = alloc(32);
    float* KLACC = alloc(1);
    // bf16 weight packs (persistent across launch)
    short* W1P  = (short*)alloc(262144);     // f1w  [512n][1024k]
    short* PWP  = (short*)alloc(98304);      // pw   [512n][384k]
    short* IPP  = (short*)alloc(393216);     // ipw  [1536n][512k]
    short* QKVP = (short*)alloc(393216);     // wqkv[s] [1536n][512k]
    short* F1P  = (short*)alloc(524288);     // ffn_w1[s] [2048n][512k]
    short* F2P  = (short*)alloc(524288);     // ffn_w2[s] [512n][2048k]

    // R overlays (disjoint lifetimes, phases serialized by stream order):
    float* PEc  = R;                               // wg phase: pe, 9096x512 fp32
    short* H1B  = (short*)(R + PEC_SZ);            // wg phase: H1, 9096x512 bf16
    float* ZFc  = R + PEC_SZ + 2328576;            // wg phase: xe@W1hi, 3032x512 fp32
    float* TOKP = ZFc;                             // tokens partials (ZFc dead after EPI3)
    short* QKVcB = (short*)R;                      // attn phase: 3032x1536 bf16
    float* MKbuf = R + 2400000;                    // attn phase: 32x379x379 fp32
    short* HIDB = (short*)R;                       // FFN phase: FULL-M 12128x2048 bf16
    short* PRIB = (short*)CTX;                     // packed pri chunk (CTX dead till fattn)
    short* Zb   = (short*)Z;                       // bf16 ln output [12128][512]
    float* FFNOUT = Z;                             // FFN phase: Zb dead after FFN1

    const size_t OUT_DISTILL = 2 * BNH;
    const size_t OUT_AW = 2 * BNH + 1;

    hipMemsetAsync(KLACC, 0, sizeof(float), stream);

    int eb = 256;
    size_t cnt4BNH = BNH / 4;
    int g4BNH = (int)((cnt4BNH + eb - 1) / eb);
    size_t cnt4CHK = CHUNK_NH / 4;
    int g4CHK = (int)((cnt4CHK + eb - 1) / eb);
    int gPACK = (ROWS_WG * (KPAD / 8) + 255) / 256;
    int gLNW = ROWS_BN / 4;

    // one-time weight packs (shared across s)
    pack_b_k<<<(512 * 128 + 255) / 256, 256, 0, stream>>>(f1w, W1P, 1024, 512, 1024);
    pack_b_k<<<(512 * 48  + 255) / 256, 256, 0, stream>>>(pw,  PWP, Nc, 512, KPAD);
    pack_b_k<<<(1536 * 64 + 255) / 256, 256, 0, stream>>>(ipw, IPP, 512, 1536, 512);

    for (int s = 0; s < 2; s++) {
        // per-s weight packs
        pack_b_k<<<(1536 * 64 + 255) / 256, 256, 0, stream>>>(wqkv[s], QKVP, 512, 1536, 512);
        pack_b_k<<<(2048 * 64 + 255) / 256, 256, 0, stream>>>(ffn_w1 + (size_t)s * Hc * 4 * Hc, F1P, 512, 2048, 512);
        pack_b_k<<<(512 * 256 + 255) / 256, 256, 0, stream>>>(ffn_w2 + (size_t)s * 4 * Hc * Hc, F2P, 2048, 512, 2048);

        lnw_bf_k<<<gLNW, 256, 0, stream>>>(x[s], ln_g + s * Hc, ln_b + s * Hc, Zb);
        hipMemsetAsync(MASS, 0, 320 * sizeof(float), stream);
        wg_stats_k<<<dim3(Bc * (Pc + 1), WGS_SPLIT), 256, 0, stream>>>(
            pri[s], conn[s], MASS, DOT, NRMP, NRMC);
        wg_sw_k<<<1, 64, 0, stream>>>(MASS, DOT, NRMP, NRMC, SW, INVM);

        // ---- weight-gen pipeline, chunked over batches ----
        for (int c = 0; c < NCHUNK; c++) {
            const float* pric = pri[s] + (size_t)c * ROWS_WG * Nc;
            const short* Zc = Zb + (size_t)c * ROWS_CHUNK * Hc;
            // xe @ f1w[512:1024] -> ZFc (fp32, consumed in EPI3)
            launch_g2<0, 1, 0>(Zc, W1P + 512, ZFc, ROWS_CHUNK, Hc, Hc, Hc, 1024,
                               nullptr, nullptr, 0, nullptr, 0, stream);
            // pri -> bf16 pack, then pri @ pw (EPI4: *invmass + bias)
            pack_pri_k<<<gPACK, 256, 0, stream>>>(pric, PRIB, ROWS_WG);
            launch_g2<4, 1, 0>(PRIB, PWP, PEc, ROWS_WG, Hc, KPAD, KPAD, KPAD,
                               pb, INVM + c * CB * Pc, Nc, nullptr, 0, stream);
            fused_nhv_k<<<g4CHK, eb, 0, stream>>>((const float4*)PEc, SW + c * CB * Pc,
                                                  (float4*)(FN + (size_t)c * CHUNK_NH), cnt4CHK);
            // pe @ f1w[0:512] + b + ZFc -> gelu -> H1B (bf16)
            launch_g2<3, 0, 1>(PEc, W1P, H1B, ROWS_WG, Hc, Hc, Hc, 1024,
                               f1b, nullptr, 0, ZFc, Nc, stream);
            // tokens = mean_n(H1): full fused=H1@f2w GEMM eliminated via mean-linearity
            tokens_part_bf_k<<<dim3(CB * Pc, TSPLIT), 512, 0, stream>>>(H1B, TOKP);
            tokens_red_k<<<CB * Pc, 512, 0, stream>>>(TOKP, TOK, c * CB * Pc);
        }
        // tokens @ f2w + f2b (tiny fp32 GEMM), then @ ipw -> QKVWG
        tok2_k<<<Bc * Pc, 512, 0, stream>>>(TOK, f2w, f2b, TOK2);
        launch_g2<1, 0, 0>(TOK2, IPP, QKVWG, Bc * Pc, 3 * Hc, Hc, Hc, Hc,
                           ipb, nullptr, 0, nullptr, 0, stream);
        wg_attn_k<<<Bc, 64, 0, stream>>>(QKVWG, out + OUT_AW + (size_t)s * (Bc * Pc), MSUM);

        // ---- mask precompute (needs MSUM), then main attention chunks ----
        mask_k<<<dim3((NNc + 255) / 256, Bc), 256, 0, stream>>>(conn[s], MSUM, alpha, MKbuf);
        for (int c = 0; c < NCHUNK; c++) {
            const short* Zc = Zb + (size_t)c * ROWS_CHUNK * Hc;
            launch_g2<0, 1, 1>(Zc, QKVP, QKVcB, ROWS_CHUNK, 3 * Hc, Hc, Hc, Hc,
                               nullptr, nullptr, 0, nullptr, 0, stream);
            fattn_mfma_k<<<dim3((Nc + ATQ - 1) / ATQ, NHc, CB), 256, 0, stream>>>(
                QKVcB, MKbuf, c * CB, CTX);
        }
        // fused: CTX = x + CTX + FN; Zb = LN(CTX)
        add3ln_k<<<gLNW, 256, 0, stream>>>(x[s], CTX, FN,
                                           ln_g + (2 + s) * Hc, ln_b + (2 + s) * Hc, Zb);

        // ---- FFN, FULL-M (de-chunked: was 192-block FFN2 at 0.75 blocks/CU) ----
        launch_g2<2, 1, 1>(Zb, F1P, HIDB, ROWS_BN, 4 * Hc, Hc, Hc, Hc,
                           ffn_b1 + (size_t)s * 4 * Hc, nullptr, 0, nullptr, 0, stream);
        launch_g2<1, 1, 0>(HIDB, F2P, FFNOUT, ROWS_BN, Hc, 4 * Hc, 4 * Hc, 4 * Hc,
                           ffn_b2 + (size_t)s * Hc, nullptr, 0, nullptr, 0, stream);

        if (s == 0) {
            finalv_k<<<g4BNH, eb, 0, stream>>>((const float4*)CTX, (const float4*)FFNOUT, dw,
                                               (float4*)out, (float4*)PROJ0, cnt4BNH);
        } else {
            final_klw2_k<<<KLB, 256, 0, stream>>>(CTX, FFNOUT, dw, PROJ0, out + BNH, KLACC);
        }
    }
    kl_final_k<<<1, 1, 0, stream>>>(KLACC, out + OUT_DISTILL);
}